// Round 1
// baseline (3341.493 us; speedup 1.0000x reference)
//
#include <hip/hip_runtime.h>
#include <math.h>

// ---- problem constants ----
#define NPATCH 16384          // B * T / P
#define SEQ    512            // T / P
#define CD     128
#define KCB    1024
#define LOGITS_N 16777216     // 32*512*1024
#define LOSS_OFF 16777216
#define IDX_OFF  16777217

// d_out scratch overlay (floats) — all dead before head GEMM writes logits
#define Z_OFF      0          // 2,097,152  z_flat [16384,128]
#define QKV_OFF    2097152    // 6,291,456  qkv    [16384,384]  (reused as F [16384,256])
#define OATT_OFF   8388608    // 2,097,152  attn out [16384,128]
#define OPROJ_OFF  10485760   // 2,097,152  proj/ffn2 out [16384,128]

// =============== encoder: one block per patch ===============
__global__ __launch_bounds__(256) void encoder_kernel(
    const float* __restrict__ x,
    const float* __restrict__ w1, const float* __restrict__ b1,
    const float* __restrict__ w2, const float* __restrict__ b2,
    const float* __restrict__ w3, const float* __restrict__ b3,
    const float* __restrict__ rw1, const float* __restrict__ rb1,
    const float* __restrict__ rw2, const float* __restrict__ rb2,
    const float* __restrict__ pw, const float* __restrict__ pb,
    float* __restrict__ z) {
  __shared__ float xs[16];
  __shared__ float h1[32 * 8];
  __shared__ float h2[64 * 4];
  __shared__ float h3[64 * 4];
  __shared__ float t1[32 * 4];
  const int n = blockIdx.x, tid = threadIdx.x;
  if (tid < 16) xs[tid] = x[n * 16 + tid];
  __syncthreads();
  { // conv1: [1,16] -> [32,8], k=4 s=2 p=1, relu
    int co = tid >> 3, l = tid & 7;
    float acc = b1[co];
#pragma unroll
    for (int kk = 0; kk < 4; ++kk) {
      int xi = 2 * l + kk - 1;
      if (xi >= 0 && xi < 16) acc += xs[xi] * w1[co * 4 + kk];
    }
    h1[co * 8 + l] = fmaxf(acc, 0.f);
  }
  __syncthreads();
  { // conv2: [32,8] -> [64,4], k=4 s=2 p=1, relu
    int co = tid >> 2, l = tid & 3;
    float acc = b2[co];
    for (int ci = 0; ci < 32; ++ci) {
      const float* wp = w2 + (co * 32 + ci) * 4;
#pragma unroll
      for (int kk = 0; kk < 4; ++kk) {
        int xi = 2 * l + kk - 1;
        if (xi >= 0 && xi < 8) acc += h1[ci * 8 + xi] * wp[kk];
      }
    }
    h2[co * 4 + l] = fmaxf(acc, 0.f);
  }
  __syncthreads();
  { // conv3: [64,4] -> [64,4], k=3 s=1 p=1 (no act)
    int co = tid >> 2, l = tid & 3;
    float acc = b3[co];
    for (int ci = 0; ci < 64; ++ci) {
      const float* wp = w3 + (co * 64 + ci) * 3;
#pragma unroll
      for (int kk = 0; kk < 3; ++kk) {
        int xi = l + kk - 1;
        if (xi >= 0 && xi < 4) acc += h2[ci * 4 + xi] * wp[kk];
      }
    }
    h3[co * 4 + l] = acc;
  }
  __syncthreads();
  // 2 residual layers: t = conv3(relu(h)) -> conv1x1(relu(t)); h += t
  for (int rl = 0; rl < 2; ++rl) {
    if (tid < 128) {
      int co = tid >> 2, l = tid & 3;
      float acc = rb1[rl * 32 + co];
      for (int ci = 0; ci < 64; ++ci) {
        const float* wp = rw1 + ((rl * 32 + co) * 64 + ci) * 3;
#pragma unroll
        for (int kk = 0; kk < 3; ++kk) {
          int xi = l + kk - 1;
          if (xi >= 0 && xi < 4) acc += fmaxf(h3[ci * 4 + xi], 0.f) * wp[kk];
        }
      }
      t1[co * 4 + l] = acc;
    }
    __syncthreads();
    {
      int co = tid >> 2, l = tid & 3;
      float acc = rb2[rl * 64 + co];
      const float* wp = rw2 + (rl * 64 + co) * 32;
      for (int ci = 0; ci < 32; ++ci)
        acc += fmaxf(t1[ci * 4 + l], 0.f) * wp[ci];
      h3[co * 4 + l] += acc;
    }
    __syncthreads();
  }
  // relu + pre 1x1 conv: [64,4] -> [32,4]; z_flat[n, e*4+l]
  if (tid < 128) {
    int e = tid >> 2, l = tid & 3;
    float acc = pb[e];
    const float* wp = pw + e * 64;
    for (int ci = 0; ci < 64; ++ci)
      acc += fmaxf(h3[ci * 4 + l], 0.f) * wp[ci];
    z[(size_t)n * 128 + e * 4 + l] = acc;
  }
}

// =============== VQ: one block per patch ===============
__global__ __launch_bounds__(256) void vq_kernel(
    const float* __restrict__ z, const float* __restrict__ cb,
    const float* __restrict__ pos, float* __restrict__ hh,
    float* __restrict__ loss_acc, float* __restrict__ idx_out) {
  __shared__ float zs[128];
  __shared__ float bd[256];
  __shared__ int bi[256];
  const int n = blockIdx.x, tid = threadIdx.x;
  if (tid < 128) zs[tid] = z[(size_t)n * 128 + tid];
  __syncthreads();
  float best = 3.4e38f;
  int bestj = 0;
  for (int e = 0; e < 4; ++e) {
    int j = tid * 4 + e;  // ascending j -> first-min tie-break within thread
    const float4* cp = reinterpret_cast<const float4*>(cb + (size_t)j * 128);
    float s = 0.f;
#pragma unroll 8
    for (int k4 = 0; k4 < 32; ++k4) {
      float4 c = cp[k4];
      float4 zv = *reinterpret_cast<const float4*>(&zs[k4 * 4]);
      float d0 = zv.x - c.x, d1 = zv.y - c.y, d2 = zv.z - c.z, d3 = zv.w - c.w;
      s += d0 * d0 + d1 * d1 + d2 * d2 + d3 * d3;
    }
    if (s < best) { best = s; bestj = j; }
  }
  bd[tid] = best; bi[tid] = bestj;
  __syncthreads();
  for (int off = 128; off > 0; off >>= 1) {
    if (tid < off) {
      float d2 = bd[tid + off]; int j2 = bi[tid + off];
      if (d2 < bd[tid] || (d2 == bd[tid] && j2 < bi[tid])) { bd[tid] = d2; bi[tid] = j2; }
    }
    __syncthreads();
  }
  const int idx = bi[0];
  if (tid == 0) idx_out[n] = (float)idx;
  float part = 0.f;
  if (tid < 128) {
    float q = cb[(size_t)idx * 128 + tid];
    float df = q - zs[tid];
    part = df * df;
    hh[(size_t)n * 128 + tid] = q + pos[(n & 511) * 128 + tid];
  }
#pragma unroll
  for (int o = 1; o < 64; o <<= 1) part += __shfl_xor(part, o);
  __shared__ float lred[4];
  if ((tid & 63) == 0) lred[tid >> 6] = part;
  __syncthreads();
  if (tid == 0) atomicAdd(loss_acc, lred[0] + lred[1]);
}

// =============== generic fp32 GEMM: C[M,N] = A[M,K] * B[N,K]^T + bias ===============
// ACT: 0 = none, 1 = exact gelu
template <int ACT>
__global__ __launch_bounds__(256) void gemm_bias(
    const float* __restrict__ A, const float* __restrict__ B,
    const float* __restrict__ bias, float* __restrict__ C,
    int M, int N, int K) {
  __shared__ float Ask[32][68];  // [k][row], padded: b128-aligned, ~2-way banks (free)
  __shared__ float Bsk[32][68];  // [k][col]
  const int tid = threadIdx.x;
  const int n0 = blockIdx.x * 64, m0 = blockIdx.y * 64;
  const int ty = tid >> 4, tx = tid & 15;  // 16x16 threads, 4x4 micro-tile
  const int lr = tid >> 3;                 // 0..31 (loader row)
  const int lc = (tid & 7) * 4;            // 0..28 (loader k-offset)
  float acc[4][4] = {};
  for (int k0 = 0; k0 < K; k0 += 32) {
#pragma unroll
    for (int p = 0; p < 2; ++p) {
      int row = p * 32 + lr;
      float4 av = *reinterpret_cast<const float4*>(A + (size_t)(m0 + row) * K + k0 + lc);
      Ask[lc + 0][row] = av.x; Ask[lc + 1][row] = av.y;
      Ask[lc + 2][row] = av.z; Ask[lc + 3][row] = av.w;
      float4 bv = *reinterpret_cast<const float4*>(B + (size_t)(n0 + row) * K + k0 + lc);
      Bsk[lc + 0][row] = bv.x; Bsk[lc + 1][row] = bv.y;
      Bsk[lc + 2][row] = bv.z; Bsk[lc + 3][row] = bv.w;
    }
    __syncthreads();
#pragma unroll
    for (int kk = 0; kk < 32; ++kk) {
      float4 av = *reinterpret_cast<const float4*>(&Ask[kk][ty * 4]);
      float4 bv = *reinterpret_cast<const float4*>(&Bsk[kk][tx * 4]);
      float a[4] = {av.x, av.y, av.z, av.w};
      float b[4] = {bv.x, bv.y, bv.z, bv.w};
#pragma unroll
      for (int ii = 0; ii < 4; ++ii)
#pragma unroll
        for (int jj = 0; jj < 4; ++jj) acc[ii][jj] += a[ii] * b[jj];
    }
    __syncthreads();
  }
#pragma unroll
  for (int ii = 0; ii < 4; ++ii) {
    int row = m0 + ty * 4 + ii;
    int col = n0 + tx * 4;
    float4 bv = *reinterpret_cast<const float4*>(bias + col);
    float o[4] = {acc[ii][0] + bv.x, acc[ii][1] + bv.y, acc[ii][2] + bv.z, acc[ii][3] + bv.w};
    if (ACT == 1) {
#pragma unroll
      for (int jj = 0; jj < 4; ++jj)
        o[jj] = 0.5f * o[jj] * (1.f + erff(o[jj] * 0.7071067811865476f));
    }
    float4 ov = {o[0], o[1], o[2], o[3]};
    *reinterpret_cast<float4*>(C + (size_t)row * N + col) = ov;
  }
}

// =============== flash-style causal attention: block per (qt, head, batch) ===============
__global__ __launch_bounds__(256) void attn_kernel(const float* __restrict__ qkv,
                                                   float* __restrict__ obuf) {
  const int qt = blockIdx.x, h = blockIdx.y, b = blockIdx.z;
  __shared__ float Qs[64][33], Ks[64][33], Vs[64][33], Os[64][33];
  __shared__ float Ss[64][65];
  __shared__ float ms[64], ls[64], alphas[64];
  const int tid = threadIdx.x;
  for (int e = 0; e < 8; ++e) {
    int idx = e * 256 + tid, i = idx >> 5, d = idx & 31;
    size_t t = (size_t)b * 512 + qt * 64 + i;
    Qs[i][d] = qkv[t * 384 + h * 32 + d];
    Os[i][d] = 0.f;
  }
  if (tid < 64) { ms[tid] = -1e30f; ls[tid] = 0.f; }
  __syncthreads();
  const float scale = 0.17677669529663687f;  // 1/sqrt(32)
  for (int kt = 0; kt <= qt; ++kt) {
    for (int e = 0; e < 8; ++e) {
      int idx = e * 256 + tid, i = idx >> 5, d = idx & 31;
      size_t t = (size_t)b * 512 + kt * 64 + i;
      Ks[i][d] = qkv[t * 384 + 128 + h * 32 + d];
      Vs[i][d] = qkv[t * 384 + 256 + h * 32 + d];
    }
    __syncthreads();
    for (int e = 0; e < 16; ++e) {
      int idx = e * 256 + tid, i = idx >> 6, j = idx & 63;
      float s = 0.f;
#pragma unroll
      for (int d = 0; d < 32; ++d) s += Qs[i][d] * Ks[j][d];
      s *= scale;
      if (kt == qt && j > i) s += -1e9f;  // matches reference additive mask
      Ss[i][j] = s;
    }
    __syncthreads();
    if (tid < 64) {
      int i = tid;
      float mx = ms[i];
      for (int j = 0; j < 64; ++j) mx = fmaxf(mx, Ss[i][j]);
      float alpha = expf(ms[i] - mx);
      float sum = 0.f;
      for (int j = 0; j < 64; ++j) {
        float p = expf(Ss[i][j] - mx);
        Ss[i][j] = p;
        sum += p;
      }
      ls[i] = ls[i] * alpha + sum;
      ms[i] = mx;
      alphas[i] = alpha;
    }
    __syncthreads();
    for (int e = 0; e < 8; ++e) {
      int idx = e * 256 + tid, i = idx >> 5, d = idx & 31;
      float a2 = 0.f;
#pragma unroll 8
      for (int j = 0; j < 64; ++j) a2 += Ss[i][j] * Vs[j][d];
      Os[i][d] = Os[i][d] * alphas[i] + a2;
    }
    __syncthreads();
  }
  for (int e = 0; e < 8; ++e) {
    int idx = e * 256 + tid, i = idx >> 5, d = idx & 31;
    size_t t = (size_t)b * 512 + qt * 64 + i;
    obuf[t * 128 + h * 32 + d] = Os[i][d] / ls[i];
  }
}

// =============== fused residual + layernorm (r may be null) ===============
__global__ __launch_bounds__(128) void resid_ln(
    const float* __restrict__ in, const float* __restrict__ r,
    float* __restrict__ outp, const float* __restrict__ g,
    const float* __restrict__ bb) {
  const int t = blockIdx.x, d = threadIdx.x;
  const size_t base = (size_t)t * 128;
  float x = in[base + d];
  if (r) x += r[base + d];
  float s = x;
#pragma unroll
  for (int o = 1; o < 64; o <<= 1) s += __shfl_xor(s, o);
  __shared__ float red[2], red2[2];
  if ((d & 63) == 0) red[d >> 6] = s;
  __syncthreads();
  float mean = (red[0] + red[1]) * 0.0078125f;
  float v = x - mean;
  float s2 = v * v;
#pragma unroll
  for (int o = 1; o < 64; o <<= 1) s2 += __shfl_xor(s2, o);
  if ((d & 63) == 0) red2[d >> 6] = s2;
  __syncthreads();
  float var = (red2[0] + red2[1]) * 0.0078125f;
  outp[base + d] = v * rsqrtf(var + 1e-5f) * g[d] + bb[d];
}

__global__ void loss_finalize(const float* __restrict__ loss, float* __restrict__ out) {
  // vq_loss = q_loss + 0.25*e_loss = 1.25 * mean((q-z)^2), mean over 16384*128
  out[0] = 1.25f * loss[0] / 2097152.0f;
}

extern "C" void kernel_launch(void* const* d_in, const int* in_sizes, int n_in,
                              void* d_out, int out_size, void* d_ws, size_t ws_size,
                              hipStream_t stream) {
  const float* x      = (const float*)d_in[0];
  const float* enc_w1 = (const float*)d_in[1];
  const float* enc_b1 = (const float*)d_in[2];
  const float* enc_w2 = (const float*)d_in[3];
  const float* enc_b2 = (const float*)d_in[4];
  const float* enc_w3 = (const float*)d_in[5];
  const float* enc_b3 = (const float*)d_in[6];
  const float* res_w1 = (const float*)d_in[7];
  const float* res_b1 = (const float*)d_in[8];
  const float* res_w2 = (const float*)d_in[9];
  const float* res_b2 = (const float*)d_in[10];
  const float* pre_w  = (const float*)d_in[11];
  const float* pre_b  = (const float*)d_in[12];
  const float* codebook = (const float*)d_in[13];
  const float* pos_emb  = (const float*)d_in[14];
  const float* qkv_w  = (const float*)d_in[15];
  const float* qkv_b  = (const float*)d_in[16];
  const float* proj_w = (const float*)d_in[17];
  const float* proj_b = (const float*)d_in[18];
  const float* ln1_g  = (const float*)d_in[19];
  const float* ln1_b  = (const float*)d_in[20];
  const float* ln2_g  = (const float*)d_in[21];
  const float* ln2_b  = (const float*)d_in[22];
  const float* ffn_w1 = (const float*)d_in[23];
  const float* ffn_b1 = (const float*)d_in[24];
  const float* ffn_w2 = (const float*)d_in[25];
  const float* ffn_b2 = (const float*)d_in[26];
  const float* fin_g  = (const float*)d_in[27];
  const float* fin_b  = (const float*)d_in[28];
  const float* head_w = (const float*)d_in[29];
  const float* head_b = (const float*)d_in[30];

  float* out = (float*)d_out;
  float* ws  = (float*)d_ws;

  // ws: hh [2M] | hhln [2M] | loss [1]   (16.8 MB)
  float* hh   = ws;
  float* hhln = ws + (1 << 21);
  float* loss = ws + (1 << 22);
  // d_out scratch overlay (all dead before head GEMM)
  float* zf    = out + Z_OFF;
  float* qkvb  = out + QKV_OFF;
  float* fbuf  = out + QKV_OFF;   // reuses qkv region (qkv dead post-attention)
  float* oatt  = out + OATT_OFF;
  float* oproj = out + OPROJ_OFF;

  hipMemsetAsync(loss, 0, sizeof(float), stream);

  encoder_kernel<<<NPATCH, 256, 0, stream>>>(x, enc_w1, enc_b1, enc_w2, enc_b2,
                                             enc_w3, enc_b3, res_w1, res_b1,
                                             res_w2, res_b2, pre_w, pre_b, zf);
  vq_kernel<<<NPATCH, 256, 0, stream>>>(zf, codebook, pos_emb, hh, loss,
                                        out + IDX_OFF);
  for (int i = 0; i < 4; ++i) {
    gemm_bias<0><<<dim3(6, 256), 256, 0, stream>>>(hh, qkv_w + i * 49152,
                                                   qkv_b + i * 384, qkvb,
                                                   NPATCH, 384, 128);
    attn_kernel<<<dim3(8, 4, 32), 256, 0, stream>>>(qkvb, oatt);
    gemm_bias<0><<<dim3(2, 256), 256, 0, stream>>>(oatt, proj_w + i * 16384,
                                                   proj_b + i * 128, oproj,
                                                   NPATCH, 128, 128);
    resid_ln<<<NPATCH, 128, 0, stream>>>(hh, oproj, hh, ln1_g + i * 128,
                                         ln1_b + i * 128);
    gemm_bias<1><<<dim3(4, 256), 256, 0, stream>>>(hh, ffn_w1 + i * 32768,
                                                   ffn_b1 + i * 256, fbuf,
                                                   NPATCH, 256, 128);
    gemm_bias<0><<<dim3(2, 256), 256, 0, stream>>>(fbuf, ffn_w2 + i * 32768,
                                                   ffn_b2 + i * 128, oproj,
                                                   NPATCH, 128, 256);
    resid_ln<<<NPATCH, 128, 0, stream>>>(hh, oproj, hh, ln2_g + i * 128,
                                         ln2_b + i * 128);
  }
  resid_ln<<<NPATCH, 128, 0, stream>>>(hh, nullptr, hhln, fin_g, fin_b);
  gemm_bias<0><<<dim3(16, 256), 256, 0, stream>>>(hhln, head_w, head_b, out,
                                                  NPATCH, 1024, 128);
  loss_finalize<<<1, 1, 0, stream>>>(loss, out + LOSS_OFF);
}

// Round 2
// 1422.813 us; speedup vs baseline: 2.3485x; 2.3485x over previous
//
#include <hip/hip_runtime.h>
#include <math.h>

// ---- problem constants ----
#define NPATCH 16384          // B * T / P
#define SEQ    512            // T / P
#define CD     128
#define KCB    1024
#define LOSS_OFF 16777216
#define IDX_OFF  16777217

// d_out scratch overlay (floats) — all dead before head GEMM writes logits
#define Z_OFF      0          // z_flat [16384,128]
#define QKV_OFF    2097152    // qkv [16384,384] (reused as F [16384,256])
#define OATT_OFF   8388608    // attn out [16384,128]

// =============== encoder v2: 32 patches per block, reg accumulators ===============
__global__ __launch_bounds__(256) void encoder2(
    const float* __restrict__ x,
    const float* __restrict__ w1, const float* __restrict__ b1,
    const float* __restrict__ w2, const float* __restrict__ b2,
    const float* __restrict__ w3, const float* __restrict__ b3,
    const float* __restrict__ rw1, const float* __restrict__ rb1,
    const float* __restrict__ rw2, const float* __restrict__ rb2,
    const float* __restrict__ pw, const float* __restrict__ pb,
    float* __restrict__ z) {
  __shared__ float ar[16384];         // 64 KB arena
  float* H1 = ar;                      // [256 feat][32 n]   (ch*8+l)
  float* H2 = ar + 8192;               // [256 feat][32 n]   (co*4+l)
  float* XS = ar + 8192;               // [16][32] overlays H2 (dead pre-conv2)
  float* H3 = ar;                      // overwrites H1 after conv3
  float* T1 = ar + 8192;               // [128][32] overlays H2 (dead post-conv3)
  const int blk = blockIdx.x, tid = threadIdx.x;
  const int n = tid & 31, g = tid >> 5;   // patch-in-block, feature group 0..7

  // load x: 32 patches x 16 samples
  if (tid < 128) {
    int p = tid >> 2, i = (tid & 3) * 4;
    float4 v = *reinterpret_cast<const float4*>(x + ((size_t)blk * 32 + p) * 16 + i);
    XS[(i + 0) * 32 + p] = v.x; XS[(i + 1) * 32 + p] = v.y;
    XS[(i + 2) * 32 + p] = v.z; XS[(i + 3) * 32 + p] = v.w;
  }
  __syncthreads();
  { // conv1: 1->32ch, L16->8, k4 s2 p1, relu.  thread: ch=g*4+c (c0..3), l0..7
    float xv[16];
#pragma unroll
    for (int i = 0; i < 16; ++i) xv[i] = XS[i * 32 + n];
#pragma unroll
    for (int c = 0; c < 4; ++c) {
      int ch = g * 4 + c;
      float4 wv = *reinterpret_cast<const float4*>(w1 + ch * 4);
      float bs = b1[ch];
      float w[4] = {wv.x, wv.y, wv.z, wv.w};
#pragma unroll
      for (int l = 0; l < 8; ++l) {
        float acc = bs;
#pragma unroll
        for (int kk = 0; kk < 4; ++kk) {
          int xi = 2 * l + kk - 1;
          if (xi >= 0 && xi < 16) acc += xv[xi] * w[kk];
        }
        H1[(ch * 8 + l) * 32 + n] = fmaxf(acc, 0.f);
      }
    }
  }
  __syncthreads();
  { // conv2: 32->64ch, L8->4, k4 s2 p1, relu.  thread: co=g*8+c (c0..7), l0..3
    float acc[8][4];
#pragma unroll
    for (int c = 0; c < 8; ++c) {
      float bs = b2[g * 8 + c];
#pragma unroll
      for (int l = 0; l < 4; ++l) acc[c][l] = bs;
    }
    for (int ci = 0; ci < 32; ++ci) {
      float hv[8];
#pragma unroll
      for (int xi = 0; xi < 8; ++xi) hv[xi] = H1[(ci * 8 + xi) * 32 + n];
#pragma unroll
      for (int c = 0; c < 8; ++c) {
        float4 wv = *reinterpret_cast<const float4*>(w2 + ((g * 8 + c) * 32 + ci) * 4);
        float w[4] = {wv.x, wv.y, wv.z, wv.w};
#pragma unroll
        for (int l = 0; l < 4; ++l)
#pragma unroll
          for (int kk = 0; kk < 4; ++kk) {
            int xi = 2 * l + kk - 1;
            if (xi >= 0 && xi < 8) acc[c][l] += hv[xi] * w[kk];
          }
      }
    }
    __syncthreads();  // all H1 reads done before H2 (overlays XS) written
#pragma unroll
    for (int c = 0; c < 8; ++c)
#pragma unroll
      for (int l = 0; l < 4; ++l)
        H2[((g * 8 + c) * 4 + l) * 32 + n] = fmaxf(acc[c][l], 0.f);
  }
  __syncthreads();
  { // conv3: 64->64ch, L4, k3 p1 (no act).  thread: co=g*8+c, l0..3
    float acc[8][4];
#pragma unroll
    for (int c = 0; c < 8; ++c) {
      float bs = b3[g * 8 + c];
#pragma unroll
      for (int l = 0; l < 4; ++l) acc[c][l] = bs;
    }
    for (int ci = 0; ci < 64; ++ci) {
      float hv[4];
#pragma unroll
      for (int xi = 0; xi < 4; ++xi) hv[xi] = H2[(ci * 4 + xi) * 32 + n];
#pragma unroll
      for (int c = 0; c < 8; ++c) {
        const float* wp = w3 + ((g * 8 + c) * 64 + ci) * 3;
        float w0 = wp[0], w1v = wp[1], w2v = wp[2];
#pragma unroll
        for (int l = 0; l < 4; ++l) {
          if (l - 1 >= 0) acc[c][l] += hv[l - 1] * w0;
          acc[c][l] += hv[l] * w1v;
          if (l + 1 < 4) acc[c][l] += hv[l + 1] * w2v;
        }
      }
    }
    __syncthreads();  // all H2 reads done before H3 (overlays H1) written
#pragma unroll
    for (int c = 0; c < 8; ++c)
#pragma unroll
      for (int l = 0; l < 4; ++l)
        H3[((g * 8 + c) * 4 + l) * 32 + n] = acc[c][l];
  }
  __syncthreads();
  // residual x2: t=conv3x3(relu(h),64->32); h += conv1x1(relu(t),32->64)
  for (int rl = 0; rl < 2; ++rl) {
    { // stage a: thread: co=g*4+c (c0..3), l0..3
      float acc[4][4];
#pragma unroll
      for (int c = 0; c < 4; ++c) {
        float bs = rb1[rl * 32 + g * 4 + c];
#pragma unroll
        for (int l = 0; l < 4; ++l) acc[c][l] = bs;
      }
      for (int ci = 0; ci < 64; ++ci) {
        float hv[4];
#pragma unroll
        for (int xi = 0; xi < 4; ++xi) hv[xi] = fmaxf(H3[(ci * 4 + xi) * 32 + n], 0.f);
#pragma unroll
        for (int c = 0; c < 4; ++c) {
          const float* wp = rw1 + ((rl * 32 + g * 4 + c) * 64 + ci) * 3;
          float w0 = wp[0], w1v = wp[1], w2v = wp[2];
#pragma unroll
          for (int l = 0; l < 4; ++l) {
            if (l - 1 >= 0) acc[c][l] += hv[l - 1] * w0;
            acc[c][l] += hv[l] * w1v;
            if (l + 1 < 4) acc[c][l] += hv[l + 1] * w2v;
          }
        }
      }
      __syncthreads();
#pragma unroll
      for (int c = 0; c < 4; ++c)
#pragma unroll
        for (int l = 0; l < 4; ++l)
          T1[((g * 4 + c) * 4 + l) * 32 + n] = acc[c][l];
    }
    __syncthreads();
    { // stage b: thread: co=g*8+c (c0..7), l0..3; h3 += conv1x1(relu(t1))
      float acc[8][4];
#pragma unroll
      for (int c = 0; c < 8; ++c) {
        float bs = rb2[rl * 64 + g * 8 + c];
#pragma unroll
        for (int l = 0; l < 4; ++l) acc[c][l] = bs;
      }
      for (int ci = 0; ci < 32; ++ci) {
        float tv[4];
#pragma unroll
        for (int l = 0; l < 4; ++l) tv[l] = fmaxf(T1[(ci * 4 + l) * 32 + n], 0.f);
#pragma unroll
        for (int c = 0; c < 8; ++c) {
          float w = rw2[(rl * 64 + g * 8 + c) * 32 + ci];
#pragma unroll
          for (int l = 0; l < 4; ++l) acc[c][l] += tv[l] * w;
        }
      }
#pragma unroll
      for (int c = 0; c < 8; ++c)
#pragma unroll
        for (int l = 0; l < 4; ++l)
          H3[((g * 8 + c) * 4 + l) * 32 + n] += acc[c][l];
    }
    __syncthreads();
  }
  { // pre 1x1: relu(h3) 64->32ch.  thread: e=g*4+c (c0..3), l0..3 -> global z
    float acc[4][4];
#pragma unroll
    for (int c = 0; c < 4; ++c) {
      float bs = pb[g * 4 + c];
#pragma unroll
      for (int l = 0; l < 4; ++l) acc[c][l] = bs;
    }
    for (int ci = 0; ci < 64; ++ci) {
      float hv[4];
#pragma unroll
      for (int l = 0; l < 4; ++l) hv[l] = fmaxf(H3[(ci * 4 + l) * 32 + n], 0.f);
#pragma unroll
      for (int c = 0; c < 4; ++c) {
        float w = pw[(g * 4 + c) * 64 + ci];
#pragma unroll
        for (int l = 0; l < 4; ++l) acc[c][l] += hv[l] * w;
      }
    }
#pragma unroll
    for (int c = 0; c < 4; ++c) {
      float4 v = {acc[c][0], acc[c][1], acc[c][2], acc[c][3]};
      *reinterpret_cast<float4*>(z + ((size_t)blk * 32 + n) * 128 + (g * 4 + c) * 4) = v;
    }
  }
}

// =============== VQ part 1: codebook squared norms ===============
__global__ __launch_bounds__(256) void cb_norms(const float* __restrict__ cb,
                                                float* __restrict__ cn) {
  int j = blockIdx.x * 256 + threadIdx.x;
  const float4* cp = reinterpret_cast<const float4*>(cb + (size_t)j * 128);
  float s = 0.f;
#pragma unroll
  for (int k = 0; k < 32; ++k) {
    float4 c = cp[k];
    s += c.x * c.x + c.y * c.y + c.z * c.z + c.w * c.w;
  }
  cn[j] = s;
}

// =============== VQ part 2: GEMM z.cb^T with fused argmin epilogue ===============
__global__ __launch_bounds__(256) void vq_argmin(
    const float* __restrict__ A, const float* __restrict__ B,
    const float* __restrict__ cn, unsigned long long* __restrict__ keys) {
  __shared__ float Ask[32][68];
  __shared__ float Bsk[32][68];
  const int tid = threadIdx.x;
  const int n0 = blockIdx.x * 64, m0 = blockIdx.y * 64;
  const int ty = tid >> 4, tx = tid & 15;
  const int lr = tid >> 3, lc = (tid & 7) * 4;
  float acc[4][4] = {};
  for (int k0 = 0; k0 < 128; k0 += 32) {
#pragma unroll
    for (int p = 0; p < 2; ++p) {
      int row = p * 32 + lr;
      float4 av = *reinterpret_cast<const float4*>(A + (size_t)(m0 + row) * 128 + k0 + lc);
      Ask[lc + 0][row] = av.x; Ask[lc + 1][row] = av.y;
      Ask[lc + 2][row] = av.z; Ask[lc + 3][row] = av.w;
      float4 bv = *reinterpret_cast<const float4*>(B + (size_t)(n0 + row) * 128 + k0 + lc);
      Bsk[lc + 0][row] = bv.x; Bsk[lc + 1][row] = bv.y;
      Bsk[lc + 2][row] = bv.z; Bsk[lc + 3][row] = bv.w;
    }
    __syncthreads();
#pragma unroll
    for (int kk = 0; kk < 32; ++kk) {
      float4 av = *reinterpret_cast<const float4*>(&Ask[kk][ty * 4]);
      float4 bv = *reinterpret_cast<const float4*>(&Bsk[kk][tx * 4]);
      float a[4] = {av.x, av.y, av.z, av.w};
      float b[4] = {bv.x, bv.y, bv.z, bv.w};
#pragma unroll
      for (int ii = 0; ii < 4; ++ii)
#pragma unroll
        for (int jj = 0; jj < 4; ++jj) acc[ii][jj] += a[ii] * b[jj];
    }
    __syncthreads();
  }
#pragma unroll
  for (int ii = 0; ii < 4; ++ii) {
    int row = m0 + ty * 4 + ii;
    unsigned long long key = ~0ull;
#pragma unroll
    for (int jj = 0; jj < 4; ++jj) {
      int j = n0 + tx * 4 + jj;
      float dv = cn[j] - 2.f * acc[ii][jj];   // |c|^2 - 2 z.c  (|z|^2 const per row)
      unsigned u = __float_as_uint(dv);
      u = (u & 0x80000000u) ? ~u : (u | 0x80000000u);  // order-preserving
      unsigned long long k = ((unsigned long long)u << 32) | (unsigned)j;
      key = k < key ? k : key;
    }
#pragma unroll
    for (int off = 1; off < 16; off <<= 1) {
      unsigned long long o = __shfl_xor(key, off);
      key = o < key ? o : key;
    }
    if (tx == 0) atomicMin(&keys[row], key);
  }
}

// =============== VQ part 3: gather q, loss, hh = q + pos ===============
__global__ __launch_bounds__(128) void vq_gather(
    const float* __restrict__ z, const float* __restrict__ cb,
    const float* __restrict__ pos, const unsigned long long* __restrict__ keys,
    float* __restrict__ hh, float* __restrict__ loss_acc,
    float* __restrict__ idx_out) {
  const int n = blockIdx.x, tid = threadIdx.x;
  const unsigned idx = (unsigned)(keys[n] & 0xffffffffull);
  if (tid == 0) idx_out[n] = (float)idx;
  float q = cb[(size_t)idx * 128 + tid];
  float df = q - z[(size_t)n * 128 + tid];
  hh[(size_t)n * 128 + tid] = q + pos[(n & 511) * 128 + tid];
  float part = df * df;
#pragma unroll
  for (int o = 1; o < 64; o <<= 1) part += __shfl_xor(part, o);
  __shared__ float lred[2];
  if ((tid & 63) == 0) lred[tid >> 6] = part;
  __syncthreads();
  if (tid == 0) atomicAdd(loss_acc, lred[0] + lred[1]);
}

// =============== generic fp32 GEMM: C[M,N] = A[M,K]*B[N,K]^T + bias ===============
// ACT: 0 = none, 1 = exact gelu
template <int ACT>
__global__ __launch_bounds__(256) void gemm_bias(
    const float* __restrict__ A, const float* __restrict__ B,
    const float* __restrict__ bias, float* __restrict__ C,
    int M, int N, int K) {
  __shared__ float Ask[32][68];
  __shared__ float Bsk[32][68];
  const int tid = threadIdx.x;
  const int n0 = blockIdx.x * 64, m0 = blockIdx.y * 64;
  const int ty = tid >> 4, tx = tid & 15;
  const int lr = tid >> 3, lc = (tid & 7) * 4;
  float acc[4][4] = {};
  for (int k0 = 0; k0 < K; k0 += 32) {
#pragma unroll
    for (int p = 0; p < 2; ++p) {
      int row = p * 32 + lr;
      float4 av = *reinterpret_cast<const float4*>(A + (size_t)(m0 + row) * K + k0 + lc);
      Ask[lc + 0][row] = av.x; Ask[lc + 1][row] = av.y;
      Ask[lc + 2][row] = av.z; Ask[lc + 3][row] = av.w;
      float4 bv = *reinterpret_cast<const float4*>(B + (size_t)(n0 + row) * K + k0 + lc);
      Bsk[lc + 0][row] = bv.x; Bsk[lc + 1][row] = bv.y;
      Bsk[lc + 2][row] = bv.z; Bsk[lc + 3][row] = bv.w;
    }
    __syncthreads();
#pragma unroll
    for (int kk = 0; kk < 32; ++kk) {
      float4 av = *reinterpret_cast<const float4*>(&Ask[kk][ty * 4]);
      float4 bv = *reinterpret_cast<const float4*>(&Bsk[kk][tx * 4]);
      float a[4] = {av.x, av.y, av.z, av.w};
      float b[4] = {bv.x, bv.y, bv.z, bv.w};
#pragma unroll
      for (int ii = 0; ii < 4; ++ii)
#pragma unroll
        for (int jj = 0; jj < 4; ++jj) acc[ii][jj] += a[ii] * b[jj];
    }
    __syncthreads();
  }
#pragma unroll
  for (int ii = 0; ii < 4; ++ii) {
    int row = m0 + ty * 4 + ii;
    int col = n0 + tx * 4;
    float4 bv = *reinterpret_cast<const float4*>(bias + col);
    float o[4] = {acc[ii][0] + bv.x, acc[ii][1] + bv.y, acc[ii][2] + bv.z, acc[ii][3] + bv.w};
    if (ACT == 1) {
#pragma unroll
      for (int jj = 0; jj < 4; ++jj)
        o[jj] = 0.5f * o[jj] * (1.f + erff(o[jj] * 0.7071067811865476f));
    }
    float4 ov = {o[0], o[1], o[2], o[3]};
    *reinterpret_cast<float4*>(C + (size_t)row * N + col) = ov;
  }
}

// ====== GEMM (N=128) with fused residual-add + layernorm epilogue ======
// out[r] = LN(A[r].B^T + bias + res[r]) * g + b;  tile 64 rows x 128 cols
__global__ __launch_bounds__(256) void gemm_ln(
    const float* __restrict__ A, const float* __restrict__ B,
    const float* __restrict__ bias, const float* __restrict__ res,
    const float* __restrict__ g, const float* __restrict__ bb,
    float* __restrict__ C, int K) {
  __shared__ float Ask[32][68];
  __shared__ float Bsk[32][132];
  const int tid = threadIdx.x;
  const int m0 = blockIdx.x * 64;
  const int ty = tid >> 4, tx = tid & 15;   // 4 rows x 8 cols micro-tile
  float acc[4][8] = {};
  for (int k0 = 0; k0 < K; k0 += 32) {
    {
      int lr = tid >> 3, lc = (tid & 7) * 4;
#pragma unroll
      for (int p = 0; p < 2; ++p) {
        int row = p * 32 + lr;
        float4 av = *reinterpret_cast<const float4*>(A + (size_t)(m0 + row) * K + k0 + lc);
        Ask[lc + 0][row] = av.x; Ask[lc + 1][row] = av.y;
        Ask[lc + 2][row] = av.z; Ask[lc + 3][row] = av.w;
      }
#pragma unroll
      for (int p = 0; p < 4; ++p) {
        int f = p * 256 + tid;
        int row = f >> 3, kc = (f & 7) * 4;
        float4 bv = *reinterpret_cast<const float4*>(B + (size_t)row * K + k0 + kc);
        Bsk[kc + 0][row] = bv.x; Bsk[kc + 1][row] = bv.y;
        Bsk[kc + 2][row] = bv.z; Bsk[kc + 3][row] = bv.w;
      }
    }
    __syncthreads();
#pragma unroll
    for (int kk = 0; kk < 32; ++kk) {
      float4 av = *reinterpret_cast<const float4*>(&Ask[kk][ty * 4]);
      float4 b0 = *reinterpret_cast<const float4*>(&Bsk[kk][tx * 8]);
      float4 b1 = *reinterpret_cast<const float4*>(&Bsk[kk][tx * 8 + 4]);
      float a[4] = {av.x, av.y, av.z, av.w};
      float b[8] = {b0.x, b0.y, b0.z, b0.w, b1.x, b1.y, b1.z, b1.w};
#pragma unroll
      for (int ii = 0; ii < 4; ++ii)
#pragma unroll
        for (int jj = 0; jj < 8; ++jj) acc[ii][jj] += a[ii] * b[jj];
    }
    __syncthreads();
  }
  // epilogue: + bias + residual, then per-row LN (row spread across 16 tx lanes)
  float4 bv0 = *reinterpret_cast<const float4*>(bias + tx * 8);
  float4 bv1 = *reinterpret_cast<const float4*>(bias + tx * 8 + 4);
  float4 gv0 = *reinterpret_cast<const float4*>(g + tx * 8);
  float4 gv1 = *reinterpret_cast<const float4*>(g + tx * 8 + 4);
  float4 lb0 = *reinterpret_cast<const float4*>(bb + tx * 8);
  float4 lb1 = *reinterpret_cast<const float4*>(bb + tx * 8 + 4);
  float bsv[8] = {bv0.x, bv0.y, bv0.z, bv0.w, bv1.x, bv1.y, bv1.z, bv1.w};
  float gg[8] = {gv0.x, gv0.y, gv0.z, gv0.w, gv1.x, gv1.y, gv1.z, gv1.w};
  float bbv[8] = {lb0.x, lb0.y, lb0.z, lb0.w, lb1.x, lb1.y, lb1.z, lb1.w};
#pragma unroll
  for (int ii = 0; ii < 4; ++ii) {
    int row = m0 + ty * 4 + ii;
    float4 r0 = *reinterpret_cast<const float4*>(res + (size_t)row * 128 + tx * 8);
    float4 r1 = *reinterpret_cast<const float4*>(res + (size_t)row * 128 + tx * 8 + 4);
    float rv[8] = {r0.x, r0.y, r0.z, r0.w, r1.x, r1.y, r1.z, r1.w};
    float o[8];
    float s = 0.f;
#pragma unroll
    for (int jj = 0; jj < 8; ++jj) { o[jj] = acc[ii][jj] + bsv[jj] + rv[jj]; s += o[jj]; }
#pragma unroll
    for (int off = 1; off < 16; off <<= 1) s += __shfl_xor(s, off);
    float mean = s * 0.0078125f;
    float s2 = 0.f;
#pragma unroll
    for (int jj = 0; jj < 8; ++jj) { o[jj] -= mean; s2 += o[jj] * o[jj]; }
#pragma unroll
    for (int off = 1; off < 16; off <<= 1) s2 += __shfl_xor(s2, off);
    float rstd = rsqrtf(s2 * 0.0078125f + 1e-5f);
    float4 o0 = {o[0] * rstd * gg[0] + bbv[0], o[1] * rstd * gg[1] + bbv[1],
                 o[2] * rstd * gg[2] + bbv[2], o[3] * rstd * gg[3] + bbv[3]};
    float4 o1 = {o[4] * rstd * gg[4] + bbv[4], o[5] * rstd * gg[5] + bbv[5],
                 o[6] * rstd * gg[6] + bbv[6], o[7] * rstd * gg[7] + bbv[7]};
    *reinterpret_cast<float4*>(C + (size_t)row * 128 + tx * 8) = o0;
    *reinterpret_cast<float4*>(C + (size_t)row * 128 + tx * 8 + 4) = o1;
  }
}

// =============== attention v2: register-tiled flash, block per (qt,h,b) ===============
__global__ __launch_bounds__(256) void attn2(const float* __restrict__ qkv,
                                             float* __restrict__ obuf) {
  const int qt = blockIdx.x, h = blockIdx.y, b = blockIdx.z;
  __shared__ float Qs[64][36], Ks[64][36], Vs[64][36];
  __shared__ float Ss[64][68];
  __shared__ float ms[64], ls[64], alphas[64];
  const int tid = threadIdx.x;
  const size_t tbase = (size_t)b * 512 + qt * 64;
  // load Q tile
#pragma unroll
  for (int u = 0; u < 2; ++u) {
    int f = u * 256 + tid, row = f >> 3, dc = (f & 7) * 4;
    float4 v = *reinterpret_cast<const float4*>(qkv + (tbase + row) * 384 + h * 32 + dc);
    *reinterpret_cast<float4*>(&Qs[row][dc]) = v;
  }
  if (tid < 64) { ms[tid] = -1e30f; ls[tid] = 0.f; }
  // PV thread mapping: i = tid>>3 (rows i, i+32), dg = tid&7 (4 cols)
  const int pi = tid >> 3, dg = tid & 7;
  float4 o0 = {0.f, 0.f, 0.f, 0.f}, o1 = {0.f, 0.f, 0.f, 0.f};
  const float scale = 0.17677669529663687f;  // 1/sqrt(32)
  __syncthreads();
  for (int kt = 0; kt <= qt; ++kt) {
    const size_t kbase = (size_t)b * 512 + kt * 64;
#pragma unroll
    for (int u = 0; u < 2; ++u) {
      int f = u * 256 + tid, row = f >> 3, dc = (f & 7) * 4;
      float4 kv = *reinterpret_cast<const float4*>(qkv + (kbase + row) * 384 + 128 + h * 32 + dc);
      *reinterpret_cast<float4*>(&Ks[row][dc]) = kv;
      float4 vv = *reinterpret_cast<const float4*>(qkv + (kbase + row) * 384 + 256 + h * 32 + dc);
      *reinterpret_cast<float4*>(&Vs[row][dc]) = vv;
    }
    __syncthreads();
    { // S = Q.K^T: 4x4 micro-tile, float4 over d
      const int ty = tid >> 4, tx = tid & 15;
      float s[4][4] = {};
#pragma unroll
      for (int d4 = 0; d4 < 8; ++d4) {
        float4 Qv[4], Kv[4];
#pragma unroll
        for (int ii = 0; ii < 4; ++ii) Qv[ii] = *reinterpret_cast<const float4*>(&Qs[ty * 4 + ii][d4 * 4]);
#pragma unroll
        for (int jj = 0; jj < 4; ++jj) Kv[jj] = *reinterpret_cast<const float4*>(&Ks[tx * 4 + jj][d4 * 4]);
#pragma unroll
        for (int ii = 0; ii < 4; ++ii)
#pragma unroll
          for (int jj = 0; jj < 4; ++jj)
            s[ii][jj] += Qv[ii].x * Kv[jj].x + Qv[ii].y * Kv[jj].y +
                         Qv[ii].z * Kv[jj].z + Qv[ii].w * Kv[jj].w;
      }
#pragma unroll
      for (int ii = 0; ii < 4; ++ii)
#pragma unroll
        for (int jj = 0; jj < 4; ++jj) {
          float v = s[ii][jj] * scale;
          if (kt == qt && (tx * 4 + jj) > (ty * 4 + ii)) v += -1e9f;
          Ss[ty * 4 + ii][tx * 4 + jj] = v;
        }
    }
    __syncthreads();
    { // online softmax: i = tid>>2, quarter q = tid&3 scans 16 j's
      const int i = tid >> 2, q = tid & 3;
      float mx = -3.4e38f;
      float4 pv[4];
#pragma unroll
      for (int t = 0; t < 4; ++t) {
        pv[t] = *reinterpret_cast<const float4*>(&Ss[i][q * 16 + t * 4]);
        mx = fmaxf(mx, fmaxf(fmaxf(pv[t].x, pv[t].y), fmaxf(pv[t].z, pv[t].w)));
      }
      mx = fmaxf(mx, __shfl_xor(mx, 1));
      mx = fmaxf(mx, __shfl_xor(mx, 2));
      float mold = ms[i];
      mx = fmaxf(mx, mold);
      float sum = 0.f;
#pragma unroll
      for (int t = 0; t < 4; ++t) {
        pv[t].x = __expf(pv[t].x - mx); pv[t].y = __expf(pv[t].y - mx);
        pv[t].z = __expf(pv[t].z - mx); pv[t].w = __expf(pv[t].w - mx);
        sum += pv[t].x + pv[t].y + pv[t].z + pv[t].w;
        *reinterpret_cast<float4*>(&Ss[i][q * 16 + t * 4]) = pv[t];
      }
      sum += __shfl_xor(sum, 1);
      sum += __shfl_xor(sum, 2);
      if (q == 0) {
        float alpha = __expf(mold - mx);
        ls[i] = ls[i] * alpha + sum;
        ms[i] = mx;
        alphas[i] = alpha;
      }
    }
    __syncthreads();
    { // O = alpha*O + P.V : rows pi, pi+32, cols dg*4..+4
      float a0 = alphas[pi], a1 = alphas[pi + 32];
      o0.x *= a0; o0.y *= a0; o0.z *= a0; o0.w *= a0;
      o1.x *= a1; o1.y *= a1; o1.z *= a1; o1.w *= a1;
#pragma unroll 4
      for (int j = 0; j < 64; ++j) {
        float p0 = Ss[pi][j], p1 = Ss[pi + 32][j];
        float4 vv = *reinterpret_cast<const float4*>(&Vs[j][dg * 4]);
        o0.x += p0 * vv.x; o0.y += p0 * vv.y; o0.z += p0 * vv.z; o0.w += p0 * vv.w;
        o1.x += p1 * vv.x; o1.y += p1 * vv.y; o1.z += p1 * vv.z; o1.w += p1 * vv.w;
      }
    }
    __syncthreads();
  }
  float inv0 = 1.f / ls[pi], inv1 = 1.f / ls[pi + 32];
  o0.x *= inv0; o0.y *= inv0; o0.z *= inv0; o0.w *= inv0;
  o1.x *= inv1; o1.y *= inv1; o1.z *= inv1; o1.w *= inv1;
  *reinterpret_cast<float4*>(obuf + (tbase + pi) * 128 + h * 32 + dg * 4) = o0;
  *reinterpret_cast<float4*>(obuf + (tbase + pi + 32) * 128 + h * 32 + dg * 4) = o1;
}

// =============== plain layernorm (final) ===============
__global__ __launch_bounds__(128) void resid_ln(
    const float* __restrict__ in, const float* __restrict__ r,
    float* __restrict__ outp, const float* __restrict__ g,
    const float* __restrict__ bb) {
  const int t = blockIdx.x, d = threadIdx.x;
  const size_t base = (size_t)t * 128;
  float x = in[base + d];
  if (r) x += r[base + d];
  float s = x;
#pragma unroll
  for (int o = 1; o < 64; o <<= 1) s += __shfl_xor(s, o);
  __shared__ float red[2], red2[2];
  if ((d & 63) == 0) red[d >> 6] = s;
  __syncthreads();
  float mean = (red[0] + red[1]) * 0.0078125f;
  float v = x - mean;
  float s2 = v * v;
#pragma unroll
  for (int o = 1; o < 64; o <<= 1) s2 += __shfl_xor(s2, o);
  if ((d & 63) == 0) red2[d >> 6] = s2;
  __syncthreads();
  float var = (red2[0] + red2[1]) * 0.0078125f;
  outp[base + d] = v * rsqrtf(var + 1e-5f) * g[d] + bb[d];
}

__global__ void loss_finalize(const float* __restrict__ loss, float* __restrict__ out) {
  out[0] = 1.25f * loss[0] / 2097152.0f;   // (1+0.25)*mean((q-z)^2)
}

extern "C" void kernel_launch(void* const* d_in, const int* in_sizes, int n_in,
                              void* d_out, int out_size, void* d_ws, size_t ws_size,
                              hipStream_t stream) {
  const float* x      = (const float*)d_in[0];
  const float* enc_w1 = (const float*)d_in[1];
  const float* enc_b1 = (const float*)d_in[2];
  const float* enc_w2 = (const float*)d_in[3];
  const float* enc_b2 = (const float*)d_in[4];
  const float* enc_w3 = (const float*)d_in[5];
  const float* enc_b3 = (const float*)d_in[6];
  const float* res_w1 = (const float*)d_in[7];
  const float* res_b1 = (const float*)d_in[8];
  const float* res_w2 = (const float*)d_in[9];
  const float* res_b2 = (const float*)d_in[10];
  const float* pre_w  = (const float*)d_in[11];
  const float* pre_b  = (const float*)d_in[12];
  const float* codebook = (const float*)d_in[13];
  const float* pos_emb  = (const float*)d_in[14];
  const float* qkv_w  = (const float*)d_in[15];
  const float* qkv_b  = (const float*)d_in[16];
  const float* proj_w = (const float*)d_in[17];
  const float* proj_b = (const float*)d_in[18];
  const float* ln1_g  = (const float*)d_in[19];
  const float* ln1_b  = (const float*)d_in[20];
  const float* ln2_g  = (const float*)d_in[21];
  const float* ln2_b  = (const float*)d_in[22];
  const float* ffn_w1 = (const float*)d_in[23];
  const float* ffn_b1 = (const float*)d_in[24];
  const float* ffn_w2 = (const float*)d_in[25];
  const float* ffn_b2 = (const float*)d_in[26];
  const float* fin_g  = (const float*)d_in[27];
  const float* fin_b  = (const float*)d_in[28];
  const float* head_w = (const float*)d_in[29];
  const float* head_b = (const float*)d_in[30];

  float* out = (float*)d_out;
  float* ws  = (float*)d_ws;

  // ws: hh [2M] | hhln [2M] | loss [1] pad | keys [16384 u64] | cn [1024]
  float* hh   = ws;
  float* hhln = ws + (1 << 21);
  float* loss = ws + (1 << 22);
  unsigned long long* keys = (unsigned long long*)(ws + (1 << 22) + 16);
  float* cn = ws + (1 << 22) + 16 + 2 * NPATCH;
  // d_out scratch overlay (dead before head GEMM)
  float* zf   = out + Z_OFF;
  float* qkvb = out + QKV_OFF;
  float* fbuf = out + QKV_OFF;
  float* oatt = out + OATT_OFF;

  hipMemsetAsync(loss, 0, sizeof(float), stream);
  hipMemsetAsync(keys, 0xFF, NPATCH * sizeof(unsigned long long), stream);

  encoder2<<<512, 256, 0, stream>>>(x, enc_w1, enc_b1, enc_w2, enc_b2,
                                    enc_w3, enc_b3, res_w1, res_b1,
                                    res_w2, res_b2, pre_w, pre_b, zf);
  cb_norms<<<4, 256, 0, stream>>>(codebook, cn);
  vq_argmin<<<dim3(16, 256), 256, 0, stream>>>(zf, codebook, cn, keys);
  vq_gather<<<NPATCH, 128, 0, stream>>>(zf, codebook, pos_emb, keys, hh, loss,
                                        out + IDX_OFF);
  for (int i = 0; i < 4; ++i) {
    gemm_bias<0><<<dim3(6, 256), 256, 0, stream>>>(hh, qkv_w + i * 49152,
                                                   qkv_b + i * 384, qkvb,
                                                   NPATCH, 384, 128);
    attn2<<<dim3(8, 4, 32), 256, 0, stream>>>(qkvb, oatt);
    gemm_ln<<<256, 256, 0, stream>>>(oatt, proj_w + i * 16384, proj_b + i * 128,
                                     hh, ln1_g + i * 128, ln1_b + i * 128, hh, 128);
    gemm_bias<1><<<dim3(4, 256), 256, 0, stream>>>(hh, ffn_w1 + i * 32768,
                                                   ffn_b1 + i * 256, fbuf,
                                                   NPATCH, 256, 128);
    gemm_ln<<<256, 256, 0, stream>>>(fbuf, ffn_w2 + i * 32768, ffn_b2 + i * 128,
                                     hh, ln2_g + i * 128, ln2_b + i * 128, hh, 256);
  }
  resid_ln<<<NPATCH, 128, 0, stream>>>(hh, nullptr, hhln, fin_g, fin_b);
  gemm_bias<0><<<dim3(16, 256), 256, 0, stream>>>(hhln, head_w, head_b, out,
                                                  NPATCH, 1024, 128);
  loss_finalize<<<1, 1, 0, stream>>>(loss, out + LOSS_OFF);
}

// Round 3
// 1033.438 us; speedup vs baseline: 3.2334x; 1.3768x over previous
//
#include <hip/hip_runtime.h>
#include <math.h>

// ---- problem constants ----
#define NPATCH 16384          // B * T / P
#define SEQ    512            // T / P
#define LOSS_OFF 16777216
#define IDX_OFF  16777217

// d_out scratch overlay (floats) — all dead before head GEMM writes logits
#define Z_OFF      0          // z_flat [16384,128]
#define QKV_OFF    2097152    // qkv [16384,384] (reused as F [16384,256])
#define OATT_OFF   8388608    // attn out [16384,128]

typedef short bf8 __attribute__((ext_vector_type(8)));    // 8 bf16 (4 VGPRs)
typedef float f32x4 __attribute__((ext_vector_type(4)));  // MFMA acc

__device__ inline short f2bf(float x) {          // fp32 -> bf16 RNE
  unsigned u = __float_as_uint(x);
  u += 0x7fffu + ((u >> 16) & 1u);
  return (short)(u >> 16);
}
__device__ inline float bf2f(short h) {
  return __uint_as_float(((unsigned)(unsigned short)h) << 16);
}

// =============== encoder v2: 32 patches per block, reg accumulators ===============
__global__ __launch_bounds__(256) void encoder2(
    const float* __restrict__ x,
    const float* __restrict__ w1, const float* __restrict__ b1,
    const float* __restrict__ w2, const float* __restrict__ b2,
    const float* __restrict__ w3, const float* __restrict__ b3,
    const float* __restrict__ rw1, const float* __restrict__ rb1,
    const float* __restrict__ rw2, const float* __restrict__ rb2,
    const float* __restrict__ pw, const float* __restrict__ pb,
    float* __restrict__ z) {
  __shared__ float ar[16384];
  float* H1 = ar;
  float* H2 = ar + 8192;
  float* XS = ar + 8192;
  float* H3 = ar;
  float* T1 = ar + 8192;
  const int blk = blockIdx.x, tid = threadIdx.x;
  const int n = tid & 31, g = tid >> 5;

  if (tid < 128) {
    int p = tid >> 2, i = (tid & 3) * 4;
    float4 v = *reinterpret_cast<const float4*>(x + ((size_t)blk * 32 + p) * 16 + i);
    XS[(i + 0) * 32 + p] = v.x; XS[(i + 1) * 32 + p] = v.y;
    XS[(i + 2) * 32 + p] = v.z; XS[(i + 3) * 32 + p] = v.w;
  }
  __syncthreads();
  { // conv1
    float xv[16];
#pragma unroll
    for (int i = 0; i < 16; ++i) xv[i] = XS[i * 32 + n];
#pragma unroll
    for (int c = 0; c < 4; ++c) {
      int ch = g * 4 + c;
      float4 wv = *reinterpret_cast<const float4*>(w1 + ch * 4);
      float bs = b1[ch];
      float w[4] = {wv.x, wv.y, wv.z, wv.w};
#pragma unroll
      for (int l = 0; l < 8; ++l) {
        float acc = bs;
#pragma unroll
        for (int kk = 0; kk < 4; ++kk) {
          int xi = 2 * l + kk - 1;
          if (xi >= 0 && xi < 16) acc += xv[xi] * w[kk];
        }
        H1[(ch * 8 + l) * 32 + n] = fmaxf(acc, 0.f);
      }
    }
  }
  __syncthreads();
  { // conv2
    float acc[8][4];
#pragma unroll
    for (int c = 0; c < 8; ++c) {
      float bs = b2[g * 8 + c];
#pragma unroll
      for (int l = 0; l < 4; ++l) acc[c][l] = bs;
    }
    for (int ci = 0; ci < 32; ++ci) {
      float hv[8];
#pragma unroll
      for (int xi = 0; xi < 8; ++xi) hv[xi] = H1[(ci * 8 + xi) * 32 + n];
#pragma unroll
      for (int c = 0; c < 8; ++c) {
        float4 wv = *reinterpret_cast<const float4*>(w2 + ((g * 8 + c) * 32 + ci) * 4);
        float w[4] = {wv.x, wv.y, wv.z, wv.w};
#pragma unroll
        for (int l = 0; l < 4; ++l)
#pragma unroll
          for (int kk = 0; kk < 4; ++kk) {
            int xi = 2 * l + kk - 1;
            if (xi >= 0 && xi < 8) acc[c][l] += hv[xi] * w[kk];
          }
      }
    }
    __syncthreads();
#pragma unroll
    for (int c = 0; c < 8; ++c)
#pragma unroll
      for (int l = 0; l < 4; ++l)
        H2[((g * 8 + c) * 4 + l) * 32 + n] = fmaxf(acc[c][l], 0.f);
  }
  __syncthreads();
  { // conv3
    float acc[8][4];
#pragma unroll
    for (int c = 0; c < 8; ++c) {
      float bs = b3[g * 8 + c];
#pragma unroll
      for (int l = 0; l < 4; ++l) acc[c][l] = bs;
    }
    for (int ci = 0; ci < 64; ++ci) {
      float hv[4];
#pragma unroll
      for (int xi = 0; xi < 4; ++xi) hv[xi] = H2[(ci * 4 + xi) * 32 + n];
#pragma unroll
      for (int c = 0; c < 8; ++c) {
        const float* wp = w3 + ((g * 8 + c) * 64 + ci) * 3;
        float w0 = wp[0], w1v = wp[1], w2v = wp[2];
#pragma unroll
        for (int l = 0; l < 4; ++l) {
          if (l - 1 >= 0) acc[c][l] += hv[l - 1] * w0;
          acc[c][l] += hv[l] * w1v;
          if (l + 1 < 4) acc[c][l] += hv[l + 1] * w2v;
        }
      }
    }
    __syncthreads();
#pragma unroll
    for (int c = 0; c < 8; ++c)
#pragma unroll
      for (int l = 0; l < 4; ++l)
        H3[((g * 8 + c) * 4 + l) * 32 + n] = acc[c][l];
  }
  __syncthreads();
  for (int rl = 0; rl < 2; ++rl) {
    {
      float acc[4][4];
#pragma unroll
      for (int c = 0; c < 4; ++c) {
        float bs = rb1[rl * 32 + g * 4 + c];
#pragma unroll
        for (int l = 0; l < 4; ++l) acc[c][l] = bs;
      }
      for (int ci = 0; ci < 64; ++ci) {
        float hv[4];
#pragma unroll
        for (int xi = 0; xi < 4; ++xi) hv[xi] = fmaxf(H3[(ci * 4 + xi) * 32 + n], 0.f);
#pragma unroll
        for (int c = 0; c < 4; ++c) {
          const float* wp = rw1 + ((rl * 32 + g * 4 + c) * 64 + ci) * 3;
          float w0 = wp[0], w1v = wp[1], w2v = wp[2];
#pragma unroll
          for (int l = 0; l < 4; ++l) {
            if (l - 1 >= 0) acc[c][l] += hv[l - 1] * w0;
            acc[c][l] += hv[l] * w1v;
            if (l + 1 < 4) acc[c][l] += hv[l + 1] * w2v;
          }
        }
      }
      __syncthreads();
#pragma unroll
      for (int c = 0; c < 4; ++c)
#pragma unroll
        for (int l = 0; l < 4; ++l)
          T1[((g * 4 + c) * 4 + l) * 32 + n] = acc[c][l];
    }
    __syncthreads();
    {
      float acc[8][4];
#pragma unroll
      for (int c = 0; c < 8; ++c) {
        float bs = rb2[rl * 64 + g * 8 + c];
#pragma unroll
        for (int l = 0; l < 4; ++l) acc[c][l] = bs;
      }
      for (int ci = 0; ci < 32; ++ci) {
        float tv[4];
#pragma unroll
        for (int l = 0; l < 4; ++l) tv[l] = fmaxf(T1[(ci * 4 + l) * 32 + n], 0.f);
#pragma unroll
        for (int c = 0; c < 8; ++c) {
          float w = rw2[(rl * 64 + g * 8 + c) * 32 + ci];
#pragma unroll
          for (int l = 0; l < 4; ++l) acc[c][l] += tv[l] * w;
        }
      }
#pragma unroll
      for (int c = 0; c < 8; ++c)
#pragma unroll
        for (int l = 0; l < 4; ++l)
          H3[((g * 8 + c) * 4 + l) * 32 + n] += acc[c][l];
    }
    __syncthreads();
  }
  {
    float acc[4][4];
#pragma unroll
    for (int c = 0; c < 4; ++c) {
      float bs = pb[g * 4 + c];
#pragma unroll
      for (int l = 0; l < 4; ++l) acc[c][l] = bs;
    }
    for (int ci = 0; ci < 64; ++ci) {
      float hv[4];
#pragma unroll
      for (int l = 0; l < 4; ++l) hv[l] = fmaxf(H3[(ci * 4 + l) * 32 + n], 0.f);
#pragma unroll
      for (int c = 0; c < 4; ++c) {
        float w = pw[(g * 4 + c) * 64 + ci];
#pragma unroll
        for (int l = 0; l < 4; ++l) acc[c][l] += hv[l] * w;
      }
    }
#pragma unroll
    for (int c = 0; c < 4; ++c) {
      float4 v = {acc[c][0], acc[c][1], acc[c][2], acc[c][3]};
      *reinterpret_cast<float4*>(z + ((size_t)blk * 32 + n) * 128 + (g * 4 + c) * 4) = v;
    }
  }
}

// =============== VQ part 1: codebook squared norms ===============
__global__ __launch_bounds__(256) void cb_norms(const float* __restrict__ cb,
                                                float* __restrict__ cn) {
  int j = blockIdx.x * 256 + threadIdx.x;
  const float4* cp = reinterpret_cast<const float4*>(cb + (size_t)j * 128);
  float s = 0.f;
#pragma unroll
  for (int k = 0; k < 32; ++k) {
    float4 c = cp[k];
    s += c.x * c.x + c.y * c.y + c.z * c.z + c.w * c.w;
  }
  cn[j] = s;
}

// =============== VQ part 2: fp32 GEMM z.cb^T with fused argmin epilogue ===============
__global__ __launch_bounds__(256) void vq_argmin(
    const float* __restrict__ A, const float* __restrict__ B,
    const float* __restrict__ cn, unsigned long long* __restrict__ keys) {
  __shared__ float Ask[32][68];
  __shared__ float Bsk[32][68];
  const int tid = threadIdx.x;
  const int n0 = blockIdx.x * 64, m0 = blockIdx.y * 64;
  const int ty = tid >> 4, tx = tid & 15;
  const int lr = tid >> 3, lc = (tid & 7) * 4;
  float acc[4][4] = {};
  for (int k0 = 0; k0 < 128; k0 += 32) {
#pragma unroll
    for (int p = 0; p < 2; ++p) {
      int row = p * 32 + lr;
      float4 av = *reinterpret_cast<const float4*>(A + (size_t)(m0 + row) * 128 + k0 + lc);
      Ask[lc + 0][row] = av.x; Ask[lc + 1][row] = av.y;
      Ask[lc + 2][row] = av.z; Ask[lc + 3][row] = av.w;
      float4 bv = *reinterpret_cast<const float4*>(B + (size_t)(n0 + row) * 128 + k0 + lc);
      Bsk[lc + 0][row] = bv.x; Bsk[lc + 1][row] = bv.y;
      Bsk[lc + 2][row] = bv.z; Bsk[lc + 3][row] = bv.w;
    }
    __syncthreads();
#pragma unroll
    for (int kk = 0; kk < 32; ++kk) {
      float4 av = *reinterpret_cast<const float4*>(&Ask[kk][ty * 4]);
      float4 bv = *reinterpret_cast<const float4*>(&Bsk[kk][tx * 4]);
      float a[4] = {av.x, av.y, av.z, av.w};
      float b[4] = {bv.x, bv.y, bv.z, bv.w};
#pragma unroll
      for (int ii = 0; ii < 4; ++ii)
#pragma unroll
        for (int jj = 0; jj < 4; ++jj) acc[ii][jj] += a[ii] * b[jj];
    }
    __syncthreads();
  }
#pragma unroll
  for (int ii = 0; ii < 4; ++ii) {
    int row = m0 + ty * 4 + ii;
    unsigned long long key = ~0ull;
#pragma unroll
    for (int jj = 0; jj < 4; ++jj) {
      int j = n0 + tx * 4 + jj;
      float dv = cn[j] - 2.f * acc[ii][jj];
      unsigned u = __float_as_uint(dv);
      u = (u & 0x80000000u) ? ~u : (u | 0x80000000u);
      unsigned long long k = ((unsigned long long)u << 32) | (unsigned)j;
      key = k < key ? k : key;
    }
#pragma unroll
    for (int off = 1; off < 16; off <<= 1) {
      unsigned long long o = __shfl_xor(key, off);
      key = o < key ? o : key;
    }
    if (tx == 0) atomicMin(&keys[row], key);
  }
}

// =============== VQ part 3: gather q, loss partials, hh = q + pos ===============
__global__ __launch_bounds__(256) void vq_gather2(
    const float* __restrict__ z, const float* __restrict__ cb,
    const float* __restrict__ pos, const unsigned long long* __restrict__ keys,
    float* __restrict__ hh, float* __restrict__ lpart,
    float* __restrict__ idx_out) {
  const int blk = blockIdx.x, tid = threadIdx.x;
  __shared__ int sidx[8];
  if (tid < 8) {
    unsigned long long k = keys[blk * 8 + tid];
    int id = (int)(unsigned)(k & 0xffffffffull);
    sidx[tid] = id;
    idx_out[blk * 8 + tid] = (float)id;
  }
  __syncthreads();
  const int p = tid >> 5, d = tid & 31;
  const size_t n = (size_t)blk * 8 + p;
  const int idx = sidx[p];
  float4 q = *reinterpret_cast<const float4*>(cb + (size_t)idx * 128 + d * 4);
  float4 zv = *reinterpret_cast<const float4*>(z + n * 128 + d * 4);
  float4 pv = *reinterpret_cast<const float4*>(pos + (size_t)(n & 511) * 128 + d * 4);
  float4 hv = {q.x + pv.x, q.y + pv.y, q.z + pv.z, q.w + pv.w};
  *reinterpret_cast<float4*>(hh + n * 128 + d * 4) = hv;
  float dx = q.x - zv.x, dy = q.y - zv.y, dz = q.z - zv.z, dw = q.w - zv.w;
  float part = dx * dx + dy * dy + dz * dz + dw * dw;
#pragma unroll
  for (int o = 1; o < 64; o <<= 1) part += __shfl_xor(part, o);
  __shared__ float lred[4];
  if ((tid & 63) == 0) lred[tid >> 6] = part;
  __syncthreads();
  if (tid == 0) lpart[blk] = lred[0] + lred[1] + lred[2] + lred[3];
}

// ========== split-bf16 MFMA GEMM: C[M,N] = A[M,128]*B[N,128]^T + bias ==========
// tile 128(M) x 64(N), K=128.  ACT: 0=none, 1=exact gelu.
// LDS row stride 40 shorts (80 B) keeps b128 alignment, ~2-way banks (free).
template <int ACT>
__global__ __launch_bounds__(256) void mgemm_bias(
    const float* __restrict__ A, const float* __restrict__ B,
    const float* __restrict__ bias, float* __restrict__ C, int N) {
  __shared__ short Ah[128 * 40], Al[128 * 40], Bh[64 * 40], Bl[64 * 40];
  const int tid = threadIdx.x;
  const int n0 = blockIdx.x * 64, m0 = blockIdx.y * 128;
  const int wave = tid >> 6, lane = tid & 63, quad = lane >> 4, l15 = lane & 15;
  const f32x4 z4 = {0.f, 0.f, 0.f, 0.f};
  f32x4 acc[2][4];
#pragma unroll
  for (int i = 0; i < 2; ++i)
#pragma unroll
    for (int j = 0; j < 4; ++j) acc[i][j] = z4;

  for (int k0 = 0; k0 < 128; k0 += 32) {
    { // stage A: 128 rows x 32 k, 2 threads/row (16 floats each)
      int r = tid >> 1, h = tid & 1;
      const float4* ap = reinterpret_cast<const float4*>(A + (size_t)(m0 + r) * 128 + k0 + h * 16);
      float4 v[4] = {ap[0], ap[1], ap[2], ap[3]};
      const float* vf = reinterpret_cast<const float*>(v);
      bf8 h0, h1, l0, l1;
#pragma unroll
      for (int q = 0; q < 8; ++q) {
        short hb_ = f2bf(vf[q]);      h0[q] = hb_; l0[q] = f2bf(vf[q] - bf2f(hb_));
        short hb2 = f2bf(vf[8 + q]);  h1[q] = hb2; l1[q] = f2bf(vf[8 + q] - bf2f(hb2));
      }
      *reinterpret_cast<bf8*>(&Ah[r * 40 + h * 16]) = h0;
      *reinterpret_cast<bf8*>(&Ah[r * 40 + h * 16 + 8]) = h1;
      *reinterpret_cast<bf8*>(&Al[r * 40 + h * 16]) = l0;
      *reinterpret_cast<bf8*>(&Al[r * 40 + h * 16 + 8]) = l1;
      // stage B: 64 rows x 32 k, 4 threads/row (8 floats each)
      int rb = tid >> 2, hb = tid & 3;
      const float4* bp = reinterpret_cast<const float4*>(B + (size_t)(n0 + rb) * 128 + k0 + hb * 8);
      float4 w0 = bp[0], w1 = bp[1];
      const float* wf0 = reinterpret_cast<const float*>(&w0);
      const float* wf1 = reinterpret_cast<const float*>(&w1);
      bf8 bh_, bl_;
#pragma unroll
      for (int q = 0; q < 4; ++q) {
        short t0 = f2bf(wf0[q]); bh_[q] = t0;     bl_[q] = f2bf(wf0[q] - bf2f(t0));
        short t1 = f2bf(wf1[q]); bh_[4 + q] = t1; bl_[4 + q] = f2bf(wf1[q] - bf2f(t1));
      }
      *reinterpret_cast<bf8*>(&Bh[rb * 40 + hb * 8]) = bh_;
      *reinterpret_cast<bf8*>(&Bl[rb * 40 + hb * 8]) = bl_;
    }
    __syncthreads();
    bf8 af[2], afl[2], bfh[4], bfl[4];
#pragma unroll
    for (int mt = 0; mt < 2; ++mt) {
      int row = wave * 32 + mt * 16 + l15;
      af[mt]  = *reinterpret_cast<const bf8*>(&Ah[row * 40 + quad * 8]);
      afl[mt] = *reinterpret_cast<const bf8*>(&Al[row * 40 + quad * 8]);
    }
#pragma unroll
    for (int nt = 0; nt < 4; ++nt) {
      int row = nt * 16 + l15;
      bfh[nt] = *reinterpret_cast<const bf8*>(&Bh[row * 40 + quad * 8]);
      bfl[nt] = *reinterpret_cast<const bf8*>(&Bl[row * 40 + quad * 8]);
    }
#pragma unroll
    for (int nt = 0; nt < 4; ++nt)
#pragma unroll
      for (int mt = 0; mt < 2; ++mt)
        acc[mt][nt] = __builtin_amdgcn_mfma_f32_16x16x32_bf16(af[mt], bfh[nt], acc[mt][nt], 0, 0, 0);
#pragma unroll
    for (int nt = 0; nt < 4; ++nt)
#pragma unroll
      for (int mt = 0; mt < 2; ++mt)
        acc[mt][nt] = __builtin_amdgcn_mfma_f32_16x16x32_bf16(af[mt], bfl[nt], acc[mt][nt], 0, 0, 0);
#pragma unroll
    for (int nt = 0; nt < 4; ++nt)
#pragma unroll
      for (int mt = 0; mt < 2; ++mt)
        acc[mt][nt] = __builtin_amdgcn_mfma_f32_16x16x32_bf16(afl[mt], bfh[nt], acc[mt][nt], 0, 0, 0);
    __syncthreads();
  }
  // epilogue: C/D layout col=lane&15, row=quad*4+reg
#pragma unroll
  for (int nt = 0; nt < 4; ++nt) {
    int col = n0 + nt * 16 + l15;
    float bv = bias[col];
#pragma unroll
    for (int mt = 0; mt < 2; ++mt) {
      int rbase = m0 + wave * 32 + mt * 16 + quad * 4;
#pragma unroll
      for (int r = 0; r < 4; ++r) {
        float v = acc[mt][nt][r] + bv;
        if (ACT == 1) v = 0.5f * v * (1.f + erff(v * 0.7071067811865476f));
        C[(size_t)(rbase + r) * N + col] = v;
      }
    }
  }
}

// ==== split-bf16 MFMA GEMM + residual + LN: out = LN(A.B^T + bias + res)*g + b ====
// tile 64(M) x 128(N=full row).  K template (128 or 256).
template <int K>
__global__ __launch_bounds__(256) void mgemm_ln(
    const float* __restrict__ A, const float* __restrict__ B,
    const float* __restrict__ bias, const float* __restrict__ res,
    const float* __restrict__ g, const float* __restrict__ bb,
    float* __restrict__ C) {
  __shared__ short Ah[64 * 40], Al[64 * 40], Bh[128 * 40], Bl[128 * 40];
  const int tid = threadIdx.x;
  const int m0 = blockIdx.x * 64;
  const int wave = tid >> 6, lane = tid & 63, quad = lane >> 4, l15 = lane & 15;
  const f32x4 z4 = {0.f, 0.f, 0.f, 0.f};
  f32x4 acc[8];
#pragma unroll
  for (int j = 0; j < 8; ++j) acc[j] = z4;

  for (int k0 = 0; k0 < K; k0 += 32) {
    { // stage A: 64 rows, 4 threads/row (8 floats)
      int ra = tid >> 2, ha = tid & 3;
      const float4* ap = reinterpret_cast<const float4*>(A + (size_t)(m0 + ra) * K + k0 + ha * 8);
      float4 v0 = ap[0], v1 = ap[1];
      const float* f0 = reinterpret_cast<const float*>(&v0);
      const float* f1 = reinterpret_cast<const float*>(&v1);
      bf8 ah_, al_;
#pragma unroll
      for (int q = 0; q < 4; ++q) {
        short t0 = f2bf(f0[q]); ah_[q] = t0;     al_[q] = f2bf(f0[q] - bf2f(t0));
        short t1 = f2bf(f1[q]); ah_[4 + q] = t1; al_[4 + q] = f2bf(f1[q] - bf2f(t1));
      }
      *reinterpret_cast<bf8*>(&Ah[ra * 40 + ha * 8]) = ah_;
      *reinterpret_cast<bf8*>(&Al[ra * 40 + ha * 8]) = al_;
      // stage B: 128 rows, 2 threads/row (16 floats)
      int rb = tid >> 1, hb = tid & 1;
      const float4* bp = reinterpret_cast<const float4*>(B + (size_t)rb * K + k0 + hb * 16);
      float4 w[4] = {bp[0], bp[1], bp[2], bp[3]};
      const float* wf = reinterpret_cast<const float*>(w);
      bf8 h0, h1, l0, l1;
#pragma unroll
      for (int q = 0; q < 8; ++q) {
        short t0 = f2bf(wf[q]);     h0[q] = t0; l0[q] = f2bf(wf[q] - bf2f(t0));
        short t1 = f2bf(wf[8 + q]); h1[q] = t1; l1[q] = f2bf(wf[8 + q] - bf2f(t1));
      }
      *reinterpret_cast<bf8*>(&Bh[rb * 40 + hb * 16]) = h0;
      *reinterpret_cast<bf8*>(&Bh[rb * 40 + hb * 16 + 8]) = h1;
      *reinterpret_cast<bf8*>(&Bl[rb * 40 + hb * 16]) = l0;
      *reinterpret_cast<bf8*>(&Bl[rb * 40 + hb * 16 + 8]) = l1;
    }
    __syncthreads();
    bf8 af, afl, bfh[8], bfl[8];
    {
      int row = wave * 16 + l15;
      af  = *reinterpret_cast<const bf8*>(&Ah[row * 40 + quad * 8]);
      afl = *reinterpret_cast<const bf8*>(&Al[row * 40 + quad * 8]);
    }
#pragma unroll
    for (int nt = 0; nt < 8; ++nt) {
      int row = nt * 16 + l15;
      bfh[nt] = *reinterpret_cast<const bf8*>(&Bh[row * 40 + quad * 8]);
      bfl[nt] = *reinterpret_cast<const bf8*>(&Bl[row * 40 + quad * 8]);
    }
#pragma unroll
    for (int nt = 0; nt < 8; ++nt)
      acc[nt] = __builtin_amdgcn_mfma_f32_16x16x32_bf16(af, bfh[nt], acc[nt], 0, 0, 0);
#pragma unroll
    for (int nt = 0; nt < 8; ++nt)
      acc[nt] = __builtin_amdgcn_mfma_f32_16x16x32_bf16(af, bfl[nt], acc[nt], 0, 0, 0);
#pragma unroll
    for (int nt = 0; nt < 8; ++nt)
      acc[nt] = __builtin_amdgcn_mfma_f32_16x16x32_bf16(afl, bfh[nt], acc[nt], 0, 0, 0);
    __syncthreads();
  }
  // epilogue: row = m0 + wave*16 + quad*4 + r; its 128 cols = 8 nt x 16 lanes (l15)
  float bias_v[8], g_v[8], bb_v[8];
#pragma unroll
  for (int nt = 0; nt < 8; ++nt) {
    int col = nt * 16 + l15;
    bias_v[nt] = bias[col]; g_v[nt] = g[col]; bb_v[nt] = bb[col];
  }
  const int rbase = m0 + wave * 16 + quad * 4;
#pragma unroll
  for (int r = 0; r < 4; ++r) {
    const int row = rbase + r;
    float ov[8];
    float s = 0.f;
#pragma unroll
    for (int nt = 0; nt < 8; ++nt) {
      ov[nt] = acc[nt][r] + bias_v[nt] + res[(size_t)row * 128 + nt * 16 + l15];
      s += ov[nt];
    }
    s += __shfl_xor(s, 1); s += __shfl_xor(s, 2);
    s += __shfl_xor(s, 4); s += __shfl_xor(s, 8);   // 16-lane group = this row
    float mean = s * 0.0078125f;
    float s2 = 0.f;
#pragma unroll
    for (int nt = 0; nt < 8; ++nt) { ov[nt] -= mean; s2 += ov[nt] * ov[nt]; }
    s2 += __shfl_xor(s2, 1); s2 += __shfl_xor(s2, 2);
    s2 += __shfl_xor(s2, 4); s2 += __shfl_xor(s2, 8);
    float rstd = rsqrtf(s2 * 0.0078125f + 1e-5f);
#pragma unroll
    for (int nt = 0; nt < 8; ++nt)
      C[(size_t)row * 128 + nt * 16 + l15] = ov[nt] * rstd * g_v[nt] + bb_v[nt];
  }
}

// =============== attention: register-tiled flash, block per (qt,h,b) ===============
__global__ __launch_bounds__(256) void attn2(const float* __restrict__ qkv,
                                             float* __restrict__ obuf) {
  const int qt = blockIdx.x, h = blockIdx.y, b = blockIdx.z;
  __shared__ float Qs[64][36], Ks[64][36], Vs[64][36];
  __shared__ float Ss[64][68];
  __shared__ float ms[64], ls[64], alphas[64];
  const int tid = threadIdx.x;
  const size_t tbase = (size_t)b * 512 + qt * 64;
#pragma unroll
  for (int u = 0; u < 2; ++u) {
    int f = u * 256 + tid, row = f >> 3, dc = (f & 7) * 4;
    float4 v = *reinterpret_cast<const float4*>(qkv + (tbase + row) * 384 + h * 32 + dc);
    *reinterpret_cast<float4*>(&Qs[row][dc]) = v;
  }
  if (tid < 64) { ms[tid] = -1e30f; ls[tid] = 0.f; }
  const int pi = tid >> 3, dg = tid & 7;
  float4 o0 = {0.f, 0.f, 0.f, 0.f}, o1 = {0.f, 0.f, 0.f, 0.f};
  const float scale = 0.17677669529663687f;
  __syncthreads();
  for (int kt = 0; kt <= qt; ++kt) {
    const size_t kbase = (size_t)b * 512 + kt * 64;
#pragma unroll
    for (int u = 0; u < 2; ++u) {
      int f = u * 256 + tid, row = f >> 3, dc = (f & 7) * 4;
      float4 kv = *reinterpret_cast<const float4*>(qkv + (kbase + row) * 384 + 128 + h * 32 + dc);
      *reinterpret_cast<float4*>(&Ks[row][dc]) = kv;
      float4 vv = *reinterpret_cast<const float4*>(qkv + (kbase + row) * 384 + 256 + h * 32 + dc);
      *reinterpret_cast<float4*>(&Vs[row][dc]) = vv;
    }
    __syncthreads();
    {
      const int ty = tid >> 4, tx = tid & 15;
      float s[4][4] = {};
#pragma unroll
      for (int d4 = 0; d4 < 8; ++d4) {
        float4 Qv[4], Kv[4];
#pragma unroll
        for (int ii = 0; ii < 4; ++ii) Qv[ii] = *reinterpret_cast<const float4*>(&Qs[ty * 4 + ii][d4 * 4]);
#pragma unroll
        for (int jj = 0; jj < 4; ++jj) Kv[jj] = *reinterpret_cast<const float4*>(&Ks[tx * 4 + jj][d4 * 4]);
#pragma unroll
        for (int ii = 0; ii < 4; ++ii)
#pragma unroll
          for (int jj = 0; jj < 4; ++jj)
            s[ii][jj] += Qv[ii].x * Kv[jj].x + Qv[ii].y * Kv[jj].y +
                         Qv[ii].z * Kv[jj].z + Qv[ii].w * Kv[jj].w;
      }
#pragma unroll
      for (int ii = 0; ii < 4; ++ii)
#pragma unroll
        for (int jj = 0; jj < 4; ++jj) {
          float v = s[ii][jj] * scale;
          if (kt == qt && (tx * 4 + jj) > (ty * 4 + ii)) v += -1e9f;
          Ss[ty * 4 + ii][tx * 4 + jj] = v;
        }
    }
    __syncthreads();
    {
      const int i = tid >> 2, q = tid & 3;
      float mx = -3.4e38f;
      float4 pv[4];
#pragma unroll
      for (int t = 0; t < 4; ++t) {
        pv[t] = *reinterpret_cast<const float4*>(&Ss[i][q * 16 + t * 4]);
        mx = fmaxf(mx, fmaxf(fmaxf(pv[t].x, pv[t].y), fmaxf(pv[t].z, pv[t].w)));
      }
      mx = fmaxf(mx, __shfl_xor(mx, 1));
      mx = fmaxf(mx, __shfl_xor(mx, 2));
      float mold = ms[i];
      mx = fmaxf(mx, mold);
      float sum = 0.f;
#pragma unroll
      for (int t = 0; t < 4; ++t) {
        pv[t].x = __expf(pv[t].x - mx); pv[t].y = __expf(pv[t].y - mx);
        pv[t].z = __expf(pv[t].z - mx); pv[t].w = __expf(pv[t].w - mx);
        sum += pv[t].x + pv[t].y + pv[t].z + pv[t].w;
        *reinterpret_cast<float4*>(&Ss[i][q * 16 + t * 4]) = pv[t];
      }
      sum += __shfl_xor(sum, 1);
      sum += __shfl_xor(sum, 2);
      if (q == 0) {
        float alpha = __expf(mold - mx);
        ls[i] = ls[i] * alpha + sum;
        ms[i] = mx;
        alphas[i] = alpha;
      }
    }
    __syncthreads();
    {
      float a0 = alphas[pi], a1 = alphas[pi + 32];
      o0.x *= a0; o0.y *= a0; o0.z *= a0; o0.w *= a0;
      o1.x *= a1; o1.y *= a1; o1.z *= a1; o1.w *= a1;
#pragma unroll 4
      for (int j = 0; j < 64; ++j) {
        float p0 = Ss[pi][j], p1 = Ss[pi + 32][j];
        float4 vv = *reinterpret_cast<const float4*>(&Vs[j][dg * 4]);
        o0.x += p0 * vv.x; o0.y += p0 * vv.y; o0.z += p0 * vv.z; o0.w += p0 * vv.w;
        o1.x += p1 * vv.x; o1.y += p1 * vv.y; o1.z += p1 * vv.z; o1.w += p1 * vv.w;
      }
    }
    __syncthreads();
  }
  float inv0 = 1.f / ls[pi], inv1 = 1.f / ls[pi + 32];
  o0.x *= inv0; o0.y *= inv0; o0.z *= inv0; o0.w *= inv0;
  o1.x *= inv1; o1.y *= inv1; o1.z *= inv1; o1.w *= inv1;
  *reinterpret_cast<float4*>(obuf + (tbase + pi) * 128 + h * 32 + dg * 4) = o0;
  *reinterpret_cast<float4*>(obuf + (tbase + pi + 32) * 128 + h * 32 + dg * 4) = o1;
}

// =============== plain layernorm (final) ===============
__global__ __launch_bounds__(128) void resid_ln(
    const float* __restrict__ in, float* __restrict__ outp,
    const float* __restrict__ g, const float* __restrict__ bb) {
  const int t = blockIdx.x, d = threadIdx.x;
  const size_t base = (size_t)t * 128;
  float x = in[base + d];
  float s = x;
#pragma unroll
  for (int o = 1; o < 64; o <<= 1) s += __shfl_xor(s, o);
  __shared__ float red[2], red2[2];
  if ((d & 63) == 0) red[d >> 6] = s;
  __syncthreads();
  float mean = (red[0] + red[1]) * 0.0078125f;
  float v = x - mean;
  float s2 = v * v;
#pragma unroll
  for (int o = 1; o < 64; o <<= 1) s2 += __shfl_xor(s2, o);
  if ((d & 63) == 0) red2[d >> 6] = s2;
  __syncthreads();
  float var = (red2[0] + red2[1]) * 0.0078125f;
  outp[base + d] = v * rsqrtf(var + 1e-5f) * g[d] + bb[d];
}

__global__ __launch_bounds__(256) void loss_finalize2(const float* __restrict__ lp,
                                                      float* __restrict__ out) {
  float s = 0.f;
  for (int i = threadIdx.x; i < 2048; i += 256) s += lp[i];
#pragma unroll
  for (int o = 1; o < 64; o <<= 1) s += __shfl_xor(s, o);
  __shared__ float red[4];
  if ((threadIdx.x & 63) == 0) red[threadIdx.x >> 6] = s;
  __syncthreads();
  if (threadIdx.x == 0)
    out[0] = 1.25f * (red[0] + red[1] + red[2] + red[3]) / 2097152.0f;
}

extern "C" void kernel_launch(void* const* d_in, const int* in_sizes, int n_in,
                              void* d_out, int out_size, void* d_ws, size_t ws_size,
                              hipStream_t stream) {
  const float* x      = (const float*)d_in[0];
  const float* enc_w1 = (const float*)d_in[1];
  const float* enc_b1 = (const float*)d_in[2];
  const float* enc_w2 = (const float*)d_in[3];
  const float* enc_b2 = (const float*)d_in[4];
  const float* enc_w3 = (const float*)d_in[5];
  const float* enc_b3 = (const float*)d_in[6];
  const float* res_w1 = (const float*)d_in[7];
  const float* res_b1 = (const float*)d_in[8];
  const float* res_w2 = (const float*)d_in[9];
  const float* res_b2 = (const float*)d_in[10];
  const float* pre_w  = (const float*)d_in[11];
  const float* pre_b  = (const float*)d_in[12];
  const float* codebook = (const float*)d_in[13];
  const float* pos_emb  = (const float*)d_in[14];
  const float* qkv_w  = (const float*)d_in[15];
  const float* qkv_b  = (const float*)d_in[16];
  const float* proj_w = (const float*)d_in[17];
  const float* proj_b = (const float*)d_in[18];
  const float* ln1_g  = (const float*)d_in[19];
  const float* ln1_b  = (const float*)d_in[20];
  const float* ln2_g  = (const float*)d_in[21];
  const float* ln2_b  = (const float*)d_in[22];
  const float* ffn_w1 = (const float*)d_in[23];
  const float* ffn_b1 = (const float*)d_in[24];
  const float* ffn_w2 = (const float*)d_in[25];
  const float* ffn_b2 = (const float*)d_in[26];
  const float* fin_g  = (const float*)d_in[27];
  const float* fin_b  = (const float*)d_in[28];
  const float* head_w = (const float*)d_in[29];
  const float* head_b = (const float*)d_in[30];

  float* out = (float*)d_out;
  float* ws  = (float*)d_ws;

  // ws: hh [2^21] | hhln [2^21] | keys [16384 u64 = 32768 f] | cn [1024] | lpart [2048]
  float* hh   = ws;
  float* hhln = ws + (1 << 21);
  unsigned long long* keys = (unsigned long long*)(ws + (1 << 22));
  float* cn    = ws + (1 << 22) + 32768;
  float* lpart = cn + 1024;
  // d_out scratch overlay (dead before head GEMM)
  float* zf   = out + Z_OFF;
  float* qkvb = out + QKV_OFF;
  float* fbuf = out + QKV_OFF;
  float* oatt = out + OATT_OFF;

  hipMemsetAsync(keys, 0xFF, NPATCH * sizeof(unsigned long long), stream);

  encoder2<<<512, 256, 0, stream>>>(x, enc_w1, enc_b1, enc_w2, enc_b2,
                                    enc_w3, enc_b3, res_w1, res_b1,
                                    res_w2, res_b2, pre_w, pre_b, zf);
  cb_norms<<<4, 256, 0, stream>>>(codebook, cn);
  vq_argmin<<<dim3(16, 256), 256, 0, stream>>>(zf, codebook, cn, keys);
  vq_gather2<<<2048, 256, 0, stream>>>(zf, codebook, pos_emb, keys, hh, lpart,
                                       out + IDX_OFF);
  for (int i = 0; i < 4; ++i) {
    mgemm_bias<0><<<dim3(6, 128), 256, 0, stream>>>(hh, qkv_w + i * 49152,
                                                    qkv_b + i * 384, qkvb, 384);
    attn2<<<dim3(8, 4, 32), 256, 0, stream>>>(qkvb, oatt);
    mgemm_ln<128><<<256, 256, 0, stream>>>(oatt, proj_w + i * 16384,
                                           proj_b + i * 128, hh,
                                           ln1_g + i * 128, ln1_b + i * 128, hh);
    mgemm_bias<1><<<dim3(4, 128), 256, 0, stream>>>(hh, ffn_w1 + i * 32768,
                                                    ffn_b1 + i * 256, fbuf, 256);
    mgemm_ln<256><<<256, 256, 0, stream>>>(fbuf, ffn_w2 + i * 32768,
                                           ffn_b2 + i * 128, hh,
                                           ln2_g + i * 128, ln2_b + i * 128, hh);
  }
  resid_ln<<<NPATCH, 128, 0, stream>>>(hh, hhln, fin_g, fin_b);
  mgemm_bias<0><<<dim3(16, 128), 256, 0, stream>>>(hhln, head_w, head_b, out, 1024);
  loss_finalize2<<<1, 256, 0, stream>>>(lpart, out + LOSS_OFF);
}

// Round 4
// 777.002 us; speedup vs baseline: 4.3005x; 1.3300x over previous
//
#include <hip/hip_runtime.h>
#include <math.h>

// ---- problem constants ----
#define NPATCH 16384          // B * T / P
#define SEQ    512            // T / P
#define LOSS_OFF 16777216
#define IDX_OFF  16777217

typedef short bf8 __attribute__((ext_vector_type(8)));    // 8 bf16 (4 VGPRs)
typedef float f32x4 __attribute__((ext_vector_type(4)));  // MFMA acc

__device__ inline short f2bf(float x) {          // fp32 -> bf16 RNE
  unsigned u = __float_as_uint(x);
  u += 0x7fffu + ((u >> 16) & 1u);
  return (short)(u >> 16);
}
__device__ inline float bf2f(short h) {
  return __uint_as_float(((unsigned)(unsigned short)h) << 16);
}

// =============== encoder v3: 16 patches/block (32KB LDS -> 5 blocks/CU) ===============
__global__ __launch_bounds__(256) void encoder3(
    const float* __restrict__ x,
    const float* __restrict__ w1, const float* __restrict__ b1,
    const float* __restrict__ w2, const float* __restrict__ b2,
    const float* __restrict__ w3, const float* __restrict__ b3,
    const float* __restrict__ rw1, const float* __restrict__ rb1,
    const float* __restrict__ rw2, const float* __restrict__ rb2,
    const float* __restrict__ pw, const float* __restrict__ pb,
    float* __restrict__ z) {
  __shared__ float ar[8192];           // 32 KB arena
  float* H1 = ar;                      // [256 feat][16 n]
  float* H2 = ar + 4096;               // [256 feat][16 n]
  float* XS = ar + 4096;               // [16][16] overlays H2
  float* H3 = ar;                      // overlays H1 after conv3
  float* T1 = ar + 4096;               // [128][16] overlays H2
  const int blk = blockIdx.x, tid = threadIdx.x;
  const int n = tid & 15, g = tid >> 4;   // patch-in-block, feature group 0..15

  if (tid < 64) {
    int p = tid >> 2, i = (tid & 3) * 4;
    float4 v = *reinterpret_cast<const float4*>(x + ((size_t)blk * 16 + p) * 16 + i);
    XS[(i + 0) * 16 + p] = v.x; XS[(i + 1) * 16 + p] = v.y;
    XS[(i + 2) * 16 + p] = v.z; XS[(i + 3) * 16 + p] = v.w;
  }
  __syncthreads();
  { // conv1: 1->32ch, L16->8, k4 s2 p1, relu.  thread: ch=g*2+c (c0..1), l0..7
    float xv[16];
#pragma unroll
    for (int i = 0; i < 16; ++i) xv[i] = XS[i * 16 + n];
#pragma unroll
    for (int c = 0; c < 2; ++c) {
      int ch = g * 2 + c;
      float4 wv = *reinterpret_cast<const float4*>(w1 + ch * 4);
      float bs = b1[ch];
      float w[4] = {wv.x, wv.y, wv.z, wv.w};
#pragma unroll
      for (int l = 0; l < 8; ++l) {
        float acc = bs;
#pragma unroll
        for (int kk = 0; kk < 4; ++kk) {
          int xi = 2 * l + kk - 1;
          if (xi >= 0 && xi < 16) acc += xv[xi] * w[kk];
        }
        H1[(ch * 8 + l) * 16 + n] = fmaxf(acc, 0.f);
      }
    }
  }
  __syncthreads();
  { // conv2: 32->64ch, L8->4, k4 s2 p1, relu.  thread: co=g*4+c, l0..3
    float acc[4][4];
#pragma unroll
    for (int c = 0; c < 4; ++c) {
      float bs = b2[g * 4 + c];
#pragma unroll
      for (int l = 0; l < 4; ++l) acc[c][l] = bs;
    }
    for (int ci = 0; ci < 32; ++ci) {
      float hv[8];
#pragma unroll
      for (int xi = 0; xi < 8; ++xi) hv[xi] = H1[(ci * 8 + xi) * 16 + n];
#pragma unroll
      for (int c = 0; c < 4; ++c) {
        float4 wv = *reinterpret_cast<const float4*>(w2 + ((g * 4 + c) * 32 + ci) * 4);
        float w[4] = {wv.x, wv.y, wv.z, wv.w};
#pragma unroll
        for (int l = 0; l < 4; ++l)
#pragma unroll
          for (int kk = 0; kk < 4; ++kk) {
            int xi = 2 * l + kk - 1;
            if (xi >= 0 && xi < 8) acc[c][l] += hv[xi] * w[kk];
          }
      }
    }
    __syncthreads();
#pragma unroll
    for (int c = 0; c < 4; ++c)
#pragma unroll
      for (int l = 0; l < 4; ++l)
        H2[((g * 4 + c) * 4 + l) * 16 + n] = fmaxf(acc[c][l], 0.f);
  }
  __syncthreads();
  { // conv3: 64->64ch, L4, k3 p1.  thread: co=g*4+c, l0..3
    float acc[4][4];
#pragma unroll
    for (int c = 0; c < 4; ++c) {
      float bs = b3[g * 4 + c];
#pragma unroll
      for (int l = 0; l < 4; ++l) acc[c][l] = bs;
    }
    for (int ci = 0; ci < 64; ++ci) {
      float hv[4];
#pragma unroll
      for (int xi = 0; xi < 4; ++xi) hv[xi] = H2[(ci * 4 + xi) * 16 + n];
#pragma unroll
      for (int c = 0; c < 4; ++c) {
        const float* wp = w3 + ((g * 4 + c) * 64 + ci) * 3;
        float w0 = wp[0], w1v = wp[1], w2v = wp[2];
#pragma unroll
        for (int l = 0; l < 4; ++l) {
          if (l - 1 >= 0) acc[c][l] += hv[l - 1] * w0;
          acc[c][l] += hv[l] * w1v;
          if (l + 1 < 4) acc[c][l] += hv[l + 1] * w2v;
        }
      }
    }
    __syncthreads();
#pragma unroll
    for (int c = 0; c < 4; ++c)
#pragma unroll
      for (int l = 0; l < 4; ++l)
        H3[((g * 4 + c) * 4 + l) * 16 + n] = acc[c][l];
  }
  __syncthreads();
  for (int rl = 0; rl < 2; ++rl) {
    { // stage a: co=g*2+c (c0..1), l0..3
      float acc[2][4];
#pragma unroll
      for (int c = 0; c < 2; ++c) {
        float bs = rb1[rl * 32 + g * 2 + c];
#pragma unroll
        for (int l = 0; l < 4; ++l) acc[c][l] = bs;
      }
      for (int ci = 0; ci < 64; ++ci) {
        float hv[4];
#pragma unroll
        for (int xi = 0; xi < 4; ++xi) hv[xi] = fmaxf(H3[(ci * 4 + xi) * 16 + n], 0.f);
#pragma unroll
        for (int c = 0; c < 2; ++c) {
          const float* wp = rw1 + ((rl * 32 + g * 2 + c) * 64 + ci) * 3;
          float w0 = wp[0], w1v = wp[1], w2v = wp[2];
#pragma unroll
          for (int l = 0; l < 4; ++l) {
            if (l - 1 >= 0) acc[c][l] += hv[l - 1] * w0;
            acc[c][l] += hv[l] * w1v;
            if (l + 1 < 4) acc[c][l] += hv[l + 1] * w2v;
          }
        }
      }
      __syncthreads();
#pragma unroll
      for (int c = 0; c < 2; ++c)
#pragma unroll
        for (int l = 0; l < 4; ++l)
          T1[((g * 2 + c) * 4 + l) * 16 + n] = acc[c][l];
    }
    __syncthreads();
    { // stage b: co=g*4+c, l0..3
      float acc[4][4];
#pragma unroll
      for (int c = 0; c < 4; ++c) {
        float bs = rb2[rl * 64 + g * 4 + c];
#pragma unroll
        for (int l = 0; l < 4; ++l) acc[c][l] = bs;
      }
      for (int ci = 0; ci < 32; ++ci) {
        float tv[4];
#pragma unroll
        for (int l = 0; l < 4; ++l) tv[l] = fmaxf(T1[(ci * 4 + l) * 16 + n], 0.f);
#pragma unroll
        for (int c = 0; c < 4; ++c) {
          float w = rw2[(rl * 64 + g * 4 + c) * 32 + ci];
#pragma unroll
          for (int l = 0; l < 4; ++l) acc[c][l] += tv[l] * w;
        }
      }
#pragma unroll
      for (int c = 0; c < 4; ++c)
#pragma unroll
        for (int l = 0; l < 4; ++l)
          H3[((g * 4 + c) * 4 + l) * 16 + n] += acc[c][l];
    }
    __syncthreads();
  }
  { // pre 1x1: relu(h3) 64->32ch.  thread: e=g*2+c (c0..1), l0..3
    float acc[2][4];
#pragma unroll
    for (int c = 0; c < 2; ++c) {
      float bs = pb[g * 2 + c];
#pragma unroll
      for (int l = 0; l < 4; ++l) acc[c][l] = bs;
    }
    for (int ci = 0; ci < 64; ++ci) {
      float hv[4];
#pragma unroll
      for (int l = 0; l < 4; ++l) hv[l] = fmaxf(H3[(ci * 4 + l) * 16 + n], 0.f);
#pragma unroll
      for (int c = 0; c < 2; ++c) {
        float w = pw[(g * 2 + c) * 64 + ci];
#pragma unroll
        for (int l = 0; l < 4; ++l) acc[c][l] += hv[l] * w;
      }
    }
#pragma unroll
    for (int c = 0; c < 2; ++c) {
      float4 v = {acc[c][0], acc[c][1], acc[c][2], acc[c][3]};
      *reinterpret_cast<float4*>(z + ((size_t)blk * 16 + n) * 128 + (g * 2 + c) * 4) = v;
    }
  }
}

// =============== weight pre-split: fp32 -> hi/lo bf16 planes (once/launch) ===============
// layout: qkv[0..196608) proj[196608..262144) ffn1[262144..393216) ffn2[393216..524288) head[524288..655360)
__global__ __launch_bounds__(256) void split_w(
    const float* __restrict__ qkv_w, const float* __restrict__ proj_w,
    const float* __restrict__ f1, const float* __restrict__ f2,
    const float* __restrict__ hw, unsigned short* __restrict__ wh,
    unsigned short* __restrict__ wl) {
  int i = blockIdx.x * 256 + threadIdx.x;
  float v;
  if (i < 196608) v = qkv_w[i];
  else if (i < 262144) v = proj_w[i - 196608];
  else if (i < 393216) v = f1[i - 262144];
  else if (i < 524288) v = f2[i - 393216];
  else v = hw[i - 524288];
  short h = f2bf(v);
  wh[i] = (unsigned short)h;
  wl[i] = (unsigned short)f2bf(v - bf2f(h));
}

// =============== VQ part 1: codebook squared norms ===============
__global__ __launch_bounds__(256) void cb_norms(const float* __restrict__ cb,
                                                float* __restrict__ cn) {
  int j = blockIdx.x * 256 + threadIdx.x;
  const float4* cp = reinterpret_cast<const float4*>(cb + (size_t)j * 128);
  float s = 0.f;
#pragma unroll
  for (int k = 0; k < 32; ++k) {
    float4 c = cp[k];
    s += c.x * c.x + c.y * c.y + c.z * c.z + c.w * c.w;
  }
  cn[j] = s;
}

// ======= VQ part 2: fp32 GEMM z.cb^T + argmin epilogue (fp32 for exactness) =======
__global__ __launch_bounds__(256) void vq_argmin(
    const float* __restrict__ A, const float* __restrict__ B,
    const float* __restrict__ cn, unsigned long long* __restrict__ keys) {
  __shared__ float Ask[32][68];
  __shared__ float Bsk[32][68];
  const int tid = threadIdx.x;
  const int n0 = blockIdx.x * 64, m0 = blockIdx.y * 64;
  const int ty = tid >> 4, tx = tid & 15;
  const int lr = tid >> 3, lc = (tid & 7) * 4;
  float acc[4][4] = {};
  for (int k0 = 0; k0 < 128; k0 += 32) {
#pragma unroll
    for (int p = 0; p < 2; ++p) {
      int row = p * 32 + lr;
      float4 av = *reinterpret_cast<const float4*>(A + (size_t)(m0 + row) * 128 + k0 + lc);
      Ask[lc + 0][row] = av.x; Ask[lc + 1][row] = av.y;
      Ask[lc + 2][row] = av.z; Ask[lc + 3][row] = av.w;
      float4 bv = *reinterpret_cast<const float4*>(B + (size_t)(n0 + row) * 128 + k0 + lc);
      Bsk[lc + 0][row] = bv.x; Bsk[lc + 1][row] = bv.y;
      Bsk[lc + 2][row] = bv.z; Bsk[lc + 3][row] = bv.w;
    }
    __syncthreads();
#pragma unroll
    for (int kk = 0; kk < 32; ++kk) {
      float4 av = *reinterpret_cast<const float4*>(&Ask[kk][ty * 4]);
      float4 bv = *reinterpret_cast<const float4*>(&Bsk[kk][tx * 4]);
      float a[4] = {av.x, av.y, av.z, av.w};
      float b[4] = {bv.x, bv.y, bv.z, bv.w};
#pragma unroll
      for (int ii = 0; ii < 4; ++ii)
#pragma unroll
        for (int jj = 0; jj < 4; ++jj) acc[ii][jj] += a[ii] * b[jj];
    }
    __syncthreads();
  }
#pragma unroll
  for (int ii = 0; ii < 4; ++ii) {
    int row = m0 + ty * 4 + ii;
    unsigned long long key = ~0ull;
#pragma unroll
    for (int jj = 0; jj < 4; ++jj) {
      int j = n0 + tx * 4 + jj;
      float dv = cn[j] - 2.f * acc[ii][jj];
      unsigned u = __float_as_uint(dv);
      u = (u & 0x80000000u) ? ~u : (u | 0x80000000u);
      unsigned long long k = ((unsigned long long)u << 32) | (unsigned)j;
      key = k < key ? k : key;
    }
#pragma unroll
    for (int off = 1; off < 16; off <<= 1) {
      unsigned long long o = __shfl_xor(key, off);
      key = o < key ? o : key;
    }
    if (tx == 0) atomicMin(&keys[row], key);
  }
}

// ===== VQ part 3: gather q, loss partials, hh = q + pos (fp32 + split planes) =====
__global__ __launch_bounds__(256) void vq_gather3(
    const float* __restrict__ z, const float* __restrict__ cb,
    const float* __restrict__ pos, const unsigned long long* __restrict__ keys,
    float* __restrict__ hh, unsigned short* __restrict__ hh_h,
    unsigned short* __restrict__ hh_l, float* __restrict__ lpart,
    float* __restrict__ idx_out) {
  const int blk = blockIdx.x, tid = threadIdx.x;
  __shared__ int sidx[8];
  if (tid < 8) {
    unsigned long long k = keys[blk * 8 + tid];
    int id = (int)(unsigned)(k & 0xffffffffull);
    sidx[tid] = id;
    idx_out[blk * 8 + tid] = (float)id;
  }
  __syncthreads();
  const int p = tid >> 5, d = tid & 31;
  const size_t n = (size_t)blk * 8 + p;
  const int idx = sidx[p];
  float4 q = *reinterpret_cast<const float4*>(cb + (size_t)idx * 128 + d * 4);
  float4 zv = *reinterpret_cast<const float4*>(z + n * 128 + d * 4);
  float4 pv = *reinterpret_cast<const float4*>(pos + (size_t)(n & 511) * 128 + d * 4);
  float hv[4] = {q.x + pv.x, q.y + pv.y, q.z + pv.z, q.w + pv.w};
  *reinterpret_cast<float4*>(hh + n * 128 + d * 4) = *reinterpret_cast<float4*>(hv);
  ushort4 h4, l4;
  unsigned short* hp = (unsigned short*)&h4;
  unsigned short* lp = (unsigned short*)&l4;
#pragma unroll
  for (int e = 0; e < 4; ++e) {
    short hb = f2bf(hv[e]);
    hp[e] = (unsigned short)hb;
    lp[e] = (unsigned short)f2bf(hv[e] - bf2f(hb));
  }
  *reinterpret_cast<ushort4*>(&hh_h[n * 128 + d * 4]) = h4;
  *reinterpret_cast<ushort4*>(&hh_l[n * 128 + d * 4]) = l4;
  float dx = q.x - zv.x, dy = q.y - zv.y, dz = q.z - zv.z, dw = q.w - zv.w;
  float part = dx * dx + dy * dy + dz * dz + dw * dw;
#pragma unroll
  for (int o = 1; o < 64; o <<= 1) part += __shfl_xor(part, o);
  __shared__ float lred[4];
  if ((tid & 63) == 0) lred[tid >> 6] = part;
  __syncthreads();
  if (tid == 0) lpart[blk] = lred[0] + lred[1] + lred[2] + lred[3];
}

// ====== split-bf16 MFMA GEMM (pre-split inputs): C = A[M,128]*B[N,128]^T + bias ======
// tile 128(M) x 64(N).  ACT: 0=none 1=gelu.  SPLIT: 1 -> write hi/lo planes, 0 -> fp32.
template <int ACT, int SPLIT>
__global__ __launch_bounds__(256) void mgemm2(
    const unsigned short* __restrict__ Ahg, const unsigned short* __restrict__ Alg,
    const unsigned short* __restrict__ Bhg, const unsigned short* __restrict__ Blg,
    const float* __restrict__ bias, float* __restrict__ C,
    unsigned short* __restrict__ Ch, unsigned short* __restrict__ Cl, int N) {
  __shared__ short Ah[128 * 40], Al[128 * 40], Bh[64 * 40], Bl[64 * 40];
  const int tid = threadIdx.x;
  const int n0 = blockIdx.x * 64, m0 = blockIdx.y * 128;
  const int wave = tid >> 6, lane = tid & 63, quad = lane >> 4, l15 = lane & 15;
  const f32x4 z4 = {0.f, 0.f, 0.f, 0.f};
  f32x4 acc[2][4];
#pragma unroll
  for (int i = 0; i < 2; ++i)
#pragma unroll
    for (int j = 0; j < 4; ++j) acc[i][j] = z4;

  const int ra = tid >> 1, ha = (tid & 1) * 16;         // A: 128 rows, 16 shorts each
  const int rb = tid >> 2, hb = (tid & 3) * 8;          // B: 64 rows, 8 shorts each
  for (int k0 = 0; k0 < 128; k0 += 32) {
    {
      const size_t abase = (size_t)(m0 + ra) * 128 + k0 + ha;
      *reinterpret_cast<bf8*>(&Ah[ra * 40 + ha])     = *reinterpret_cast<const bf8*>(&Ahg[abase]);
      *reinterpret_cast<bf8*>(&Ah[ra * 40 + ha + 8]) = *reinterpret_cast<const bf8*>(&Ahg[abase + 8]);
      *reinterpret_cast<bf8*>(&Al[ra * 40 + ha])     = *reinterpret_cast<const bf8*>(&Alg[abase]);
      *reinterpret_cast<bf8*>(&Al[ra * 40 + ha + 8]) = *reinterpret_cast<const bf8*>(&Alg[abase + 8]);
      const size_t bbase = (size_t)(n0 + rb) * 128 + k0 + hb;
      *reinterpret_cast<bf8*>(&Bh[rb * 40 + hb]) = *reinterpret_cast<const bf8*>(&Bhg[bbase]);
      *reinterpret_cast<bf8*>(&Bl[rb * 40 + hb]) = *reinterpret_cast<const bf8*>(&Blg[bbase]);
    }
    __syncthreads();
    bf8 af[2], afl[2], bfh[4], bfl[4];
#pragma unroll
    for (int mt = 0; mt < 2; ++mt) {
      int row = wave * 32 + mt * 16 + l15;
      af[mt]  = *reinterpret_cast<const bf8*>(&Ah[row * 40 + quad * 8]);
      afl[mt] = *reinterpret_cast<const bf8*>(&Al[row * 40 + quad * 8]);
    }
#pragma unroll
    for (int nt = 0; nt < 4; ++nt) {
      int row = nt * 16 + l15;
      bfh[nt] = *reinterpret_cast<const bf8*>(&Bh[row * 40 + quad * 8]);
      bfl[nt] = *reinterpret_cast<const bf8*>(&Bl[row * 40 + quad * 8]);
    }
#pragma unroll
    for (int nt = 0; nt < 4; ++nt)
#pragma unroll
      for (int mt = 0; mt < 2; ++mt)
        acc[mt][nt] = __builtin_amdgcn_mfma_f32_16x16x32_bf16(af[mt], bfh[nt], acc[mt][nt], 0, 0, 0);
#pragma unroll
    for (int nt = 0; nt < 4; ++nt)
#pragma unroll
      for (int mt = 0; mt < 2; ++mt)
        acc[mt][nt] = __builtin_amdgcn_mfma_f32_16x16x32_bf16(af[mt], bfl[nt], acc[mt][nt], 0, 0, 0);
#pragma unroll
    for (int nt = 0; nt < 4; ++nt)
#pragma unroll
      for (int mt = 0; mt < 2; ++mt)
        acc[mt][nt] = __builtin_amdgcn_mfma_f32_16x16x32_bf16(afl[mt], bfh[nt], acc[mt][nt], 0, 0, 0);
    __syncthreads();
  }
#pragma unroll
  for (int nt = 0; nt < 4; ++nt) {
    int col = n0 + nt * 16 + l15;
    float bv = bias[col];
#pragma unroll
    for (int mt = 0; mt < 2; ++mt) {
      int rbase = m0 + wave * 32 + mt * 16 + quad * 4;
#pragma unroll
      for (int r = 0; r < 4; ++r) {
        float v = acc[mt][nt][r] + bv;
        if (ACT == 1) v = 0.5f * v * (1.f + erff(v * 0.7071067811865476f));
        if (SPLIT) {
          short hb_ = f2bf(v);
          Ch[(size_t)(rbase + r) * N + col] = (unsigned short)hb_;
          Cl[(size_t)(rbase + r) * N + col] = (unsigned short)f2bf(v - bf2f(hb_));
        } else {
          C[(size_t)(rbase + r) * N + col] = v;
        }
      }
    }
  }
}

// == split-bf16 MFMA GEMM + residual + LN: out = LN(A.B^T+bias+res)*g+b (fp32+planes) ==
// tile 64(M) x 128(N).  K: 128 or 256.
template <int K>
__global__ __launch_bounds__(256) void mgemm_ln2(
    const unsigned short* __restrict__ Ahg, const unsigned short* __restrict__ Alg,
    const unsigned short* __restrict__ Bhg, const unsigned short* __restrict__ Blg,
    const float* __restrict__ bias, const float* __restrict__ res,
    const float* __restrict__ g, const float* __restrict__ bb,
    float* __restrict__ C, unsigned short* __restrict__ Ch,
    unsigned short* __restrict__ Cl) {
  __shared__ short Ah[64 * 40], Al[64 * 40], Bh[128 * 40], Bl[128 * 40];
  const int tid = threadIdx.x;
  const int m0 = blockIdx.x * 64;
  const int wave = tid >> 6, lane = tid & 63, quad = lane >> 4, l15 = lane & 15;
  const f32x4 z4 = {0.f, 0.f, 0.f, 0.f};
  f32x4 acc[8];
#pragma unroll
  for (int j = 0; j < 8; ++j) acc[j] = z4;

  const int ra = tid >> 2, ha = (tid & 3) * 8;          // A: 64 rows, 8 shorts each
  const int rb = tid >> 1, hb = (tid & 1) * 16;         // B: 128 rows, 16 shorts each
  for (int k0 = 0; k0 < K; k0 += 32) {
    {
      const size_t abase = (size_t)(m0 + ra) * K + k0 + ha;
      *reinterpret_cast<bf8*>(&Ah[ra * 40 + ha]) = *reinterpret_cast<const bf8*>(&Ahg[abase]);
      *reinterpret_cast<bf8*>(&Al[ra * 40 + ha]) = *reinterpret_cast<const bf8*>(&Alg[abase]);
      const size_t bbase = (size_t)rb * K + k0 + hb;
      *reinterpret_cast<bf8*>(&Bh[rb * 40 + hb])     = *reinterpret_cast<const bf8*>(&Bhg[bbase]);
      *reinterpret_cast<bf8*>(&Bh[rb * 40 + hb + 8]) = *reinterpret_cast<const bf8*>(&Bhg[bbase + 8]);
      *reinterpret_cast<bf8*>(&Bl[rb * 40 + hb])     = *reinterpret_cast<const bf8*>(&Blg[bbase]);
      *reinterpret_cast<bf8*>(&Bl[rb * 40 + hb + 8]) = *reinterpret_cast<const bf8*>(&Blg[bbase + 8]);
    }
    __syncthreads();
    bf8 af, afl, bfh[8], bfl[8];
    {
      int row = wave * 16 + l15;
      af  = *reinterpret_cast<const bf8*>(&Ah[row * 40 + quad * 8]);
      afl = *reinterpret_cast<const bf8*>(&Al[row * 40 + quad * 8]);
    }
#pragma unroll
    for (int nt = 0; nt < 8; ++nt) {
      int row = nt * 16 + l15;
      bfh[nt] = *reinterpret_cast<const bf8*>(&Bh[row * 40 + quad * 8]);
      bfl[nt] = *reinterpret_cast<const bf8*>(&Bl[row * 40 + quad * 8]);
    }
#pragma unroll
    for (int nt = 0; nt < 8; ++nt)
      acc[nt] = __builtin_amdgcn_mfma_f32_16x16x32_bf16(af, bfh[nt], acc[nt], 0, 0, 0);
#pragma unroll
    for (int nt = 0; nt < 8; ++nt)
      acc[nt] = __builtin_amdgcn_mfma_f32_16x16x32_bf16(af, bfl[nt], acc[nt], 0, 0, 0);
#pragma unroll
    for (int nt = 0; nt < 8; ++nt)
      acc[nt] = __builtin_amdgcn_mfma_f32_16x16x32_bf16(afl, bfh[nt], acc[nt], 0, 0, 0);
    __syncthreads();
  }
  float bias_v[8], g_v[8], bb_v[8];
#pragma unroll
  for (int nt = 0; nt < 8; ++nt) {
    int col = nt * 16 + l15;
    bias_v[nt] = bias[col]; g_v[nt] = g[col]; bb_v[nt] = bb[col];
  }
  const int rbase = m0 + wave * 16 + quad * 4;
#pragma unroll
  for (int r = 0; r < 4; ++r) {
    const int row = rbase + r;
    float ov[8];
    float s = 0.f;
#pragma unroll
    for (int nt = 0; nt < 8; ++nt) {
      ov[nt] = acc[nt][r] + bias_v[nt] + res[(size_t)row * 128 + nt * 16 + l15];
      s += ov[nt];
    }
    s += __shfl_xor(s, 1); s += __shfl_xor(s, 2);
    s += __shfl_xor(s, 4); s += __shfl_xor(s, 8);
    float mean = s * 0.0078125f;
    float s2 = 0.f;
#pragma unroll
    for (int nt = 0; nt < 8; ++nt) { ov[nt] -= mean; s2 += ov[nt] * ov[nt]; }
    s2 += __shfl_xor(s2, 1); s2 += __shfl_xor(s2, 2);
    s2 += __shfl_xor(s2, 4); s2 += __shfl_xor(s2, 8);
    float rstd = rsqrtf(s2 * 0.0078125f + 1e-5f);
#pragma unroll
    for (int nt = 0; nt < 8; ++nt) {
      float v = ov[nt] * rstd * g_v[nt] + bb_v[nt];
      size_t off = (size_t)row * 128 + nt * 16 + l15;
      C[off] = v;
      short hb_ = f2bf(v);
      Ch[off] = (unsigned short)hb_;
      Cl[off] = (unsigned short)f2bf(v - bf2f(hb_));
    }
  }
}

// ====== MFMA flash attention: block per (qt,h,b); reads/writes split planes ======
__global__ __launch_bounds__(256) void attn3(
    const unsigned short* __restrict__ qh_, const unsigned short* __restrict__ ql_,
    unsigned short* __restrict__ oh, unsigned short* __restrict__ ol) {
  const int qt = blockIdx.x, h = blockIdx.y, b = blockIdx.z;
  __shared__ short Kh[64 * 40], Kl[64 * 40];     // [key][d]
  __shared__ short Vth[32 * 72], Vtl[32 * 72];   // [d][key]
  __shared__ float Ss[64 * 72];
  __shared__ float ms[64], ls[64], alphas[64];
  const int tid = threadIdx.x;
  const int wave = tid >> 6, lane = tid & 63, quad = lane >> 4, l15 = lane & 15;
  const size_t tbase = (size_t)b * 512 + qt * 64;
  // Q fragment (A-layout: m=l15, k=quad*8+j), direct from global, resident all kernel
  bf8 qfh, qfl;
  {
    const size_t qoff = (tbase + wave * 16 + l15) * 384 + h * 32 + quad * 8;
    qfh = *reinterpret_cast<const bf8*>(&qh_[qoff]);
    qfl = *reinterpret_cast<const bf8*>(&ql_[qoff]);
  }
  if (tid < 64) { ms[tid] = -1e30f; ls[tid] = 0.f; }
  const f32x4 z4 = {0.f, 0.f, 0.f, 0.f};
  f32x4 o[2] = {z4, z4};
  const float scale = 0.17677669529663687f;  // 1/sqrt(32)
  const int sr = tid >> 2, sc8 = (tid & 3) * 8;   // staging: key row, d-offset
  for (int kt = 0; kt <= qt; ++kt) {
    const size_t kbase = (size_t)b * 512 + kt * 64;
    { // stage K (row-major) and V (transposed), pre-split shorts
      const size_t koff = (kbase + sr) * 384 + 128 + h * 32 + sc8;
      *reinterpret_cast<bf8*>(&Kh[sr * 40 + sc8]) = *reinterpret_cast<const bf8*>(&qh_[koff]);
      *reinterpret_cast<bf8*>(&Kl[sr * 40 + sc8]) = *reinterpret_cast<const bf8*>(&ql_[koff]);
      const size_t voff = (kbase + sr) * 384 + 256 + h * 32 + sc8;
      bf8 vh8 = *reinterpret_cast<const bf8*>(&qh_[voff]);
      bf8 vl8 = *reinterpret_cast<const bf8*>(&ql_[voff]);
#pragma unroll
      for (int j = 0; j < 8; ++j) {
        Vth[(sc8 + j) * 72 + sr] = vh8[j];
        Vtl[(sc8 + j) * 72 + sr] = vl8[j];
      }
    }
    __syncthreads();
    { // S = Q.K^T via MFMA (split-3); wave handles 16 queries (mt = wave)
#pragma unroll
      for (int nt = 0; nt < 4; ++nt) {
        const int krow = nt * 16 + l15;
        bf8 kfh = *reinterpret_cast<const bf8*>(&Kh[krow * 40 + quad * 8]);
        bf8 kfl = *reinterpret_cast<const bf8*>(&Kl[krow * 40 + quad * 8]);
        f32x4 s = z4;
        s = __builtin_amdgcn_mfma_f32_16x16x32_bf16(qfh, kfh, s, 0, 0, 0);
        s = __builtin_amdgcn_mfma_f32_16x16x32_bf16(qfh, kfl, s, 0, 0, 0);
        s = __builtin_amdgcn_mfma_f32_16x16x32_bf16(qfl, kfh, s, 0, 0, 0);
#pragma unroll
        for (int r = 0; r < 4; ++r) {
          int row64 = wave * 16 + quad * 4 + r;   // query in tile
          int col64 = nt * 16 + l15;              // key in tile
          float v = s[r] * scale;
          if (kt == qt && col64 > row64) v += -1e9f;
          Ss[row64 * 72 + col64] = v;
        }
      }
    }
    __syncthreads();
    { // online softmax: row i = tid>>2, quarter q = tid&3 scans 16 cols
      const int i = tid >> 2, q = tid & 3;
      float mx = -3.4e38f;
      float4 pv[4];
#pragma unroll
      for (int t = 0; t < 4; ++t) {
        pv[t] = *reinterpret_cast<const float4*>(&Ss[i * 72 + q * 16 + t * 4]);
        mx = fmaxf(mx, fmaxf(fmaxf(pv[t].x, pv[t].y), fmaxf(pv[t].z, pv[t].w)));
      }
      mx = fmaxf(mx, __shfl_xor(mx, 1));
      mx = fmaxf(mx, __shfl_xor(mx, 2));
      float mold = ms[i];
      mx = fmaxf(mx, mold);
      float sum = 0.f;
#pragma unroll
      for (int t = 0; t < 4; ++t) {
        pv[t].x = __expf(pv[t].x - mx); pv[t].y = __expf(pv[t].y - mx);
        pv[t].z = __expf(pv[t].z - mx); pv[t].w = __expf(pv[t].w - mx);
        sum += pv[t].x + pv[t].y + pv[t].z + pv[t].w;
        *reinterpret_cast<float4*>(&Ss[i * 72 + q * 16 + t * 4]) = pv[t];
      }
      sum += __shfl_xor(sum, 1);
      sum += __shfl_xor(sum, 2);
      if (q == 0) {
        float alpha = __expf(mold - mx);
        ls[i] = ls[i] * alpha + sum;
        ms[i] = mx;
        alphas[i] = alpha;
      }
    }
    __syncthreads();
    { // O = alpha*O + P.V via MFMA; P read from Ss with on-the-fly split
      bf8 ph[2], pl[2];
#pragma unroll
      for (int c = 0; c < 2; ++c) {
        const float* pp = &Ss[(wave * 16 + l15) * 72 + c * 32 + quad * 8];
        float4 p0 = *reinterpret_cast<const float4*>(pp);
        float4 p1 = *reinterpret_cast<const float4*>(pp + 4);
        float pf[8] = {p0.x, p0.y, p0.z, p0.w, p1.x, p1.y, p1.z, p1.w};
#pragma unroll
        for (int j = 0; j < 8; ++j) {
          short hb_ = f2bf(pf[j]);
          ph[c][j] = hb_;
          pl[c][j] = f2bf(pf[j] - bf2f(hb_));
        }
      }
      float a0 = alphas[wave * 16 + quad * 4 + 0];
      float a1 = alphas[wave * 16 + quad * 4 + 1];
      float a2 = alphas[wave * 16 + quad * 4 + 2];
      float a3 = alphas[wave * 16 + quad * 4 + 3];
#pragma unroll
      for (int dt = 0; dt < 2; ++dt) {
        o[dt][0] *= a0; o[dt][1] *= a1; o[dt][2] *= a2; o[dt][3] *= a3;
#pragma unroll
        for (int c = 0; c < 2; ++c) {
          const int vrow = dt * 16 + l15;
          bf8 vfh = *reinterpret_cast<const bf8*>(&Vth[vrow * 72 + c * 32 + quad * 8]);
          bf8 vfl = *reinterpret_cast<const bf8*>(&Vtl[vrow * 72 + c * 32 + quad * 8]);
          o[dt] = __builtin_amdgcn_mfma_f32_16x16x32_bf16(ph[c], vfh, o[dt], 0, 0, 0);
          o[dt] = __builtin_amdgcn_mfma_f32_16x16x32_bf16(ph[c], vfl, o[dt], 0, 0, 0);
          o[dt] = __builtin_amdgcn_mfma_f32_16x16x32_bf16(pl[c], vfh, o[dt], 0, 0, 0);
        }
      }
    }
    __syncthreads();
  }
  // finalize: row = wave*16 + quad*4 + r, col = h*32 + dt*16 + l15; write split planes
#pragma unroll
  for (int r = 0; r < 4; ++r) {
    float inv = 1.f / ls[wave * 16 + quad * 4 + r];
    size_t row = tbase + wave * 16 + quad * 4 + r;
#pragma unroll
    for (int dt = 0; dt < 2; ++dt) {
      float v = o[dt][r] * inv;
      short hb_ = f2bf(v);
      size_t off = row * 128 + h * 32 + dt * 16 + l15;
      oh[off] = (unsigned short)hb_;
      ol[off] = (unsigned short)f2bf(v - bf2f(hb_));
    }
  }
}

// =============== final layernorm: fp32 in -> split planes out ===============
__global__ __launch_bounds__(128) void final_ln(
    const float* __restrict__ in, unsigned short* __restrict__ oh,
    unsigned short* __restrict__ ol, const float* __restrict__ g,
    const float* __restrict__ bb) {
  const int t = blockIdx.x, d = threadIdx.x;
  const size_t base = (size_t)t * 128;
  float x = in[base + d];
  float s = x;
#pragma unroll
  for (int o = 1; o < 64; o <<= 1) s += __shfl_xor(s, o);
  __shared__ float red[2], red2[2];
  if ((d & 63) == 0) red[d >> 6] = s;
  __syncthreads();
  float mean = (red[0] + red[1]) * 0.0078125f;
  float v = x - mean;
  float s2 = v * v;
#pragma unroll
  for (int o = 1; o < 64; o <<= 1) s2 += __shfl_xor(s2, o);
  if ((d & 63) == 0) red2[d >> 6] = s2;
  __syncthreads();
  float var = (red2[0] + red2[1]) * 0.0078125f;
  float y = v * rsqrtf(var + 1e-5f) * g[d] + bb[d];
  short hb_ = f2bf(y);
  oh[base + d] = (unsigned short)hb_;
  ol[base + d] = (unsigned short)f2bf(y - bf2f(hb_));
}

__global__ __launch_bounds__(256) void loss_finalize2(const float* __restrict__ lp,
                                                      float* __restrict__ out) {
  float s = 0.f;
  for (int i = threadIdx.x; i < 2048; i += 256) s += lp[i];
#pragma unroll
  for (int o = 1; o < 64; o <<= 1) s += __shfl_xor(s, o);
  __shared__ float red[4];
  if ((threadIdx.x & 63) == 0) red[threadIdx.x >> 6] = s;
  __syncthreads();
  if (threadIdx.x == 0)
    out[0] = 1.25f * (red[0] + red[1] + red[2] + red[3]) / 2097152.0f;
}

extern "C" void kernel_launch(void* const* d_in, const int* in_sizes, int n_in,
                              void* d_out, int out_size, void* d_ws, size_t ws_size,
                              hipStream_t stream) {
  const float* x      = (const float*)d_in[0];
  const float* enc_w1 = (const float*)d_in[1];
  const float* enc_b1 = (const float*)d_in[2];
  const float* enc_w2 = (const float*)d_in[3];
  const float* enc_b2 = (const float*)d_in[4];
  const float* enc_w3 = (const float*)d_in[5];
  const float* enc_b3 = (const float*)d_in[6];
  const float* res_w1 = (const float*)d_in[7];
  const float* res_b1 = (const float*)d_in[8];
  const float* res_w2 = (const float*)d_in[9];
  const float* res_b2 = (const float*)d_in[10];
  const float* pre_w  = (const float*)d_in[11];
  const float* pre_b  = (const float*)d_in[12];
  const float* codebook = (const float*)d_in[13];
  const float* pos_emb  = (const float*)d_in[14];
  const float* qkv_w  = (const float*)d_in[15];
  const float* qkv_b  = (const float*)d_in[16];
  const float* proj_w = (const float*)d_in[17];
  const float* proj_b = (const float*)d_in[18];
  const float* ln1_g  = (const float*)d_in[19];
  const float* ln1_b  = (const float*)d_in[20];
  const float* ln2_g  = (const float*)d_in[21];
  const float* ln2_b  = (const float*)d_in[22];
  const float* ffn_w1 = (const float*)d_in[23];
  const float* ffn_b1 = (const float*)d_in[24];
  const float* ffn_w2 = (const float*)d_in[25];
  const float* ffn_b2 = (const float*)d_in[26];
  const float* fin_g  = (const float*)d_in[27];
  const float* fin_b  = (const float*)d_in[28];
  const float* head_w = (const float*)d_in[29];
  const float* head_b = (const float*)d_in[30];

  float* out = (float*)d_out;
  float* ws  = (float*)d_ws;

  // ws: keys(32768f) | cn(1024) | lpart(2048) | wh/wl planes | hhln planes  (~11 MB)
  unsigned long long* keys = (unsigned long long*)ws;
  float* cn    = ws + 32768;
  float* lpart = ws + 33792;
  unsigned short* wh = (unsigned short*)(ws + 36864);
  unsigned short* wl = (unsigned short*)(ws + 36864 + 327680);
  unsigned short* hhln_h = (unsigned short*)(ws + 692224);
  unsigned short* hhln_l = (unsigned short*)(ws + 692224 + 1048576);

  // d_out scratch overlay (float offsets; all < 2^24, dead before head GEMM)
  float* zf = out;                                            // [0 .. 2^21)
  float* hh = out + 2097152;                                  // [2^21 .. 2^22)
  unsigned short* hh_h   = (unsigned short*)(out + 4194304);
  unsigned short* hh_l   = (unsigned short*)(out + 5242880);
  unsigned short* qkvb_h = (unsigned short*)(out + 6291456);
  unsigned short* qkvb_l = (unsigned short*)(out + 9437184);
  unsigned short* oatt_h = (unsigned short*)(out + 12582912);
  unsigned short* oatt_l = (unsigned short*)(out + 13631488);
  unsigned short* fbuf_h = (unsigned short*)(out + 0);        // overlays zf (dead)
  unsigned short* fbuf_l = (unsigned short*)(out + 14680064);

  // weight-plane offsets
  const int W_QKV = 0, W_PROJ = 196608, W_F1 = 262144, W_F2 = 393216, W_HEAD = 524288;

  hipMemsetAsync(keys, 0xFF, NPATCH * sizeof(unsigned long long), stream);

  encoder3<<<1024, 256, 0, stream>>>(x, enc_w1, enc_b1, enc_w2, enc_b2,
                                     enc_w3, enc_b3, res_w1, res_b1,
                                     res_w2, res_b2, pre_w, pre_b, zf);
  split_w<<<2560, 256, 0, stream>>>(qkv_w, proj_w, ffn_w1, ffn_w2, head_w, wh, wl);
  cb_norms<<<4, 256, 0, stream>>>(codebook, cn);
  vq_argmin<<<dim3(16, 256), 256, 0, stream>>>(zf, codebook, cn, keys);
  vq_gather3<<<2048, 256, 0, stream>>>(zf, codebook, pos_emb, keys, hh, hh_h, hh_l,
                                       lpart, out + IDX_OFF);
  for (int i = 0; i < 4; ++i) {
    mgemm2<0, 1><<<dim3(6, 128), 256, 0, stream>>>(
        hh_h, hh_l, wh + W_QKV + i * 49152, wl + W_QKV + i * 49152,
        qkv_b + i * 384, nullptr, qkvb_h, qkvb_l, 384);
    attn3<<<dim3(8, 4, 32), 256, 0, stream>>>(qkvb_h, qkvb_l, oatt_h, oatt_l);
    mgemm_ln2<128><<<256, 256, 0, stream>>>(
        oatt_h, oatt_l, wh + W_PROJ + i * 16384, wl + W_PROJ + i * 16384,
        proj_b + i * 128, hh, ln1_g + i * 128, ln1_b + i * 128, hh, hh_h, hh_l);
    mgemm2<1, 1><<<dim3(4, 128), 256, 0, stream>>>(
        hh_h, hh_l, wh + W_F1 + i * 32768, wl + W_F1 + i * 32768,
        ffn_b1 + i * 256, nullptr, fbuf_h, fbuf_l, 256);
    mgemm_ln2<256><<<256, 256, 0, stream>>>(
        fbuf_h, fbuf_l, wh + W_F2 + i * 32768, wl + W_F2 + i * 32768,
        ffn_b2 + i * 128, hh, ln2_g + i * 128, ln2_b + i * 128, hh, hh_h, hh_l);
  }
  final_ln<<<NPATCH, 128, 0, stream>>>(hh, hhln_h, hhln_l, fin_g, fin_b);
  mgemm2<0, 0><<<dim3(16, 128), 256, 0, stream>>>(
      hhln_h, hhln_l, wh + W_HEAD, wl + W_HEAD, head_b, out, nullptr, nullptr, 1024);
  loss_finalize2<<<1, 256, 0, stream>>>(lpart, out + LOSS_OFF);
}

// Round 5
// 773.809 us; speedup vs baseline: 4.3182x; 1.0041x over previous
//
#include <hip/hip_runtime.h>
#include <math.h>

// ---- problem constants ----
#define NPATCH 16384          // B * T / P
#define SEQ    512            // T / P
#define LOSS_OFF 16777216
#define IDX_OFF  16777217

typedef short bf8 __attribute__((ext_vector_type(8)));    // 8 bf16 (4 VGPRs)
typedef float f32x4 __attribute__((ext_vector_type(4)));  // MFMA acc

__device__ inline short f2bf(float x) {          // fp32 -> bf16 RNE
  unsigned u = __float_as_uint(x);
  u += 0x7fffu + ((u >> 16) & 1u);
  return (short)(u >> 16);
}
__device__ inline float bf2f(short h) {
  return __uint_as_float(((unsigned)(unsigned short)h) << 16);
}

// ====== encoder v3b: 16 patches/block, stride-17 LDS (kills 4-way bank conflicts) ======
#define EST 17
__global__ __launch_bounds__(256) void encoder3(
    const float* __restrict__ x,
    const float* __restrict__ w1, const float* __restrict__ b1,
    const float* __restrict__ w2, const float* __restrict__ b2,
    const float* __restrict__ w3, const float* __restrict__ b3,
    const float* __restrict__ rw1, const float* __restrict__ rb1,
    const float* __restrict__ rw2, const float* __restrict__ rb2,
    const float* __restrict__ pw, const float* __restrict__ pb,
    float* __restrict__ z) {
  __shared__ float ar[8704];           // 34.8 KB arena (4 blocks/CU)
  float* H1 = ar;                      // [256 feat][EST]
  float* H2 = ar + 4352;               // [256 feat][EST]
  float* XS = ar + 4352;               // [16][16] overlays H2
  float* H3 = ar;                      // overlays H1 after conv3
  float* T1 = ar + 4352;               // [128][EST] overlays H2
  const int blk = blockIdx.x, tid = threadIdx.x;
  const int n = tid & 15, g = tid >> 4;   // patch-in-block, feature group 0..15

  if (tid < 64) {
    int p = tid >> 2, i = (tid & 3) * 4;
    float4 v = *reinterpret_cast<const float4*>(x + ((size_t)blk * 16 + p) * 16 + i);
    XS[(i + 0) * 16 + p] = v.x; XS[(i + 1) * 16 + p] = v.y;
    XS[(i + 2) * 16 + p] = v.z; XS[(i + 3) * 16 + p] = v.w;
  }
  __syncthreads();
  { // conv1: 1->32ch, L16->8, k4 s2 p1, relu.  thread: ch=g*2+c (c0..1), l0..7
    float xv[16];
#pragma unroll
    for (int i = 0; i < 16; ++i) xv[i] = XS[i * 16 + n];
#pragma unroll
    for (int c = 0; c < 2; ++c) {
      int ch = g * 2 + c;
      float4 wv = *reinterpret_cast<const float4*>(w1 + ch * 4);
      float bs = b1[ch];
      float w[4] = {wv.x, wv.y, wv.z, wv.w};
#pragma unroll
      for (int l = 0; l < 8; ++l) {
        float acc = bs;
#pragma unroll
        for (int kk = 0; kk < 4; ++kk) {
          int xi = 2 * l + kk - 1;
          if (xi >= 0 && xi < 16) acc += xv[xi] * w[kk];
        }
        H1[(ch * 8 + l) * EST + n] = fmaxf(acc, 0.f);
      }
    }
  }
  __syncthreads();
  { // conv2: 32->64ch, L8->4, k4 s2 p1, relu.  thread: co=g*4+c, l0..3
    float acc[4][4];
#pragma unroll
    for (int c = 0; c < 4; ++c) {
      float bs = b2[g * 4 + c];
#pragma unroll
      for (int l = 0; l < 4; ++l) acc[c][l] = bs;
    }
    for (int ci = 0; ci < 32; ++ci) {
      float hv[8];
#pragma unroll
      for (int xi = 0; xi < 8; ++xi) hv[xi] = H1[(ci * 8 + xi) * EST + n];
#pragma unroll
      for (int c = 0; c < 4; ++c) {
        float4 wv = *reinterpret_cast<const float4*>(w2 + ((g * 4 + c) * 32 + ci) * 4);
        float w[4] = {wv.x, wv.y, wv.z, wv.w};
#pragma unroll
        for (int l = 0; l < 4; ++l)
#pragma unroll
          for (int kk = 0; kk < 4; ++kk) {
            int xi = 2 * l + kk - 1;
            if (xi >= 0 && xi < 8) acc[c][l] += hv[xi] * w[kk];
          }
      }
    }
    __syncthreads();
#pragma unroll
    for (int c = 0; c < 4; ++c)
#pragma unroll
      for (int l = 0; l < 4; ++l)
        H2[((g * 4 + c) * 4 + l) * EST + n] = fmaxf(acc[c][l], 0.f);
  }
  __syncthreads();
  { // conv3: 64->64ch, L4, k3 p1.  thread: co=g*4+c, l0..3
    float acc[4][4];
#pragma unroll
    for (int c = 0; c < 4; ++c) {
      float bs = b3[g * 4 + c];
#pragma unroll
      for (int l = 0; l < 4; ++l) acc[c][l] = bs;
    }
    for (int ci = 0; ci < 64; ++ci) {
      float hv[4];
#pragma unroll
      for (int xi = 0; xi < 4; ++xi) hv[xi] = H2[(ci * 4 + xi) * EST + n];
#pragma unroll
      for (int c = 0; c < 4; ++c) {
        const float* wp = w3 + ((g * 4 + c) * 64 + ci) * 3;
        float w0 = wp[0], w1v = wp[1], w2v = wp[2];
#pragma unroll
        for (int l = 0; l < 4; ++l) {
          if (l - 1 >= 0) acc[c][l] += hv[l - 1] * w0;
          acc[c][l] += hv[l] * w1v;
          if (l + 1 < 4) acc[c][l] += hv[l + 1] * w2v;
        }
      }
    }
    __syncthreads();
#pragma unroll
    for (int c = 0; c < 4; ++c)
#pragma unroll
      for (int l = 0; l < 4; ++l)
        H3[((g * 4 + c) * 4 + l) * EST + n] = acc[c][l];
  }
  __syncthreads();
  for (int rl = 0; rl < 2; ++rl) {
    { // stage a: co=g*2+c (c0..1), l0..3
      float acc[2][4];
#pragma unroll
      for (int c = 0; c < 2; ++c) {
        float bs = rb1[rl * 32 + g * 2 + c];
#pragma unroll
        for (int l = 0; l < 4; ++l) acc[c][l] = bs;
      }
      for (int ci = 0; ci < 64; ++ci) {
        float hv[4];
#pragma unroll
        for (int xi = 0; xi < 4; ++xi) hv[xi] = fmaxf(H3[(ci * 4 + xi) * EST + n], 0.f);
#pragma unroll
        for (int c = 0; c < 2; ++c) {
          const float* wp = rw1 + ((rl * 32 + g * 2 + c) * 64 + ci) * 3;
          float w0 = wp[0], w1v = wp[1], w2v = wp[2];
#pragma unroll
          for (int l = 0; l < 4; ++l) {
            if (l - 1 >= 0) acc[c][l] += hv[l - 1] * w0;
            acc[c][l] += hv[l] * w1v;
            if (l + 1 < 4) acc[c][l] += hv[l + 1] * w2v;
          }
        }
      }
      __syncthreads();
#pragma unroll
      for (int c = 0; c < 2; ++c)
#pragma unroll
        for (int l = 0; l < 4; ++l)
          T1[((g * 2 + c) * 4 + l) * EST + n] = acc[c][l];
    }
    __syncthreads();
    { // stage b: co=g*4+c, l0..3
      float acc[4][4];
#pragma unroll
      for (int c = 0; c < 4; ++c) {
        float bs = rb2[rl * 64 + g * 4 + c];
#pragma unroll
        for (int l = 0; l < 4; ++l) acc[c][l] = bs;
      }
      for (int ci = 0; ci < 32; ++ci) {
        float tv[4];
#pragma unroll
        for (int l = 0; l < 4; ++l) tv[l] = fmaxf(T1[(ci * 4 + l) * EST + n], 0.f);
#pragma unroll
        for (int c = 0; c < 4; ++c) {
          float w = rw2[(rl * 64 + g * 4 + c) * 32 + ci];
#pragma unroll
          for (int l = 0; l < 4; ++l) acc[c][l] += tv[l] * w;
        }
      }
#pragma unroll
      for (int c = 0; c < 4; ++c)
#pragma unroll
        for (int l = 0; l < 4; ++l)
          H3[((g * 4 + c) * 4 + l) * EST + n] += acc[c][l];
    }
    __syncthreads();
  }
  { // pre 1x1: relu(h3) 64->32ch.  thread: e=g*2+c (c0..1), l0..3
    float acc[2][4];
#pragma unroll
    for (int c = 0; c < 2; ++c) {
      float bs = pb[g * 2 + c];
#pragma unroll
      for (int l = 0; l < 4; ++l) acc[c][l] = bs;
    }
    for (int ci = 0; ci < 64; ++ci) {
      float hv[4];
#pragma unroll
      for (int l = 0; l < 4; ++l) hv[l] = fmaxf(H3[(ci * 4 + l) * EST + n], 0.f);
#pragma unroll
      for (int c = 0; c < 2; ++c) {
        float w = pw[(g * 2 + c) * 64 + ci];
#pragma unroll
        for (int l = 0; l < 4; ++l) acc[c][l] += hv[l] * w;
      }
    }
#pragma unroll
    for (int c = 0; c < 2; ++c) {
      float4 v = {acc[c][0], acc[c][1], acc[c][2], acc[c][3]};
      *reinterpret_cast<float4*>(z + ((size_t)blk * 16 + n) * 128 + (g * 2 + c) * 4) = v;
    }
  }
}

// =============== weight pre-split: fp32 -> hi/lo bf16 planes (once/launch) ===============
__global__ __launch_bounds__(256) void split_w(
    const float* __restrict__ qkv_w, const float* __restrict__ proj_w,
    const float* __restrict__ f1, const float* __restrict__ f2,
    const float* __restrict__ hw, unsigned short* __restrict__ wh,
    unsigned short* __restrict__ wl) {
  int i = blockIdx.x * 256 + threadIdx.x;
  float v;
  if (i < 196608) v = qkv_w[i];
  else if (i < 262144) v = proj_w[i - 196608];
  else if (i < 393216) v = f1[i - 262144];
  else if (i < 524288) v = f2[i - 393216];
  else v = hw[i - 524288];
  short h = f2bf(v);
  wh[i] = (unsigned short)h;
  wl[i] = (unsigned short)f2bf(v - bf2f(h));
}

// ====== VQ part 2 v2: fp32 GEMM z.cb^T + inline |c|^2 + fused argmin ======
// tile 128(M) x 128(N), 8x8 micro-tile, K=128.  fp32 for argmin exactness.
__global__ __launch_bounds__(256) void vq_argmin2(
    const float* __restrict__ A, const float* __restrict__ B,
    unsigned long long* __restrict__ keys) {
  __shared__ float Ask[32][132];
  __shared__ float Bsk[32][132];
  __shared__ float cns[128];
  const int tid = threadIdx.x;
  const int n0 = blockIdx.x * 128, m0 = blockIdx.y * 128;
  const int ty = tid >> 4, tx = tid & 15;
  const int lr = tid >> 1, lh = (tid & 1) * 16;
  float acc[8][8] = {};
  float cn_part = 0.f;
  for (int k0 = 0; k0 < 128; k0 += 32) {
    const float4* ap = reinterpret_cast<const float4*>(A + (size_t)(m0 + lr) * 128 + k0 + lh);
    const float4* bp = reinterpret_cast<const float4*>(B + (size_t)(n0 + lr) * 128 + k0 + lh);
#pragma unroll
    for (int q = 0; q < 4; ++q) {
      float4 av = ap[q];
      Ask[lh + q * 4 + 0][lr] = av.x; Ask[lh + q * 4 + 1][lr] = av.y;
      Ask[lh + q * 4 + 2][lr] = av.z; Ask[lh + q * 4 + 3][lr] = av.w;
      float4 bv = bp[q];
      Bsk[lh + q * 4 + 0][lr] = bv.x; Bsk[lh + q * 4 + 1][lr] = bv.y;
      Bsk[lh + q * 4 + 2][lr] = bv.z; Bsk[lh + q * 4 + 3][lr] = bv.w;
      cn_part += bv.x * bv.x + bv.y * bv.y + bv.z * bv.z + bv.w * bv.w;
    }
    __syncthreads();
#pragma unroll 8
    for (int kk = 0; kk < 32; ++kk) {
      float a[8], b[8];
      *reinterpret_cast<float4*>(&a[0]) = *reinterpret_cast<const float4*>(&Ask[kk][ty * 8]);
      *reinterpret_cast<float4*>(&a[4]) = *reinterpret_cast<const float4*>(&Ask[kk][ty * 8 + 4]);
      *reinterpret_cast<float4*>(&b[0]) = *reinterpret_cast<const float4*>(&Bsk[kk][tx * 4]);
      *reinterpret_cast<float4*>(&b[4]) = *reinterpret_cast<const float4*>(&Bsk[kk][64 + tx * 4]);
#pragma unroll
      for (int ii = 0; ii < 8; ++ii)
#pragma unroll
        for (int jj = 0; jj < 8; ++jj) acc[ii][jj] += a[ii] * b[jj];
    }
    __syncthreads();
  }
  // codebook norms: thread pair (lr) holds the two 64-k halves of col n0+lr
  cn_part += __shfl_xor(cn_part, 1);
  if ((tid & 1) == 0) cns[lr] = cn_part;
  __syncthreads();
  float cnv[8];
#pragma unroll
  for (int jj = 0; jj < 4; ++jj) {
    cnv[jj] = cns[tx * 4 + jj];
    cnv[4 + jj] = cns[64 + tx * 4 + jj];
  }
#pragma unroll
  for (int ii = 0; ii < 8; ++ii) {
    int row = m0 + ty * 8 + ii;
    unsigned long long key = ~0ull;
#pragma unroll
    for (int jj = 0; jj < 8; ++jj) {
      int j = n0 + (jj < 4 ? tx * 4 + jj : 64 + tx * 4 + (jj - 4));
      float dv = cnv[jj] - 2.f * acc[ii][jj];   // |c|^2 - 2 z.c
      unsigned u = __float_as_uint(dv);
      u = (u & 0x80000000u) ? ~u : (u | 0x80000000u);  // order-preserving
      unsigned long long k = ((unsigned long long)u << 32) | (unsigned)j;
      key = k < key ? k : key;
    }
#pragma unroll
    for (int off = 1; off < 16; off <<= 1) {
      unsigned long long o = __shfl_xor(key, off);
      key = o < key ? o : key;
    }
    if (tx == 0) atomicMin(&keys[row], key);
  }
}

// ===== VQ part 3: gather q, loss partials, hh = q + pos (fp32 + split planes) =====
__global__ __launch_bounds__(256) void vq_gather3(
    const float* __restrict__ z, const float* __restrict__ cb,
    const float* __restrict__ pos, const unsigned long long* __restrict__ keys,
    float* __restrict__ hh, unsigned short* __restrict__ hh_h,
    unsigned short* __restrict__ hh_l, float* __restrict__ lpart,
    float* __restrict__ idx_out) {
  const int blk = blockIdx.x, tid = threadIdx.x;
  __shared__ int sidx[8];
  if (tid < 8) {
    unsigned long long k = keys[blk * 8 + tid];
    int id = (int)(unsigned)(k & 0xffffffffull);
    sidx[tid] = id;
    idx_out[blk * 8 + tid] = (float)id;
  }
  __syncthreads();
  const int p = tid >> 5, d = tid & 31;
  const size_t n = (size_t)blk * 8 + p;
  const int idx = sidx[p];
  float4 q = *reinterpret_cast<const float4*>(cb + (size_t)idx * 128 + d * 4);
  float4 zv = *reinterpret_cast<const float4*>(z + n * 128 + d * 4);
  float4 pv = *reinterpret_cast<const float4*>(pos + (size_t)(n & 511) * 128 + d * 4);
  float hv[4] = {q.x + pv.x, q.y + pv.y, q.z + pv.z, q.w + pv.w};
  *reinterpret_cast<float4*>(hh + n * 128 + d * 4) = *reinterpret_cast<float4*>(hv);
  ushort4 h4, l4;
  unsigned short* hp = (unsigned short*)&h4;
  unsigned short* lp = (unsigned short*)&l4;
#pragma unroll
  for (int e = 0; e < 4; ++e) {
    short hb = f2bf(hv[e]);
    hp[e] = (unsigned short)hb;
    lp[e] = (unsigned short)f2bf(hv[e] - bf2f(hb));
  }
  *reinterpret_cast<ushort4*>(&hh_h[n * 128 + d * 4]) = h4;
  *reinterpret_cast<ushort4*>(&hh_l[n * 128 + d * 4]) = l4;
  float dx = q.x - zv.x, dy = q.y - zv.y, dz = q.z - zv.z, dw = q.w - zv.w;
  float part = dx * dx + dy * dy + dz * dz + dw * dw;
#pragma unroll
  for (int o = 1; o < 64; o <<= 1) part += __shfl_xor(part, o);
  __shared__ float lred[4];
  if ((tid & 63) == 0) lred[tid >> 6] = part;
  __syncthreads();
  if (tid == 0) lpart[blk] = lred[0] + lred[1] + lred[2] + lred[3];
}

// ====== split-bf16 MFMA GEMM (pre-split inputs): C = A[M,128]*B[N,128]^T + bias ======
// tile 128(M) x 64(N).  ACT: 0=none 1=gelu.  SPLIT: 1 -> write hi/lo planes, 0 -> fp32.
template <int ACT, int SPLIT>
__global__ __launch_bounds__(256) void mgemm2(
    const unsigned short* __restrict__ Ahg, const unsigned short* __restrict__ Alg,
    const unsigned short* __restrict__ Bhg, const unsigned short* __restrict__ Blg,
    const float* __restrict__ bias, float* __restrict__ C,
    unsigned short* __restrict__ Ch, unsigned short* __restrict__ Cl, int N) {
  __shared__ short Ah[128 * 40], Al[128 * 40], Bh[64 * 40], Bl[64 * 40];
  const int tid = threadIdx.x;
  const int n0 = blockIdx.x * 64, m0 = blockIdx.y * 128;
  const int wave = tid >> 6, lane = tid & 63, quad = lane >> 4, l15 = lane & 15;
  const f32x4 z4 = {0.f, 0.f, 0.f, 0.f};
  f32x4 acc[2][4];
#pragma unroll
  for (int i = 0; i < 2; ++i)
#pragma unroll
    for (int j = 0; j < 4; ++j) acc[i][j] = z4;

  const int ra = tid >> 1, ha = (tid & 1) * 16;         // A: 128 rows, 16 shorts each
  const int rb = tid >> 2, hb = (tid & 3) * 8;          // B: 64 rows, 8 shorts each
  for (int k0 = 0; k0 < 128; k0 += 32) {
    {
      const size_t abase = (size_t)(m0 + ra) * 128 + k0 + ha;
      *reinterpret_cast<bf8*>(&Ah[ra * 40 + ha])     = *reinterpret_cast<const bf8*>(&Ahg[abase]);
      *reinterpret_cast<bf8*>(&Ah[ra * 40 + ha + 8]) = *reinterpret_cast<const bf8*>(&Ahg[abase + 8]);
      *reinterpret_cast<bf8*>(&Al[ra * 40 + ha])     = *reinterpret_cast<const bf8*>(&Alg[abase]);
      *reinterpret_cast<bf8*>(&Al[ra * 40 + ha + 8]) = *reinterpret_cast<const bf8*>(&Alg[abase + 8]);
      const size_t bbase = (size_t)(n0 + rb) * 128 + k0 + hb;
      *reinterpret_cast<bf8*>(&Bh[rb * 40 + hb]) = *reinterpret_cast<const bf8*>(&Bhg[bbase]);
      *reinterpret_cast<bf8*>(&Bl[rb * 40 + hb]) = *reinterpret_cast<const bf8*>(&Blg[bbase]);
    }
    __syncthreads();
    bf8 af[2], afl[2], bfh[4], bfl[4];
#pragma unroll
    for (int mt = 0; mt < 2; ++mt) {
      int row = wave * 32 + mt * 16 + l15;
      af[mt]  = *reinterpret_cast<const bf8*>(&Ah[row * 40 + quad * 8]);
      afl[mt] = *reinterpret_cast<const bf8*>(&Al[row * 40 + quad * 8]);
    }
#pragma unroll
    for (int nt = 0; nt < 4; ++nt) {
      int row = nt * 16 + l15;
      bfh[nt] = *reinterpret_cast<const bf8*>(&Bh[row * 40 + quad * 8]);
      bfl[nt] = *reinterpret_cast<const bf8*>(&Bl[row * 40 + quad * 8]);
    }
#pragma unroll
    for (int nt = 0; nt < 4; ++nt)
#pragma unroll
      for (int mt = 0; mt < 2; ++mt)
        acc[mt][nt] = __builtin_amdgcn_mfma_f32_16x16x32_bf16(af[mt], bfh[nt], acc[mt][nt], 0, 0, 0);
#pragma unroll
    for (int nt = 0; nt < 4; ++nt)
#pragma unroll
      for (int mt = 0; mt < 2; ++mt)
        acc[mt][nt] = __builtin_amdgcn_mfma_f32_16x16x32_bf16(af[mt], bfl[nt], acc[mt][nt], 0, 0, 0);
#pragma unroll
    for (int nt = 0; nt < 4; ++nt)
#pragma unroll
      for (int mt = 0; mt < 2; ++mt)
        acc[mt][nt] = __builtin_amdgcn_mfma_f32_16x16x32_bf16(afl[mt], bfh[nt], acc[mt][nt], 0, 0, 0);
    __syncthreads();
  }
#pragma unroll
  for (int nt = 0; nt < 4; ++nt) {
    int col = n0 + nt * 16 + l15;
    float bv = bias[col];
#pragma unroll
    for (int mt = 0; mt < 2; ++mt) {
      int rbase = m0 + wave * 32 + mt * 16 + quad * 4;
#pragma unroll
      for (int r = 0; r < 4; ++r) {
        float v = acc[mt][nt][r] + bv;
        if (ACT == 1) v = 0.5f * v * (1.f + erff(v * 0.7071067811865476f));
        if (SPLIT) {
          short hb_ = f2bf(v);
          Ch[(size_t)(rbase + r) * N + col] = (unsigned short)hb_;
          Cl[(size_t)(rbase + r) * N + col] = (unsigned short)f2bf(v - bf2f(hb_));
        } else {
          C[(size_t)(rbase + r) * N + col] = v;
        }
      }
    }
  }
}

// == split-bf16 MFMA GEMM + residual + LN (optionally + second/final LN) ==
// out = LN(A.B^T+bias+res)*g+b; FINAL=1: y = LN2(out)*g2+b2 -> planes only.
// tile 64(M) x 128(N).  K: 128 or 256.
template <int K, int FINAL>
__global__ __launch_bounds__(256) void mgemm_ln2(
    const unsigned short* __restrict__ Ahg, const unsigned short* __restrict__ Alg,
    const unsigned short* __restrict__ Bhg, const unsigned short* __restrict__ Blg,
    const float* __restrict__ bias, const float* __restrict__ res,
    const float* __restrict__ g, const float* __restrict__ bb,
    const float* __restrict__ g2, const float* __restrict__ bb2,
    float* __restrict__ C, unsigned short* __restrict__ Ch,
    unsigned short* __restrict__ Cl) {
  __shared__ short Ah[64 * 40], Al[64 * 40], Bh[128 * 40], Bl[128 * 40];
  const int tid = threadIdx.x;
  const int m0 = blockIdx.x * 64;
  const int wave = tid >> 6, lane = tid & 63, quad = lane >> 4, l15 = lane & 15;
  const f32x4 z4 = {0.f, 0.f, 0.f, 0.f};
  f32x4 acc[8];
#pragma unroll
  for (int j = 0; j < 8; ++j) acc[j] = z4;

  const int ra = tid >> 2, ha = (tid & 3) * 8;          // A: 64 rows, 8 shorts each
  const int rb = tid >> 1, hb = (tid & 1) * 16;         // B: 128 rows, 16 shorts each
  for (int k0 = 0; k0 < K; k0 += 32) {
    {
      const size_t abase = (size_t)(m0 + ra) * K + k0 + ha;
      *reinterpret_cast<bf8*>(&Ah[ra * 40 + ha]) = *reinterpret_cast<const bf8*>(&Ahg[abase]);
      *reinterpret_cast<bf8*>(&Al[ra * 40 + ha]) = *reinterpret_cast<const bf8*>(&Alg[abase]);
      const size_t bbase = (size_t)rb * K + k0 + hb;
      *reinterpret_cast<bf8*>(&Bh[rb * 40 + hb])     = *reinterpret_cast<const bf8*>(&Bhg[bbase]);
      *reinterpret_cast<bf8*>(&Bh[rb * 40 + hb + 8]) = *reinterpret_cast<const bf8*>(&Bhg[bbase + 8]);
      *reinterpret_cast<bf8*>(&Bl[rb * 40 + hb])     = *reinterpret_cast<const bf8*>(&Blg[bbase]);
      *reinterpret_cast<bf8*>(&Bl[rb * 40 + hb + 8]) = *reinterpret_cast<const bf8*>(&Blg[bbase + 8]);
    }
    __syncthreads();
    bf8 af, afl, bfh[8], bfl[8];
    {
      int row = wave * 16 + l15;
      af  = *reinterpret_cast<const bf8*>(&Ah[row * 40 + quad * 8]);
      afl = *reinterpret_cast<const bf8*>(&Al[row * 40 + quad * 8]);
    }
#pragma unroll
    for (int nt = 0; nt < 8; ++nt) {
      int row = nt * 16 + l15;
      bfh[nt] = *reinterpret_cast<const bf8*>(&Bh[row * 40 + quad * 8]);
      bfl[nt] = *reinterpret_cast<const bf8*>(&Bl[row * 40 + quad * 8]);
    }
#pragma unroll
    for (int nt = 0; nt < 8; ++nt)
      acc[nt] = __builtin_amdgcn_mfma_f32_16x16x32_bf16(af, bfh[nt], acc[nt], 0, 0, 0);
#pragma unroll
    for (int nt = 0; nt < 8; ++nt)
      acc[nt] = __builtin_amdgcn_mfma_f32_16x16x32_bf16(af, bfl[nt], acc[nt], 0, 0, 0);
#pragma unroll
    for (int nt = 0; nt < 8; ++nt)
      acc[nt] = __builtin_amdgcn_mfma_f32_16x16x32_bf16(afl, bfh[nt], acc[nt], 0, 0, 0);
    __syncthreads();
  }
  float bias_v[8], g_v[8], bb_v[8], g2_v[8], bb2_v[8];
#pragma unroll
  for (int nt = 0; nt < 8; ++nt) {
    int col = nt * 16 + l15;
    bias_v[nt] = bias[col]; g_v[nt] = g[col]; bb_v[nt] = bb[col];
    if (FINAL) { g2_v[nt] = g2[col]; bb2_v[nt] = bb2[col]; }
  }
  const int rbase = m0 + wave * 16 + quad * 4;
#pragma unroll
  for (int r = 0; r < 4; ++r) {
    const int row = rbase + r;
    float ov[8];
    float s = 0.f;
#pragma unroll
    for (int nt = 0; nt < 8; ++nt) {
      ov[nt] = acc[nt][r] + bias_v[nt] + res[(size_t)row * 128 + nt * 16 + l15];
      s += ov[nt];
    }
    s += __shfl_xor(s, 1); s += __shfl_xor(s, 2);
    s += __shfl_xor(s, 4); s += __shfl_xor(s, 8);
    float mean = s * 0.0078125f;
    float s2 = 0.f;
#pragma unroll
    for (int nt = 0; nt < 8; ++nt) { ov[nt] -= mean; s2 += ov[nt] * ov[nt]; }
    s2 += __shfl_xor(s2, 1); s2 += __shfl_xor(s2, 2);
    s2 += __shfl_xor(s2, 4); s2 += __shfl_xor(s2, 8);
    float rstd = rsqrtf(s2 * 0.0078125f + 1e-5f);
    if (FINAL) {
      float yv[8];
      float s3 = 0.f;
#pragma unroll
      for (int nt = 0; nt < 8; ++nt) { yv[nt] = ov[nt] * rstd * g_v[nt] + bb_v[nt]; s3 += yv[nt]; }
      s3 += __shfl_xor(s3, 1); s3 += __shfl_xor(s3, 2);
      s3 += __shfl_xor(s3, 4); s3 += __shfl_xor(s3, 8);
      float mean2 = s3 * 0.0078125f;
      float s4 = 0.f;
#pragma unroll
      for (int nt = 0; nt < 8; ++nt) { yv[nt] -= mean2; s4 += yv[nt] * yv[nt]; }
      s4 += __shfl_xor(s4, 1); s4 += __shfl_xor(s4, 2);
      s4 += __shfl_xor(s4, 4); s4 += __shfl_xor(s4, 8);
      float rstd2 = rsqrtf(s4 * 0.0078125f + 1e-5f);
#pragma unroll
      for (int nt = 0; nt < 8; ++nt) {
        float v = yv[nt] * rstd2 * g2_v[nt] + bb2_v[nt];
        size_t off = (size_t)row * 128 + nt * 16 + l15;
        short hb_ = f2bf(v);
        Ch[off] = (unsigned short)hb_;
        Cl[off] = (unsigned short)f2bf(v - bf2f(hb_));
      }
    } else {
#pragma unroll
      for (int nt = 0; nt < 8; ++nt) {
        float v = ov[nt] * rstd * g_v[nt] + bb_v[nt];
        size_t off = (size_t)row * 128 + nt * 16 + l15;
        C[off] = v;
        short hb_ = f2bf(v);
        Ch[off] = (unsigned short)hb_;
        Cl[off] = (unsigned short)f2bf(v - bf2f(hb_));
      }
    }
  }
}

// ====== MFMA flash attention: block per (qt,h,b); reads/writes split planes ======
__global__ __launch_bounds__(256) void attn3(
    const unsigned short* __restrict__ qh_, const unsigned short* __restrict__ ql_,
    unsigned short* __restrict__ oh, unsigned short* __restrict__ ol) {
  const int qt = blockIdx.x, h = blockIdx.y, b = blockIdx.z;
  __shared__ short Kh[64 * 40], Kl[64 * 40];     // [key][d]
  __shared__ short Vth[32 * 72], Vtl[32 * 72];   // [d][key]
  __shared__ float Ss[64 * 72];
  __shared__ float ms[64], ls[64], alphas[64];
  const int tid = threadIdx.x;
  const int wave = tid >> 6, lane = tid & 63, quad = lane >> 4, l15 = lane & 15;
  const size_t tbase = (size_t)b * 512 + qt * 64;
  bf8 qfh, qfl;
  {
    const size_t qoff = (tbase + wave * 16 + l15) * 384 + h * 32 + quad * 8;
    qfh = *reinterpret_cast<const bf8*>(&qh_[qoff]);
    qfl = *reinterpret_cast<const bf8*>(&ql_[qoff]);
  }
  if (tid < 64) { ms[tid] = -1e30f; ls[tid] = 0.f; }
  const f32x4 z4 = {0.f, 0.f, 0.f, 0.f};
  f32x4 o[2] = {z4, z4};
  const float scale = 0.17677669529663687f;  // 1/sqrt(32)
  const int sr = tid >> 2, sc8 = (tid & 3) * 8;
  for (int kt = 0; kt <= qt; ++kt) {
    const size_t kbase = (size_t)b * 512 + kt * 64;
    {
      const size_t koff = (kbase + sr) * 384 + 128 + h * 32 + sc8;
      *reinterpret_cast<bf8*>(&Kh[sr * 40 + sc8]) = *reinterpret_cast<const bf8*>(&qh_[koff]);
      *reinterpret_cast<bf8*>(&Kl[sr * 40 + sc8]) = *reinterpret_cast<const bf8*>(&ql_[koff]);
      const size_t voff = (kbase + sr) * 384 + 256 + h * 32 + sc8;
      bf8 vh8 = *reinterpret_cast<const bf8*>(&qh_[voff]);
      bf8 vl8 = *reinterpret_cast<const bf8*>(&ql_[voff]);
#pragma unroll
      for (int j = 0; j < 8; ++j) {
        Vth[(sc8 + j) * 72 + sr] = vh8[j];
        Vtl[(sc8 + j) * 72 + sr] = vl8[j];
      }
    }
    __syncthreads();
    {
#pragma unroll
      for (int nt = 0; nt < 4; ++nt) {
        const int krow = nt * 16 + l15;
        bf8 kfh = *reinterpret_cast<const bf8*>(&Kh[krow * 40 + quad * 8]);
        bf8 kfl = *reinterpret_cast<const bf8*>(&Kl[krow * 40 + quad * 8]);
        f32x4 s = z4;
        s = __builtin_amdgcn_mfma_f32_16x16x32_bf16(qfh, kfh, s, 0, 0, 0);
        s = __builtin_amdgcn_mfma_f32_16x16x32_bf16(qfh, kfl, s, 0, 0, 0);
        s = __builtin_amdgcn_mfma_f32_16x16x32_bf16(qfl, kfh, s, 0, 0, 0);
#pragma unroll
        for (int r = 0; r < 4; ++r) {
          int row64 = wave * 16 + quad * 4 + r;
          int col64 = nt * 16 + l15;
          float v = s[r] * scale;
          if (kt == qt && col64 > row64) v += -1e9f;
          Ss[row64 * 72 + col64] = v;
        }
      }
    }
    __syncthreads();
    {
      const int i = tid >> 2, q = tid & 3;
      float mx = -3.4e38f;
      float4 pv[4];
#pragma unroll
      for (int t = 0; t < 4; ++t) {
        pv[t] = *reinterpret_cast<const float4*>(&Ss[i * 72 + q * 16 + t * 4]);
        mx = fmaxf(mx, fmaxf(fmaxf(pv[t].x, pv[t].y), fmaxf(pv[t].z, pv[t].w)));
      }
      mx = fmaxf(mx, __shfl_xor(mx, 1));
      mx = fmaxf(mx, __shfl_xor(mx, 2));
      float mold = ms[i];
      mx = fmaxf(mx, mold);
      float sum = 0.f;
#pragma unroll
      for (int t = 0; t < 4; ++t) {
        pv[t].x = __expf(pv[t].x - mx); pv[t].y = __expf(pv[t].y - mx);
        pv[t].z = __expf(pv[t].z - mx); pv[t].w = __expf(pv[t].w - mx);
        sum += pv[t].x + pv[t].y + pv[t].z + pv[t].w;
        *reinterpret_cast<float4*>(&Ss[i * 72 + q * 16 + t * 4]) = pv[t];
      }
      sum += __shfl_xor(sum, 1);
      sum += __shfl_xor(sum, 2);
      if (q == 0) {
        float alpha = __expf(mold - mx);
        ls[i] = ls[i] * alpha + sum;
        ms[i] = mx;
        alphas[i] = alpha;
      }
    }
    __syncthreads();
    {
      bf8 ph[2], pl[2];
#pragma unroll
      for (int c = 0; c < 2; ++c) {
        const float* pp = &Ss[(wave * 16 + l15) * 72 + c * 32 + quad * 8];
        float4 p0 = *reinterpret_cast<const float4*>(pp);
        float4 p1 = *reinterpret_cast<const float4*>(pp + 4);
        float pf[8] = {p0.x, p0.y, p0.z, p0.w, p1.x, p1.y, p1.z, p1.w};
#pragma unroll
        for (int j = 0; j < 8; ++j) {
          short hb_ = f2bf(pf[j]);
          ph[c][j] = hb_;
          pl[c][j] = f2bf(pf[j] - bf2f(hb_));
        }
      }
      float a0 = alphas[wave * 16 + quad * 4 + 0];
      float a1 = alphas[wave * 16 + quad * 4 + 1];
      float a2 = alphas[wave * 16 + quad * 4 + 2];
      float a3 = alphas[wave * 16 + quad * 4 + 3];
#pragma unroll
      for (int dt = 0; dt < 2; ++dt) {
        o[dt][0] *= a0; o[dt][1] *= a1; o[dt][2] *= a2; o[dt][3] *= a3;
#pragma unroll
        for (int c = 0; c < 2; ++c) {
          const int vrow = dt * 16 + l15;
          bf8 vfh = *reinterpret_cast<const bf8*>(&Vth[vrow * 72 + c * 32 + quad * 8]);
          bf8 vfl = *reinterpret_cast<const bf8*>(&Vtl[vrow * 72 + c * 32 + quad * 8]);
          o[dt] = __builtin_amdgcn_mfma_f32_16x16x32_bf16(ph[c], vfh, o[dt], 0, 0, 0);
          o[dt] = __builtin_amdgcn_mfma_f32_16x16x32_bf16(ph[c], vfl, o[dt], 0, 0, 0);
          o[dt] = __builtin_amdgcn_mfma_f32_16x16x32_bf16(pl[c], vfh, o[dt], 0, 0, 0);
        }
      }
    }
    __syncthreads();
  }
#pragma unroll
  for (int r = 0; r < 4; ++r) {
    float inv = 1.f / ls[wave * 16 + quad * 4 + r];
    size_t row = tbase + wave * 16 + quad * 4 + r;
#pragma unroll
    for (int dt = 0; dt < 2; ++dt) {
      float v = o[dt][r] * inv;
      short hb_ = f2bf(v);
      size_t off = row * 128 + h * 32 + dt * 16 + l15;
      oh[off] = (unsigned short)hb_;
      ol[off] = (unsigned short)f2bf(v - bf2f(hb_));
    }
  }
}

__global__ __launch_bounds__(256) void loss_finalize2(const float* __restrict__ lp,
                                                      float* __restrict__ out) {
  float s = 0.f;
  for (int i = threadIdx.x; i < 2048; i += 256) s += lp[i];
#pragma unroll
  for (int o = 1; o < 64; o <<= 1) s += __shfl_xor(s, o);
  __shared__ float red[4];
  if ((threadIdx.x & 63) == 0) red[threadIdx.x >> 6] = s;
  __syncthreads();
  if (threadIdx.x == 0)
    out[0] = 1.25f * (red[0] + red[1] + red[2] + red[3]) / 2097152.0f;
}

extern "C" void kernel_launch(void* const* d_in, const int* in_sizes, int n_in,
                              void* d_out, int out_size, void* d_ws, size_t ws_size,
                              hipStream_t stream) {
  const float* x      = (const float*)d_in[0];
  const float* enc_w1 = (const float*)d_in[1];
  const float* enc_b1 = (const float*)d_in[2];
  const float* enc_w2 = (const float*)d_in[3];
  const float* enc_b2 = (const float*)d_in[4];
  const float* enc_w3 = (const float*)d_in[5];
  const float* enc_b3 = (const float*)d_in[6];
  const float* res_w1 = (const float*)d_in[7];
  const float* res_b1 = (const float*)d_in[8];
  const float* res_w2 = (const float*)d_in[9];
  const float* res_b2 = (const float*)d_in[10];
  const float* pre_w  = (const float*)d_in[11];
  const float* pre_b  = (const float*)d_in[12];
  const float* codebook = (const float*)d_in[13];
  const float* pos_emb  = (const float*)d_in[14];
  const float* qkv_w  = (const float*)d_in[15];
  const float* qkv_b  = (const float*)d_in[16];
  const float* proj_w = (const float*)d_in[17];
  const float* proj_b = (const float*)d_in[18];
  const float* ln1_g  = (const float*)d_in[19];
  const float* ln1_b  = (const float*)d_in[20];
  const float* ln2_g  = (const float*)d_in[21];
  const float* ln2_b  = (const float*)d_in[22];
  const float* ffn_w1 = (const float*)d_in[23];
  const float* ffn_b1 = (const float*)d_in[24];
  const float* ffn_w2 = (const float*)d_in[25];
  const float* ffn_b2 = (const float*)d_in[26];
  const float* fin_g  = (const float*)d_in[27];
  const float* fin_b  = (const float*)d_in[28];
  const float* head_w = (const float*)d_in[29];
  const float* head_b = (const float*)d_in[30];

  float* out = (float*)d_out;
  float* ws  = (float*)d_ws;

  // ws: keys(32768f) | lpart(2048) | pad | wh/wl planes | hhln planes
  unsigned long long* keys = (unsigned long long*)ws;
  float* lpart = ws + 32768;
  unsigned short* wh = (unsigned short*)(ws + 36864);
  unsigned short* wl = (unsigned short*)(ws + 36864 + 327680);
  unsigned short* hhln_h = (unsigned short*)(ws + 692224);
  unsigned short* hhln_l = (unsigned short*)(ws + 692224 + 1048576);

  // d_out scratch overlay (float offsets; dead before head GEMM)
  float* zf = out;                                            // [0 .. 2^21)
  float* hh = out + 2097152;                                  // [2^21 .. 2^22)
  unsigned short* hh_h   = (unsigned short*)(out + 4194304);
  unsigned short* hh_l   = (unsigned short*)(out + 5242880);
  unsigned short* qkvb_h = (unsigned short*)(out + 6291456);
  unsigned short* qkvb_l = (unsigned short*)(out + 9437184);
  unsigned short* oatt_h = (unsigned short*)(out + 12582912);
  unsigned short* oatt_l = (unsigned short*)(out + 13631488);
  unsigned short* fbuf_h = (unsigned short*)(out + 0);        // overlays zf (dead)
  unsigned short* fbuf_l = (unsigned short*)(out + 14680064);

  const int W_QKV = 0, W_PROJ = 196608, W_F1 = 262144, W_F2 = 393216, W_HEAD = 524288;

  hipMemsetAsync(keys, 0xFF, NPATCH * sizeof(unsigned long long), stream);

  encoder3<<<1024, 256, 0, stream>>>(x, enc_w1, enc_b1, enc_w2, enc_b2,
                                     enc_w3, enc_b3, res_w1, res_b1,
                                     res_w2, res_b2, pre_w, pre_b, zf);
  split_w<<<2560, 256, 0, stream>>>(qkv_w, proj_w, ffn_w1, ffn_w2, head_w, wh, wl);
  vq_argmin2<<<dim3(8, 128), 256, 0, stream>>>(zf, codebook, keys);
  vq_gather3<<<2048, 256, 0, stream>>>(zf, codebook, pos_emb, keys, hh, hh_h, hh_l,
                                       lpart, out + IDX_OFF);
  for (int i = 0; i < 4; ++i) {
    mgemm2<0, 1><<<dim3(6, 128), 256, 0, stream>>>(
        hh_h, hh_l, wh + W_QKV + i * 49152, wl + W_QKV + i * 49152,
        qkv_b + i * 384, nullptr, qkvb_h, qkvb_l, 384);
    attn3<<<dim3(8, 4, 32), 256, 0, stream>>>(qkvb_h, qkvb_l, oatt_h, oatt_l);
    mgemm_ln2<128, 0><<<256, 256, 0, stream>>>(
        oatt_h, oatt_l, wh + W_PROJ + i * 16384, wl + W_PROJ + i * 16384,
        proj_b + i * 128, hh, ln1_g + i * 128, ln1_b + i * 128,
        nullptr, nullptr, hh, hh_h, hh_l);
    mgemm2<1, 1><<<dim3(4, 128), 256, 0, stream>>>(
        hh_h, hh_l, wh + W_F1 + i * 32768, wl + W_F1 + i * 32768,
        ffn_b1 + i * 256, nullptr, fbuf_h, fbuf_l, 256);
    if (i < 3) {
      mgemm_ln2<256, 0><<<256, 256, 0, stream>>>(
          fbuf_h, fbuf_l, wh + W_F2 + i * 32768, wl + W_F2 + i * 32768,
          ffn_b2 + i * 128, hh, ln2_g + i * 128, ln2_b + i * 128,
          nullptr, nullptr, hh, hh_h, hh_l);
    } else {
      mgemm_ln2<256, 1><<<256, 256, 0, stream>>>(
          fbuf_h, fbuf_l, wh + W_F2 + i * 32768, wl + W_F2 + i * 32768,
          ffn_b2 + i * 128, hh, ln2_g + i * 128, ln2_b + i * 128,
          fin_g, fin_b, hh, hhln_h, hhln_l);
    }
  }
  mgemm2<0, 0><<<dim3(16, 128), 256, 0, stream>>>(
      hhln_h, hhln_l, wh + W_HEAD, wl + W_HEAD, head_b, out, nullptr, nullptr, 1024);
  loss_finalize2<<<1, 256, 0, stream>>>(lpart, out + LOSS_OFF);
}

// Round 6
// 754.804 us; speedup vs baseline: 4.4270x; 1.0252x over previous
//
#include <hip/hip_runtime.h>
#include <math.h>

// ---- problem constants ----
#define NPATCH 16384          // B * T / P
#define SEQ    512            // T / P
#define LOSS_OFF 16777216
#define IDX_OFF  16777217

typedef short bf8 __attribute__((ext_vector_type(8)));    // 8 bf16 (4 VGPRs)
typedef float f32x4 __attribute__((ext_vector_type(4)));  // MFMA acc

__device__ inline short f2bf(float x) {          // fp32 -> bf16 RNE
  unsigned u = __float_as_uint(x);
  u += 0x7fffu + ((u >> 16) & 1u);
  return (short)(u >> 16);
}
__device__ inline float bf2f(short h) {
  return __uint_as_float(((unsigned)(unsigned short)h) << 16);
}

// ====== encoder v4: 8 patches/block, stride-9 LDS, 18.4KB -> 8 blocks/CU ======
// launch_bounds(256,8): pin VGPR<=64 so occupancy is LDS-limited at 8 blocks/CU.
#define EST 9
__global__ __launch_bounds__(256, 8) void encoder4(
    const float* __restrict__ x,
    const float* __restrict__ w1, const float* __restrict__ b1,
    const float* __restrict__ w2, const float* __restrict__ b2,
    const float* __restrict__ w3, const float* __restrict__ b3,
    const float* __restrict__ rw1, const float* __restrict__ rb1,
    const float* __restrict__ rw2, const float* __restrict__ rb2,
    const float* __restrict__ pw, const float* __restrict__ pb,
    float* __restrict__ z) {
  __shared__ float ar[4608];           // 18.4 KB arena
  float* H1 = ar;                      // [256 feat][EST]
  float* H2 = ar + 2304;               // [256 feat][EST]
  float* XS = ar + 2304;               // [16][8] overlays H2
  float* H3 = ar;                      // overlays H1 after conv3
  float* T1 = ar + 2304;               // [128][EST] overlays H2
  const int blk = blockIdx.x, tid = threadIdx.x;
  const int n = tid & 7, g = tid >> 3;    // patch-in-block 0..7, feature group 0..31

  if (tid < 32) {
    int p = tid >> 2, i = (tid & 3) * 4;
    float4 v = *reinterpret_cast<const float4*>(x + ((size_t)blk * 8 + p) * 16 + i);
    XS[(i + 0) * 8 + p] = v.x; XS[(i + 1) * 8 + p] = v.y;
    XS[(i + 2) * 8 + p] = v.z; XS[(i + 3) * 8 + p] = v.w;
  }
  __syncthreads();
  { // conv1: 1->32ch, L16->8, k4 s2 p1, relu.  thread: ch=g, l0..7
    float xv[16];
#pragma unroll
    for (int i = 0; i < 16; ++i) xv[i] = XS[i * 8 + n];
    float4 wv = *reinterpret_cast<const float4*>(w1 + g * 4);
    float bs = b1[g];
    float w[4] = {wv.x, wv.y, wv.z, wv.w};
#pragma unroll
    for (int l = 0; l < 8; ++l) {
      float acc = bs;
#pragma unroll
      for (int kk = 0; kk < 4; ++kk) {
        int xi = 2 * l + kk - 1;
        if (xi >= 0 && xi < 16) acc += xv[xi] * w[kk];
      }
      H1[(g * 8 + l) * EST + n] = fmaxf(acc, 0.f);
    }
  }
  __syncthreads();
  { // conv2: 32->64ch, L8->4, k4 s2 p1, relu.  thread: co=g*2+c (c0..1), l0..3
    float acc[2][4];
#pragma unroll
    for (int c = 0; c < 2; ++c) {
      float bs = b2[g * 2 + c];
#pragma unroll
      for (int l = 0; l < 4; ++l) acc[c][l] = bs;
    }
    for (int ci = 0; ci < 32; ++ci) {
      float hv[8];
#pragma unroll
      for (int xi = 0; xi < 8; ++xi) hv[xi] = H1[(ci * 8 + xi) * EST + n];
#pragma unroll
      for (int c = 0; c < 2; ++c) {
        float4 wv = *reinterpret_cast<const float4*>(w2 + ((g * 2 + c) * 32 + ci) * 4);
        float w[4] = {wv.x, wv.y, wv.z, wv.w};
#pragma unroll
        for (int l = 0; l < 4; ++l)
#pragma unroll
          for (int kk = 0; kk < 4; ++kk) {
            int xi = 2 * l + kk - 1;
            if (xi >= 0 && xi < 8) acc[c][l] += hv[xi] * w[kk];
          }
      }
    }
    __syncthreads();
#pragma unroll
    for (int c = 0; c < 2; ++c)
#pragma unroll
      for (int l = 0; l < 4; ++l)
        H2[((g * 2 + c) * 4 + l) * EST + n] = fmaxf(acc[c][l], 0.f);
  }
  __syncthreads();
  { // conv3: 64->64ch, L4, k3 p1.  thread: co=g*2+c, l0..3
    float acc[2][4];
#pragma unroll
    for (int c = 0; c < 2; ++c) {
      float bs = b3[g * 2 + c];
#pragma unroll
      for (int l = 0; l < 4; ++l) acc[c][l] = bs;
    }
    for (int ci = 0; ci < 64; ++ci) {
      float hv[4];
#pragma unroll
      for (int xi = 0; xi < 4; ++xi) hv[xi] = H2[(ci * 4 + xi) * EST + n];
#pragma unroll
      for (int c = 0; c < 2; ++c) {
        const float* wp = w3 + ((g * 2 + c) * 64 + ci) * 3;
        float w0 = wp[0], w1v = wp[1], w2v = wp[2];
#pragma unroll
        for (int l = 0; l < 4; ++l) {
          if (l - 1 >= 0) acc[c][l] += hv[l - 1] * w0;
          acc[c][l] += hv[l] * w1v;
          if (l + 1 < 4) acc[c][l] += hv[l + 1] * w2v;
        }
      }
    }
    __syncthreads();
#pragma unroll
    for (int c = 0; c < 2; ++c)
#pragma unroll
      for (int l = 0; l < 4; ++l)
        H3[((g * 2 + c) * 4 + l) * EST + n] = acc[c][l];
  }
  __syncthreads();
  for (int rl = 0; rl < 2; ++rl) {
    { // stage a: co=g (1 per thread), l0..3
      float acc[4];
      {
        float bs = rb1[rl * 32 + g];
#pragma unroll
        for (int l = 0; l < 4; ++l) acc[l] = bs;
      }
      for (int ci = 0; ci < 64; ++ci) {
        float hv[4];
#pragma unroll
        for (int xi = 0; xi < 4; ++xi) hv[xi] = fmaxf(H3[(ci * 4 + xi) * EST + n], 0.f);
        const float* wp = rw1 + ((rl * 32 + g) * 64 + ci) * 3;
        float w0 = wp[0], w1v = wp[1], w2v = wp[2];
#pragma unroll
        for (int l = 0; l < 4; ++l) {
          if (l - 1 >= 0) acc[l] += hv[l - 1] * w0;
          acc[l] += hv[l] * w1v;
          if (l + 1 < 4) acc[l] += hv[l + 1] * w2v;
        }
      }
      __syncthreads();
#pragma unroll
      for (int l = 0; l < 4; ++l)
        T1[(g * 4 + l) * EST + n] = acc[l];
    }
    __syncthreads();
    { // stage b: co=g*2+c, l0..3; h3 += conv1x1(relu(t1))
      float acc[2][4];
#pragma unroll
      for (int c = 0; c < 2; ++c) {
        float bs = rb2[rl * 64 + g * 2 + c];
#pragma unroll
        for (int l = 0; l < 4; ++l) acc[c][l] = bs;
      }
      for (int ci = 0; ci < 32; ++ci) {
        float tv[4];
#pragma unroll
        for (int l = 0; l < 4; ++l) tv[l] = fmaxf(T1[(ci * 4 + l) * EST + n], 0.f);
#pragma unroll
        for (int c = 0; c < 2; ++c) {
          float w = rw2[(rl * 64 + g * 2 + c) * 32 + ci];
#pragma unroll
          for (int l = 0; l < 4; ++l) acc[c][l] += tv[l] * w;
        }
      }
#pragma unroll
      for (int c = 0; c < 2; ++c)
#pragma unroll
        for (int l = 0; l < 4; ++l)
          H3[((g * 2 + c) * 4 + l) * EST + n] += acc[c][l];
    }
    __syncthreads();
  }
  { // pre 1x1: relu(h3) 64->32ch.  thread: e=g, l0..3 -> global z (float4)
    float acc[4];
    {
      float bs = pb[g];
#pragma unroll
      for (int l = 0; l < 4; ++l) acc[l] = bs;
    }
    for (int ci = 0; ci < 64; ++ci) {
      float hv[4];
#pragma unroll
      for (int l = 0; l < 4; ++l) hv[l] = fmaxf(H3[(ci * 4 + l) * EST + n], 0.f);
      float w = pw[g * 64 + ci];
#pragma unroll
      for (int l = 0; l < 4; ++l) acc[l] += hv[l] * w;
    }
    float4 v = {acc[0], acc[1], acc[2], acc[3]};
    *reinterpret_cast<float4*>(z + ((size_t)blk * 8 + n) * 128 + g * 4) = v;
  }
}

// =============== weight pre-split: fp32 -> hi/lo bf16 planes (once/launch) ===============
__global__ __launch_bounds__(256) void split_w(
    const float* __restrict__ qkv_w, const float* __restrict__ proj_w,
    const float* __restrict__ f1, const float* __restrict__ f2,
    const float* __restrict__ hw, unsigned short* __restrict__ wh,
    unsigned short* __restrict__ wl) {
  int i = blockIdx.x * 256 + threadIdx.x;
  float v;
  if (i < 196608) v = qkv_w[i];
  else if (i < 262144) v = proj_w[i - 196608];
  else if (i < 393216) v = f1[i - 262144];
  else if (i < 524288) v = f2[i - 393216];
  else v = hw[i - 524288];
  short h = f2bf(v);
  wh[i] = (unsigned short)h;
  wl[i] = (unsigned short)f2bf(v - bf2f(h));
}

// ====== VQ part 2 v2: fp32 GEMM z.cb^T + inline |c|^2 + fused argmin ======
// tile 128(M) x 128(N), 8x8 micro-tile, K=128.  fp32 for argmin exactness.
__global__ __launch_bounds__(256) void vq_argmin2(
    const float* __restrict__ A, const float* __restrict__ B,
    unsigned long long* __restrict__ keys) {
  __shared__ float Ask[32][132];
  __shared__ float Bsk[32][132];
  __shared__ float cns[128];
  const int tid = threadIdx.x;
  const int n0 = blockIdx.x * 128, m0 = blockIdx.y * 128;
  const int ty = tid >> 4, tx = tid & 15;
  const int lr = tid >> 1, lh = (tid & 1) * 16;
  float acc[8][8] = {};
  float cn_part = 0.f;
  for (int k0 = 0; k0 < 128; k0 += 32) {
    const float4* ap = reinterpret_cast<const float4*>(A + (size_t)(m0 + lr) * 128 + k0 + lh);
    const float4* bp = reinterpret_cast<const float4*>(B + (size_t)(n0 + lr) * 128 + k0 + lh);
#pragma unroll
    for (int q = 0; q < 4; ++q) {
      float4 av = ap[q];
      Ask[lh + q * 4 + 0][lr] = av.x; Ask[lh + q * 4 + 1][lr] = av.y;
      Ask[lh + q * 4 + 2][lr] = av.z; Ask[lh + q * 4 + 3][lr] = av.w;
      float4 bv = bp[q];
      Bsk[lh + q * 4 + 0][lr] = bv.x; Bsk[lh + q * 4 + 1][lr] = bv.y;
      Bsk[lh + q * 4 + 2][lr] = bv.z; Bsk[lh + q * 4 + 3][lr] = bv.w;
      cn_part += bv.x * bv.x + bv.y * bv.y + bv.z * bv.z + bv.w * bv.w;
    }
    __syncthreads();
#pragma unroll 8
    for (int kk = 0; kk < 32; ++kk) {
      float a[8], b[8];
      *reinterpret_cast<float4*>(&a[0]) = *reinterpret_cast<const float4*>(&Ask[kk][ty * 8]);
      *reinterpret_cast<float4*>(&a[4]) = *reinterpret_cast<const float4*>(&Ask[kk][ty * 8 + 4]);
      *reinterpret_cast<float4*>(&b[0]) = *reinterpret_cast<const float4*>(&Bsk[kk][tx * 4]);
      *reinterpret_cast<float4*>(&b[4]) = *reinterpret_cast<const float4*>(&Bsk[kk][64 + tx * 4]);
#pragma unroll
      for (int ii = 0; ii < 8; ++ii)
#pragma unroll
        for (int jj = 0; jj < 8; ++jj) acc[ii][jj] += a[ii] * b[jj];
    }
    __syncthreads();
  }
  cn_part += __shfl_xor(cn_part, 1);
  if ((tid & 1) == 0) cns[lr] = cn_part;
  __syncthreads();
  float cnv[8];
#pragma unroll
  for (int jj = 0; jj < 4; ++jj) {
    cnv[jj] = cns[tx * 4 + jj];
    cnv[4 + jj] = cns[64 + tx * 4 + jj];
  }
#pragma unroll
  for (int ii = 0; ii < 8; ++ii) {
    int row = m0 + ty * 8 + ii;
    unsigned long long key = ~0ull;
#pragma unroll
    for (int jj = 0; jj < 8; ++jj) {
      int j = n0 + (jj < 4 ? tx * 4 + jj : 64 + tx * 4 + (jj - 4));
      float dv = cnv[jj] - 2.f * acc[ii][jj];   // |c|^2 - 2 z.c
      unsigned u = __float_as_uint(dv);
      u = (u & 0x80000000u) ? ~u : (u | 0x80000000u);  // order-preserving
      unsigned long long k = ((unsigned long long)u << 32) | (unsigned)j;
      key = k < key ? k : key;
    }
#pragma unroll
    for (int off = 1; off < 16; off <<= 1) {
      unsigned long long o = __shfl_xor(key, off);
      key = o < key ? o : key;
    }
    if (tx == 0) atomicMin(&keys[row], key);
  }
}

// ===== VQ part 3: gather q, loss partials, hh = q + pos (fp32 + split planes) =====
__global__ __launch_bounds__(256) void vq_gather3(
    const float* __restrict__ z, const float* __restrict__ cb,
    const float* __restrict__ pos, const unsigned long long* __restrict__ keys,
    float* __restrict__ hh, unsigned short* __restrict__ hh_h,
    unsigned short* __restrict__ hh_l, float* __restrict__ lpart,
    float* __restrict__ idx_out) {
  const int blk = blockIdx.x, tid = threadIdx.x;
  __shared__ int sidx[8];
  if (tid < 8) {
    unsigned long long k = keys[blk * 8 + tid];
    int id = (int)(unsigned)(k & 0xffffffffull);
    sidx[tid] = id;
    idx_out[blk * 8 + tid] = (float)id;
  }
  __syncthreads();
  const int p = tid >> 5, d = tid & 31;
  const size_t n = (size_t)blk * 8 + p;
  const int idx = sidx[p];
  float4 q = *reinterpret_cast<const float4*>(cb + (size_t)idx * 128 + d * 4);
  float4 zv = *reinterpret_cast<const float4*>(z + n * 128 + d * 4);
  float4 pv = *reinterpret_cast<const float4*>(pos + (size_t)(n & 511) * 128 + d * 4);
  float hv[4] = {q.x + pv.x, q.y + pv.y, q.z + pv.z, q.w + pv.w};
  *reinterpret_cast<float4*>(hh + n * 128 + d * 4) = *reinterpret_cast<float4*>(hv);
  ushort4 h4, l4;
  unsigned short* hp = (unsigned short*)&h4;
  unsigned short* lp = (unsigned short*)&l4;
#pragma unroll
  for (int e = 0; e < 4; ++e) {
    short hb = f2bf(hv[e]);
    hp[e] = (unsigned short)hb;
    lp[e] = (unsigned short)f2bf(hv[e] - bf2f(hb));
  }
  *reinterpret_cast<ushort4*>(&hh_h[n * 128 + d * 4]) = h4;
  *reinterpret_cast<ushort4*>(&hh_l[n * 128 + d * 4]) = l4;
  float dx = q.x - zv.x, dy = q.y - zv.y, dz = q.z - zv.z, dw = q.w - zv.w;
  float part = dx * dx + dy * dy + dz * dz + dw * dw;
#pragma unroll
  for (int o = 1; o < 64; o <<= 1) part += __shfl_xor(part, o);
  __shared__ float lred[4];
  if ((tid & 63) == 0) lred[tid >> 6] = part;
  __syncthreads();
  if (tid == 0) lpart[blk] = lred[0] + lred[1] + lred[2] + lred[3];
}

// ====== split-bf16 MFMA GEMM (pre-split inputs): C = A[M,128]*B[N,128]^T + bias ======
// tile 128(M) x 64(N).  ACT: 0=none 1=gelu.  SPLIT: 1 -> write hi/lo planes, 0 -> fp32.
template <int ACT, int SPLIT>
__global__ __launch_bounds__(256) void mgemm2(
    const unsigned short* __restrict__ Ahg, const unsigned short* __restrict__ Alg,
    const unsigned short* __restrict__ Bhg, const unsigned short* __restrict__ Blg,
    const float* __restrict__ bias, float* __restrict__ C,
    unsigned short* __restrict__ Ch, unsigned short* __restrict__ Cl, int N) {
  __shared__ short Ah[128 * 40], Al[128 * 40], Bh[64 * 40], Bl[64 * 40];
  const int tid = threadIdx.x;
  const int n0 = blockIdx.x * 64, m0 = blockIdx.y * 128;
  const int wave = tid >> 6, lane = tid & 63, quad = lane >> 4, l15 = lane & 15;
  const f32x4 z4 = {0.f, 0.f, 0.f, 0.f};
  f32x4 acc[2][4];
#pragma unroll
  for (int i = 0; i < 2; ++i)
#pragma unroll
    for (int j = 0; j < 4; ++j) acc[i][j] = z4;

  const int ra = tid >> 1, ha = (tid & 1) * 16;         // A: 128 rows, 16 shorts each
  const int rb = tid >> 2, hb = (tid & 3) * 8;          // B: 64 rows, 8 shorts each
  for (int k0 = 0; k0 < 128; k0 += 32) {
    {
      const size_t abase = (size_t)(m0 + ra) * 128 + k0 + ha;
      *reinterpret_cast<bf8*>(&Ah[ra * 40 + ha])     = *reinterpret_cast<const bf8*>(&Ahg[abase]);
      *reinterpret_cast<bf8*>(&Ah[ra * 40 + ha + 8]) = *reinterpret_cast<const bf8*>(&Ahg[abase + 8]);
      *reinterpret_cast<bf8*>(&Al[ra * 40 + ha])     = *reinterpret_cast<const bf8*>(&Alg[abase]);
      *reinterpret_cast<bf8*>(&Al[ra * 40 + ha + 8]) = *reinterpret_cast<const bf8*>(&Alg[abase + 8]);
      const size_t bbase = (size_t)(n0 + rb) * 128 + k0 + hb;
      *reinterpret_cast<bf8*>(&Bh[rb * 40 + hb]) = *reinterpret_cast<const bf8*>(&Bhg[bbase]);
      *reinterpret_cast<bf8*>(&Bl[rb * 40 + hb]) = *reinterpret_cast<const bf8*>(&Blg[bbase]);
    }
    __syncthreads();
    bf8 af[2], afl[2], bfh[4], bfl[4];
#pragma unroll
    for (int mt = 0; mt < 2; ++mt) {
      int row = wave * 32 + mt * 16 + l15;
      af[mt]  = *reinterpret_cast<const bf8*>(&Ah[row * 40 + quad * 8]);
      afl[mt] = *reinterpret_cast<const bf8*>(&Al[row * 40 + quad * 8]);
    }
#pragma unroll
    for (int nt = 0; nt < 4; ++nt) {
      int row = nt * 16 + l15;
      bfh[nt] = *reinterpret_cast<const bf8*>(&Bh[row * 40 + quad * 8]);
      bfl[nt] = *reinterpret_cast<const bf8*>(&Bl[row * 40 + quad * 8]);
    }
#pragma unroll
    for (int nt = 0; nt < 4; ++nt)
#pragma unroll
      for (int mt = 0; mt < 2; ++mt)
        acc[mt][nt] = __builtin_amdgcn_mfma_f32_16x16x32_bf16(af[mt], bfh[nt], acc[mt][nt], 0, 0, 0);
#pragma unroll
    for (int nt = 0; nt < 4; ++nt)
#pragma unroll
      for (int mt = 0; mt < 2; ++mt)
        acc[mt][nt] = __builtin_amdgcn_mfma_f32_16x16x32_bf16(af[mt], bfl[nt], acc[mt][nt], 0, 0, 0);
#pragma unroll
    for (int nt = 0; nt < 4; ++nt)
#pragma unroll
      for (int mt = 0; mt < 2; ++mt)
        acc[mt][nt] = __builtin_amdgcn_mfma_f32_16x16x32_bf16(afl[mt], bfh[nt], acc[mt][nt], 0, 0, 0);
    __syncthreads();
  }
#pragma unroll
  for (int nt = 0; nt < 4; ++nt) {
    int col = n0 + nt * 16 + l15;
    float bv = bias[col];
#pragma unroll
    for (int mt = 0; mt < 2; ++mt) {
      int rbase = m0 + wave * 32 + mt * 16 + quad * 4;
#pragma unroll
      for (int r = 0; r < 4; ++r) {
        float v = acc[mt][nt][r] + bv;
        if (ACT == 1) v = 0.5f * v * (1.f + erff(v * 0.7071067811865476f));
        if (SPLIT) {
          short hb_ = f2bf(v);
          Ch[(size_t)(rbase + r) * N + col] = (unsigned short)hb_;
          Cl[(size_t)(rbase + r) * N + col] = (unsigned short)f2bf(v - bf2f(hb_));
        } else {
          C[(size_t)(rbase + r) * N + col] = v;
        }
      }
    }
  }
}

// == split-bf16 MFMA GEMM + residual + LN (optionally + second/final LN) ==
// out = LN(A.B^T+bias+res)*g+b; FINAL=1: y = LN2(out)*g2+b2 -> planes only.
// tile 64(M) x 128(N).  K: 128 or 256.
template <int K, int FINAL>
__global__ __launch_bounds__(256) void mgemm_ln2(
    const unsigned short* __restrict__ Ahg, const unsigned short* __restrict__ Alg,
    const unsigned short* __restrict__ Bhg, const unsigned short* __restrict__ Blg,
    const float* __restrict__ bias, const float* __restrict__ res,
    const float* __restrict__ g, const float* __restrict__ bb,
    const float* __restrict__ g2, const float* __restrict__ bb2,
    float* __restrict__ C, unsigned short* __restrict__ Ch,
    unsigned short* __restrict__ Cl) {
  __shared__ short Ah[64 * 40], Al[64 * 40], Bh[128 * 40], Bl[128 * 40];
  const int tid = threadIdx.x;
  const int m0 = blockIdx.x * 64;
  const int wave = tid >> 6, lane = tid & 63, quad = lane >> 4, l15 = lane & 15;
  const f32x4 z4 = {0.f, 0.f, 0.f, 0.f};
  f32x4 acc[8];
#pragma unroll
  for (int j = 0; j < 8; ++j) acc[j] = z4;

  const int ra = tid >> 2, ha = (tid & 3) * 8;          // A: 64 rows, 8 shorts each
  const int rb = tid >> 1, hb = (tid & 1) * 16;         // B: 128 rows, 16 shorts each
  for (int k0 = 0; k0 < K; k0 += 32) {
    {
      const size_t abase = (size_t)(m0 + ra) * K + k0 + ha;
      *reinterpret_cast<bf8*>(&Ah[ra * 40 + ha]) = *reinterpret_cast<const bf8*>(&Ahg[abase]);
      *reinterpret_cast<bf8*>(&Al[ra * 40 + ha]) = *reinterpret_cast<const bf8*>(&Alg[abase]);
      const size_t bbase = (size_t)rb * K + k0 + hb;
      *reinterpret_cast<bf8*>(&Bh[rb * 40 + hb])     = *reinterpret_cast<const bf8*>(&Bhg[bbase]);
      *reinterpret_cast<bf8*>(&Bh[rb * 40 + hb + 8]) = *reinterpret_cast<const bf8*>(&Bhg[bbase + 8]);
      *reinterpret_cast<bf8*>(&Bl[rb * 40 + hb])     = *reinterpret_cast<const bf8*>(&Blg[bbase]);
      *reinterpret_cast<bf8*>(&Bl[rb * 40 + hb + 8]) = *reinterpret_cast<const bf8*>(&Blg[bbase + 8]);
    }
    __syncthreads();
    bf8 af, afl, bfh[8], bfl[8];
    {
      int row = wave * 16 + l15;
      af  = *reinterpret_cast<const bf8*>(&Ah[row * 40 + quad * 8]);
      afl = *reinterpret_cast<const bf8*>(&Al[row * 40 + quad * 8]);
    }
#pragma unroll
    for (int nt = 0; nt < 8; ++nt) {
      int row = nt * 16 + l15;
      bfh[nt] = *reinterpret_cast<const bf8*>(&Bh[row * 40 + quad * 8]);
      bfl[nt] = *reinterpret_cast<const bf8*>(&Bl[row * 40 + quad * 8]);
    }
#pragma unroll
    for (int nt = 0; nt < 8; ++nt)
      acc[nt] = __builtin_amdgcn_mfma_f32_16x16x32_bf16(af, bfh[nt], acc[nt], 0, 0, 0);
#pragma unroll
    for (int nt = 0; nt < 8; ++nt)
      acc[nt] = __builtin_amdgcn_mfma_f32_16x16x32_bf16(af, bfl[nt], acc[nt], 0, 0, 0);
#pragma unroll
    for (int nt = 0; nt < 8; ++nt)
      acc[nt] = __builtin_amdgcn_mfma_f32_16x16x32_bf16(afl, bfh[nt], acc[nt], 0, 0, 0);
    __syncthreads();
  }
  float bias_v[8], g_v[8], bb_v[8], g2_v[8], bb2_v[8];
#pragma unroll
  for (int nt = 0; nt < 8; ++nt) {
    int col = nt * 16 + l15;
    bias_v[nt] = bias[col]; g_v[nt] = g[col]; bb_v[nt] = bb[col];
    if (FINAL) { g2_v[nt] = g2[col]; bb2_v[nt] = bb2[col]; }
  }
  const int rbase = m0 + wave * 16 + quad * 4;
#pragma unroll
  for (int r = 0; r < 4; ++r) {
    const int row = rbase + r;
    float ov[8];
    float s = 0.f;
#pragma unroll
    for (int nt = 0; nt < 8; ++nt) {
      ov[nt] = acc[nt][r] + bias_v[nt] + res[(size_t)row * 128 + nt * 16 + l15];
      s += ov[nt];
    }
    s += __shfl_xor(s, 1); s += __shfl_xor(s, 2);
    s += __shfl_xor(s, 4); s += __shfl_xor(s, 8);
    float mean = s * 0.0078125f;
    float s2 = 0.f;
#pragma unroll
    for (int nt = 0; nt < 8; ++nt) { ov[nt] -= mean; s2 += ov[nt] * ov[nt]; }
    s2 += __shfl_xor(s2, 1); s2 += __shfl_xor(s2, 2);
    s2 += __shfl_xor(s2, 4); s2 += __shfl_xor(s2, 8);
    float rstd = rsqrtf(s2 * 0.0078125f + 1e-5f);
    if (FINAL) {
      float yv[8];
      float s3 = 0.f;
#pragma unroll
      for (int nt = 0; nt < 8; ++nt) { yv[nt] = ov[nt] * rstd * g_v[nt] + bb_v[nt]; s3 += yv[nt]; }
      s3 += __shfl_xor(s3, 1); s3 += __shfl_xor(s3, 2);
      s3 += __shfl_xor(s3, 4); s3 += __shfl_xor(s3, 8);
      float mean2 = s3 * 0.0078125f;
      float s4 = 0.f;
#pragma unroll
      for (int nt = 0; nt < 8; ++nt) { yv[nt] -= mean2; s4 += yv[nt] * yv[nt]; }
      s4 += __shfl_xor(s4, 1); s4 += __shfl_xor(s4, 2);
      s4 += __shfl_xor(s4, 4); s4 += __shfl_xor(s4, 8);
      float rstd2 = rsqrtf(s4 * 0.0078125f + 1e-5f);
#pragma unroll
      for (int nt = 0; nt < 8; ++nt) {
        float v = yv[nt] * rstd2 * g2_v[nt] + bb2_v[nt];
        size_t off = (size_t)row * 128 + nt * 16 + l15;
        short hb_ = f2bf(v);
        Ch[off] = (unsigned short)hb_;
        Cl[off] = (unsigned short)f2bf(v - bf2f(hb_));
      }
    } else {
#pragma unroll
      for (int nt = 0; nt < 8; ++nt) {
        float v = ov[nt] * rstd * g_v[nt] + bb_v[nt];
        size_t off = (size_t)row * 128 + nt * 16 + l15;
        C[off] = v;
        short hb_ = f2bf(v);
        Ch[off] = (unsigned short)hb_;
        Cl[off] = (unsigned short)f2bf(v - bf2f(hb_));
      }
    }
  }
}

// ====== MFMA flash attention: block per (qt,h,b); reads/writes split planes ======
__global__ __launch_bounds__(256) void attn3(
    const unsigned short* __restrict__ qh_, const unsigned short* __restrict__ ql_,
    unsigned short* __restrict__ oh, unsigned short* __restrict__ ol) {
  const int qt = blockIdx.x, h = blockIdx.y, b = blockIdx.z;
  __shared__ short Kh[64 * 40], Kl[64 * 40];     // [key][d]
  __shared__ short Vth[32 * 72], Vtl[32 * 72];   // [d][key]
  __shared__ float Ss[64 * 72];
  __shared__ float ms[64], ls[64], alphas[64];
  const int tid = threadIdx.x;
  const int wave = tid >> 6, lane = tid & 63, quad = lane >> 4, l15 = lane & 15;
  const size_t tbase = (size_t)b * 512 + qt * 64;
  bf8 qfh, qfl;
  {
    const size_t qoff = (tbase + wave * 16 + l15) * 384 + h * 32 + quad * 8;
    qfh = *reinterpret_cast<const bf8*>(&qh_[qoff]);
    qfl = *reinterpret_cast<const bf8*>(&ql_[qoff]);
  }
  if (tid < 64) { ms[tid] = -1e30f; ls[tid] = 0.f; }
  const f32x4 z4 = {0.f, 0.f, 0.f, 0.f};
  f32x4 o[2] = {z4, z4};
  const float scale = 0.17677669529663687f;  // 1/sqrt(32)
  const int sr = tid >> 2, sc8 = (tid & 3) * 8;
  for (int kt = 0; kt <= qt; ++kt) {
    const size_t kbase = (size_t)b * 512 + kt * 64;
    {
      const size_t koff = (kbase + sr) * 384 + 128 + h * 32 + sc8;
      *reinterpret_cast<bf8*>(&Kh[sr * 40 + sc8]) = *reinterpret_cast<const bf8*>(&qh_[koff]);
      *reinterpret_cast<bf8*>(&Kl[sr * 40 + sc8]) = *reinterpret_cast<const bf8*>(&ql_[koff]);
      const size_t voff = (kbase + sr) * 384 + 256 + h * 32 + sc8;
      bf8 vh8 = *reinterpret_cast<const bf8*>(&qh_[voff]);
      bf8 vl8 = *reinterpret_cast<const bf8*>(&ql_[voff]);
#pragma unroll
      for (int j = 0; j < 8; ++j) {
        Vth[(sc8 + j) * 72 + sr] = vh8[j];
        Vtl[(sc8 + j) * 72 + sr] = vl8[j];
      }
    }
    __syncthreads();
    {
#pragma unroll
      for (int nt = 0; nt < 4; ++nt) {
        const int krow = nt * 16 + l15;
        bf8 kfh = *reinterpret_cast<const bf8*>(&Kh[krow * 40 + quad * 8]);
        bf8 kfl = *reinterpret_cast<const bf8*>(&Kl[krow * 40 + quad * 8]);
        f32x4 s = z4;
        s = __builtin_amdgcn_mfma_f32_16x16x32_bf16(qfh, kfh, s, 0, 0, 0);
        s = __builtin_amdgcn_mfma_f32_16x16x32_bf16(qfh, kfl, s, 0, 0, 0);
        s = __builtin_amdgcn_mfma_f32_16x16x32_bf16(qfl, kfh, s, 0, 0, 0);
#pragma unroll
        for (int r = 0; r < 4; ++r) {
          int row64 = wave * 16 + quad * 4 + r;
          int col64 = nt * 16 + l15;
          float v = s[r] * scale;
          if (kt == qt && col64 > row64) v += -1e9f;
          Ss[row64 * 72 + col64] = v;
        }
      }
    }
    __syncthreads();
    {
      const int i = tid >> 2, q = tid & 3;
      float mx = -3.4e38f;
      float4 pv[4];
#pragma unroll
      for (int t = 0; t < 4; ++t) {
        pv[t] = *reinterpret_cast<const float4*>(&Ss[i * 72 + q * 16 + t * 4]);
        mx = fmaxf(mx, fmaxf(fmaxf(pv[t].x, pv[t].y), fmaxf(pv[t].z, pv[t].w)));
      }
      mx = fmaxf(mx, __shfl_xor(mx, 1));
      mx = fmaxf(mx, __shfl_xor(mx, 2));
      float mold = ms[i];
      mx = fmaxf(mx, mold);
      float sum = 0.f;
#pragma unroll
      for (int t = 0; t < 4; ++t) {
        pv[t].x = __expf(pv[t].x - mx); pv[t].y = __expf(pv[t].y - mx);
        pv[t].z = __expf(pv[t].z - mx); pv[t].w = __expf(pv[t].w - mx);
        sum += pv[t].x + pv[t].y + pv[t].z + pv[t].w;
        *reinterpret_cast<float4*>(&Ss[i * 72 + q * 16 + t * 4]) = pv[t];
      }
      sum += __shfl_xor(sum, 1);
      sum += __shfl_xor(sum, 2);
      if (q == 0) {
        float alpha = __expf(mold - mx);
        ls[i] = ls[i] * alpha + sum;
        ms[i] = mx;
        alphas[i] = alpha;
      }
    }
    __syncthreads();
    {
      bf8 ph[2], pl[2];
#pragma unroll
      for (int c = 0; c < 2; ++c) {
        const float* pp = &Ss[(wave * 16 + l15) * 72 + c * 32 + quad * 8];
        float4 p0 = *reinterpret_cast<const float4*>(pp);
        float4 p1 = *reinterpret_cast<const float4*>(pp + 4);
        float pf[8] = {p0.x, p0.y, p0.z, p0.w, p1.x, p1.y, p1.z, p1.w};
#pragma unroll
        for (int j = 0; j < 8; ++j) {
          short hb_ = f2bf(pf[j]);
          ph[c][j] = hb_;
          pl[c][j] = f2bf(pf[j] - bf2f(hb_));
        }
      }
      float a0 = alphas[wave * 16 + quad * 4 + 0];
      float a1 = alphas[wave * 16 + quad * 4 + 1];
      float a2 = alphas[wave * 16 + quad * 4 + 2];
      float a3 = alphas[wave * 16 + quad * 4 + 3];
#pragma unroll
      for (int dt = 0; dt < 2; ++dt) {
        o[dt][0] *= a0; o[dt][1] *= a1; o[dt][2] *= a2; o[dt][3] *= a3;
#pragma unroll
        for (int c = 0; c < 2; ++c) {
          const int vrow = dt * 16 + l15;
          bf8 vfh = *reinterpret_cast<const bf8*>(&Vth[vrow * 72 + c * 32 + quad * 8]);
          bf8 vfl = *reinterpret_cast<const bf8*>(&Vtl[vrow * 72 + c * 32 + quad * 8]);
          o[dt] = __builtin_amdgcn_mfma_f32_16x16x32_bf16(ph[c], vfh, o[dt], 0, 0, 0);
          o[dt] = __builtin_amdgcn_mfma_f32_16x16x32_bf16(ph[c], vfl, o[dt], 0, 0, 0);
          o[dt] = __builtin_amdgcn_mfma_f32_16x16x32_bf16(pl[c], vfh, o[dt], 0, 0, 0);
        }
      }
    }
    __syncthreads();
  }
#pragma unroll
  for (int r = 0; r < 4; ++r) {
    float inv = 1.f / ls[wave * 16 + quad * 4 + r];
    size_t row = tbase + wave * 16 + quad * 4 + r;
#pragma unroll
    for (int dt = 0; dt < 2; ++dt) {
      float v = o[dt][r] * inv;
      short hb_ = f2bf(v);
      size_t off = row * 128 + h * 32 + dt * 16 + l15;
      oh[off] = (unsigned short)hb_;
      ol[off] = (unsigned short)f2bf(v - bf2f(hb_));
    }
  }
}

__global__ __launch_bounds__(256) void loss_finalize2(const float* __restrict__ lp,
                                                      float* __restrict__ out) {
  float s = 0.f;
  for (int i = threadIdx.x; i < 2048; i += 256) s += lp[i];
#pragma unroll
  for (int o = 1; o < 64; o <<= 1) s += __shfl_xor(s, o);
  __shared__ float red[4];
  if ((threadIdx.x & 63) == 0) red[threadIdx.x >> 6] = s;
  __syncthreads();
  if (threadIdx.x == 0)
    out[0] = 1.25f * (red[0] + red[1] + red[2] + red[3]) / 2097152.0f;
}

extern "C" void kernel_launch(void* const* d_in, const int* in_sizes, int n_in,
                              void* d_out, int out_size, void* d_ws, size_t ws_size,
                              hipStream_t stream) {
  const float* x      = (const float*)d_in[0];
  const float* enc_w1 = (const float*)d_in[1];
  const float* enc_b1 = (const float*)d_in[2];
  const float* enc_w2 = (const float*)d_in[3];
  const float* enc_b2 = (const float*)d_in[4];
  const float* enc_w3 = (const float*)d_in[5];
  const float* enc_b3 = (const float*)d_in[6];
  const float* res_w1 = (const float*)d_in[7];
  const float* res_b1 = (const float*)d_in[8];
  const float* res_w2 = (const float*)d_in[9];
  const float* res_b2 = (const float*)d_in[10];
  const float* pre_w  = (const float*)d_in[11];
  const float* pre_b  = (const float*)d_in[12];
  const float* codebook = (const float*)d_in[13];
  const float* pos_emb  = (const float*)d_in[14];
  const float* qkv_w  = (const float*)d_in[15];
  const float* qkv_b  = (const float*)d_in[16];
  const float* proj_w = (const float*)d_in[17];
  const float* proj_b = (const float*)d_in[18];
  const float* ln1_g  = (const float*)d_in[19];
  const float* ln1_b  = (const float*)d_in[20];
  const float* ln2_g  = (const float*)d_in[21];
  const float* ln2_b  = (const float*)d_in[22];
  const float* ffn_w1 = (const float*)d_in[23];
  const float* ffn_b1 = (const float*)d_in[24];
  const float* ffn_w2 = (const float*)d_in[25];
  const float* ffn_b2 = (const float*)d_in[26];
  const float* fin_g  = (const float*)d_in[27];
  const float* fin_b  = (const float*)d_in[28];
  const float* head_w = (const float*)d_in[29];
  const float* head_b = (const float*)d_in[30];

  float* out = (float*)d_out;
  float* ws  = (float*)d_ws;

  // ws: keys(32768f) | lpart(2048) | pad | wh/wl planes | hhln planes
  unsigned long long* keys = (unsigned long long*)ws;
  float* lpart = ws + 32768;
  unsigned short* wh = (unsigned short*)(ws + 36864);
  unsigned short* wl = (unsigned short*)(ws + 36864 + 327680);
  unsigned short* hhln_h = (unsigned short*)(ws + 692224);
  unsigned short* hhln_l = (unsigned short*)(ws + 692224 + 1048576);

  // d_out scratch overlay (float offsets; dead before head GEMM)
  float* zf = out;                                            // [0 .. 2^21)
  float* hh = out + 2097152;                                  // [2^21 .. 2^22)
  unsigned short* hh_h   = (unsigned short*)(out + 4194304);
  unsigned short* hh_l   = (unsigned short*)(out + 5242880);
  unsigned short* qkvb_h = (unsigned short*)(out + 6291456);
  unsigned short* qkvb_l = (unsigned short*)(out + 9437184);
  unsigned short* oatt_h = (unsigned short*)(out + 12582912);
  unsigned short* oatt_l = (unsigned short*)(out + 13631488);
  unsigned short* fbuf_h = (unsigned short*)(out + 0);        // overlays zf (dead)
  unsigned short* fbuf_l = (unsigned short*)(out + 14680064);

  const int W_QKV = 0, W_PROJ = 196608, W_F1 = 262144, W_F2 = 393216, W_HEAD = 524288;

  hipMemsetAsync(keys, 0xFF, NPATCH * sizeof(unsigned long long), stream);

  encoder4<<<2048, 256, 0, stream>>>(x, enc_w1, enc_b1, enc_w2, enc_b2,
                                     enc_w3, enc_b3, res_w1, res_b1,
                                     res_w2, res_b2, pre_w, pre_b, zf);
  split_w<<<2560, 256, 0, stream>>>(qkv_w, proj_w, ffn_w1, ffn_w2, head_w, wh, wl);
  vq_argmin2<<<dim3(8, 128), 256, 0, stream>>>(zf, codebook, keys);
  vq_gather3<<<2048, 256, 0, stream>>>(zf, codebook, pos_emb, keys, hh, hh_h, hh_l,
                                       lpart, out + IDX_OFF);
  for (int i = 0; i < 4; ++i) {
    mgemm2<0, 1><<<dim3(6, 128), 256, 0, stream>>>(
        hh_h, hh_l, wh + W_QKV + i * 49152, wl + W_QKV + i * 49152,
        qkv_b + i * 384, nullptr, qkvb_h, qkvb_l, 384);
    attn3<<<dim3(8, 4, 32), 256, 0, stream>>>(qkvb_h, qkvb_l, oatt_h, oatt_l);
    mgemm_ln2<128, 0><<<256, 256, 0, stream>>>(
        oatt_h, oatt_l, wh + W_PROJ + i * 16384, wl + W_PROJ + i * 16384,
        proj_b + i * 128, hh, ln1_g + i * 128, ln1_b + i * 128,
        nullptr, nullptr, hh, hh_h, hh_l);
    mgemm2<1, 1><<<dim3(4, 128), 256, 0, stream>>>(
        hh_h, hh_l, wh + W_F1 + i * 32768, wl + W_F1 + i * 32768,
        ffn_b1 + i * 256, nullptr, fbuf_h, fbuf_l, 256);
    if (i < 3) {
      mgemm_ln2<256, 0><<<256, 256, 0, stream>>>(
          fbuf_h, fbuf_l, wh + W_F2 + i * 32768, wl + W_F2 + i * 32768,
          ffn_b2 + i * 128, hh, ln2_g + i * 128, ln2_b + i * 128,
          nullptr, nullptr, hh, hh_h, hh_l);
    } else {
      mgemm_ln2<256, 1><<<256, 256, 0, stream>>>(
          fbuf_h, fbuf_l, wh + W_F2 + i * 32768, wl + W_F2 + i * 32768,
          ffn_b2 + i * 128, hh, ln2_g + i * 128, ln2_b + i * 128,
          fin_g, fin_b, hh, hhln_h, hhln_l);
    }
  }
  mgemm2<0, 0><<<dim3(16, 128), 256, 0, stream>>>(
      hhln_h, hhln_l, wh + W_HEAD, wl + W_HEAD, head_b, out, nullptr, nullptr, 1024);
  loss_finalize2<<<1, 256, 0, stream>>>(lpart, out + LOSS_OFF);
}